// Round 16
// baseline (298.449 us; speedup 1.0000x reference)
//
#include <hip/hip_runtime.h>
#include <math.h>

#define BB 2
#define TT 2048
#define CC 1024
#define HH 16
#define DD 64
#define INNER 1024
#define BT (BB*TT)   /* 4096 */
#define EPSF 1e-6f
#define CH 64
#define NC (TT/CH)        /* 32 */
#define NBH (BB*HH)       /* 32 */
#define NCHK (NBH*NC)     /* 1024 */

typedef unsigned short u16;
typedef __bf16 bf16x8 __attribute__((ext_vector_type(8)));
typedef float f32x4 __attribute__((ext_vector_type(4)));

__device__ inline u16 f2bf(float f) {   // RNE float->bf16
  unsigned u = __builtin_bit_cast(unsigned, f);
  return (u16)((u + 0x7fffu + ((u >> 16) & 1u)) >> 16);
}
__device__ inline float b2f(u16 b) {
  unsigned u = ((unsigned)b) << 16;
  return __builtin_bit_cast(float, u);
}
__device__ inline void gll16(const u16* g, u16* l) {
  __builtin_amdgcn_global_load_lds(
      (const __attribute__((address_space(1))) void*)g,
      (__attribute__((address_space(3))) void*)l, 16, 0, 0);
}

// Static device scratch (fully overwritten every call; deterministic).
__device__ u16   g_pqb[BT * INNER];      // pre_q bf16
__device__ u16   g_pkb[BT * INNER];      // pre_k
__device__ u16   g_pvb[BT * INNER];      // pre_v
__device__ u16   g_qb [BT * INNER];      // q bf16 (post conv+l2)
__device__ u16   g_kb [BT * INNER];
__device__ u16   g_vb [BT * INNER];
__device__ u16   g_gb [BT * INNER];      // g projection bf16
__device__ u16   g_ob [BT * INNER];      // o bf16
__device__ float g_beta[BT * HH];
__device__ float g_ldec[BT * HH];
__device__ u16   g_xb[BT * CC];          // x in bf16
__device__ u16   g_wbb[4 * INNER * CC];  // wq|wk|wv|wg in bf16
__device__ u16   g_wob[CC * INNER];      // wo in bf16
__device__ u16   g_gatedb[BT * INNER];   // gated activations bf16
// per-chunk tensors: output path bf16, state path fp32
__device__ u16   g_U0 [NCHK * CH * DD];
__device__ u16   g_Wt [NCHK * DD * CH];
__device__ u16   g_Bt [NCHK * CH * CH];
__device__ u16   g_Qht[NCHK * DD * CH];
__device__ float g_Mc [NCHK * DD * DD];  // M[d][s] row-major (d = row)
__device__ float g_bc [NCHK * DD * DD];  // b[d][e]
__device__ float g_Sall[NCHK * DD * DD]; // chunk-start states [d][e]

// ---------------------------------------------------------------------------
// Fused cast of x and all weights to bf16.
// ---------------------------------------------------------------------------
__global__ __launch_bounds__(256) void cast_all(
    const float* __restrict__ x, const float* __restrict__ wq,
    const float* __restrict__ wk, const float* __restrict__ wv,
    const float* __restrict__ wg, const float* __restrict__ wo,
    u16* __restrict__ xb, u16* __restrict__ wb, u16* __restrict__ wob) {
  long i = ((long)blockIdx.x * 256 + threadIdx.x) * 4;
  const float* src;
  u16* dst;
  if (i < 4194304)      { src = x  + i;             dst = xb + i; }
  else if (i < 5242880) { src = wq + (i - 4194304); dst = wb + (i - 4194304); }
  else if (i < 6291456) { src = wk + (i - 5242880); dst = wb + (i - 4194304); }
  else if (i < 7340032) { src = wv + (i - 6291456); dst = wb + (i - 4194304); }
  else if (i < 8388608) { src = wg + (i - 7340032); dst = wb + (i - 4194304); }
  else                  { src = wo + (i - 8388608); dst = wob + (i - 8388608); }
  float4 v = *(const float4*)src;
  ushort4 o;
  o.x = f2bf(v.x); o.y = f2bf(v.y); o.z = f2bf(v.z); o.w = f2bf(v.w);
  *(ushort4*)dst = o;
}

// ---------------------------------------------------------------------------
// bf16 MFMA GEMM: BK=64 (half the barrier drains of BK=32), source-swizzled
// LDS (0 bank conflicts), XCD serpentine region remap.
// C[m,n] = sum_k A[m,k]*B[n,k], K=1024, 128x128 tiles, flat 1D grid.
// Staging: 1024 16B-chunks/matrix/iter; chunk c: row=c>>3, phys slot=c&7,
// global slot = phys ^ (row&7) (source pre-swizzle, m173). Reads: phys =
// (ks*4+kq) ^ (lr&7) -> 2 lanes/bank-quad (free, m136). Bit-identical math,
// K accumulated in ascending order (ks=0 then ks=1 per 64-step).
// ---------------------------------------------------------------------------
template <typename OutT, int NBN>
__global__ __launch_bounds__(256) void bgemm4(
    const u16* __restrict__ A, const u16* __restrict__ B,
    OutT* __restrict__ c0, OutT* __restrict__ c1,
    OutT* __restrict__ c2, OutT* __restrict__ c3) {
  __shared__ u16 lA[128 * 64];
  __shared__ u16 lB[128 * 64];
  const int tid = threadIdx.x;
  const int bid = blockIdx.x;
  int bm, bn;
  if constexpr (NBN == 32) {
    // 8 XCD regions of 16bm x 8bn, serpentine within region
    const int xcd = bid & 7;
    const int idx = bid >> 3;          // 0..127
    const int in_ = idx >> 4;          // 0..7
    int im = idx & 15;
    im = (in_ & 1) ? (15 - im) : im;
    bm = ((xcd >> 2) * 16 + im) * 128;
    bn = ((xcd & 3) * 8 + in_) * 128;
  } else {
    // NBN == 8: each XCD owns 4bm x 8bn, serpentine
    const int xcd = bid & 7;
    const int idx = bid >> 3;          // 0..31
    const int in_ = idx >> 2;          // 0..7
    int im = idx & 3;
    im = (in_ & 1) ? (3 - im) : im;
    bm = (xcd * 4 + im) * 128;
    bn = in_ * 128;
  }
  const int lane = tid & 63;
  const int wave = tid >> 6;
  const int wr = (wave >> 1) * 64, wc = (wave & 1) * 64;
  const int lr = lane & 15;
  const int kq = lane >> 4;            // 0..3
  // staging bases: row0 = tid>>3, slot swizzle independent of p (32p&7==0)
  const int srow0 = tid >> 3;          // 0..31
  const int gcol = ((tid & 7) ^ (srow0 & 7)) * 8;
  const u16* gA0 = &A[(long)(bm + srow0) * CC + gcol];
  const u16* gB0 = &B[(long)(bn + srow0) * CC + gcol];
  u16* lA0 = &lA[tid * 8];
  u16* lB0 = &lB[tid * 8];
  f32x4 acc[4][4] = {};

  for (int k0 = 0; k0 < CC; k0 += 64) {
    __syncthreads();                  // protect prev-iter LDS reads
#pragma unroll
    for (int p = 0; p < 4; ++p) {
      gll16(gA0 + (long)p * 32 * CC + k0, lA0 + p * 2048);
      gll16(gB0 + (long)p * 32 * CC + k0, lB0 + p * 2048);
    }
    __syncthreads();                  // drains vmcnt before reads
#pragma unroll
    for (int ks = 0; ks < 2; ++ks) {
      const int sl = ((ks * 4 + kq) ^ (lr & 7)) * 8;
      bf16x8 af[4], bf_[4];
#pragma unroll
      for (int m = 0; m < 4; ++m)
        af[m] = __builtin_bit_cast(bf16x8,
            *(const uint4*)&lA[(wr + m * 16 + lr) * 64 + sl]);
#pragma unroll
      for (int n = 0; n < 4; ++n)
        bf_[n] = __builtin_bit_cast(bf16x8,
            *(const uint4*)&lB[(wc + n * 16 + lr) * 64 + sl]);
#pragma unroll
      for (int m = 0; m < 4; ++m)
#pragma unroll
        for (int n = 0; n < 4; ++n)
          acc[m][n] = __builtin_amdgcn_mfma_f32_16x16x32_bf16(
              af[m], bf_[n], acc[m][n], 0, 0, 0);
    }
  }
  OutT* cp = (bn < 1024) ? c0 : (bn < 2048) ? c1 : (bn < 3072) ? c2 : c3;
  const int ccol0 = (bn & 1023) + wc;
  const int crow0 = bm + wr + kq * 4;
#pragma unroll
  for (int m = 0; m < 4; ++m)
#pragma unroll
    for (int n = 0; n < 4; ++n) {
      int col = ccol0 + n * 16 + lr;
#pragma unroll
      for (int r = 0; r < 4; ++r) {
        long idx2 = (long)(crow0 + m * 16 + r) * INNER + col;
        if constexpr (sizeof(OutT) == 2) cp[idx2] = f2bf(acc[m][n][r]);
        else                             cp[idx2] = acc[m][n][r];
      }
    }
}

// ---------------------------------------------------------------------------
// Fused causal depthwise conv1d(K=4) + SiLU (+per-head L2 norm for q,k).
// ---------------------------------------------------------------------------
__global__ __launch_bounds__(256) void conv3(
    const u16* __restrict__ pq, const u16* __restrict__ pk,
    const u16* __restrict__ pv,
    const float* __restrict__ cqw, const float* __restrict__ cqb,
    const float* __restrict__ ckw, const float* __restrict__ ckb,
    const float* __restrict__ cvw, const float* __restrict__ cvb,
    u16* __restrict__ oq, u16* __restrict__ ok, u16* __restrict__ ov) {
  const int which = blockIdx.y;
  const u16* pre = which == 0 ? pq : which == 1 ? pk : pv;
  const float* cw = which == 0 ? cqw : which == 1 ? ckw : cvw;
  const float* cb = which == 0 ? cqb : which == 1 ? ckb : cvb;
  u16* out = which == 0 ? oq : which == 1 ? ok : ov;
  const int do_l2 = (which < 2);

  const int bt = blockIdx.x;
  const int b = bt / TT, t = bt % TT;
  const int tid = threadIdx.x;
  const int c4 = tid * 4;
  float xt[4][4];
#pragma unroll
  for (int j = 0; j < 4; ++j) {
    int ts = t - 3 + j;
    if (ts >= 0) {
      ushort4 u = *(const ushort4*)&pre[(long)(b * TT + ts) * INNER + c4];
      xt[j][0] = b2f(u.x); xt[j][1] = b2f(u.y);
      xt[j][2] = b2f(u.z); xt[j][3] = b2f(u.w);
    } else {
      xt[j][0] = xt[j][1] = xt[j][2] = xt[j][3] = 0.f;
    }
  }
  float4 bias4 = *(const float4*)&cb[c4];
  const float* bp = (const float*)&bias4;
  float y[4];
#pragma unroll
  for (int ci = 0; ci < 4; ++ci) {
    float4 w4 = *(const float4*)&cw[(c4 + ci) * 4];
    float acc = bp[ci];
    acc += w4.x * xt[0][ci];
    acc += w4.y * xt[1][ci];
    acc += w4.z * xt[2][ci];
    acc += w4.w * xt[3][ci];
    y[ci] = acc / (1.f + expf(-acc));   // SiLU
  }
  if (do_l2) {
    float ssq = y[0]*y[0] + y[1]*y[1] + y[2]*y[2] + y[3]*y[3];
    ssq += __shfl_xor(ssq, 1);
    ssq += __shfl_xor(ssq, 2);
    ssq += __shfl_xor(ssq, 4);
    ssq += __shfl_xor(ssq, 8);   // 16 threads = one head (64 channels)
    float r = rsqrtf(ssq + EPSF);
    y[0] *= r; y[1] *= r; y[2] *= r; y[3] *= r;
  }
  ushort4 res;
  res.x = f2bf(y[0]); res.y = f2bf(y[1]);
  res.z = f2bf(y[2]); res.w = f2bf(y[3]);
  *(ushort4*)&out[(long)bt * INNER + c4] = res;
}

// ---------------------------------------------------------------------------
// beta = sigmoid(x@wb.T); ldec = -exp(A_log)*softplus(x@wa.T + dt_bias)
// ---------------------------------------------------------------------------
__global__ __launch_bounds__(256) void proj_ab3(
    const float* __restrict__ x, const float* __restrict__ wa,
    const float* __restrict__ wb, const float* __restrict__ dt_bias,
    const float* __restrict__ A_log, float* __restrict__ beta,
    float* __restrict__ ldec) {
  const int m0 = blockIdx.x * 8;
  const int tid = threadIdx.x;
  __shared__ float xs[8][132];
  __shared__ float ws[32][132];
  const int row = tid >> 5;
  const int col = tid & 31;
  float a0 = 0.f, a1 = 0.f, a2 = 0.f, a3 = 0.f;
  const int sxr = tid >> 5, sxc = (tid & 31) * 4;
  for (int k0 = 0; k0 < CC; k0 += 128) {
    __syncthreads();
    *(float4*)&xs[sxr][sxc] = *(const float4*)&x[(long)(m0 + sxr) * CC + k0 + sxc];
#pragma unroll
    for (int p = 0; p < 4; ++p) {
      int idx = tid + p * 256;
      int wr = idx >> 5, wc4 = (idx & 31) * 4;
      const float* wsrc = (wr < 16) ? &wa[(long)wr * CC] : &wb[(long)(wr - 16) * CC];
      *(float4*)&ws[wr][wc4] = *(const float4*)&wsrc[k0 + wc4];
    }
    __syncthreads();
#pragma unroll
    for (int kk = 0; kk < 128; kk += 16) {
      float4 x0 = *(const float4*)&xs[row][kk + 0];
      float4 w0 = *(const float4*)&ws[col][kk + 0];
      float4 x1 = *(const float4*)&xs[row][kk + 4];
      float4 w1 = *(const float4*)&ws[col][kk + 4];
      float4 x2 = *(const float4*)&xs[row][kk + 8];
      float4 w2 = *(const float4*)&ws[col][kk + 8];
      float4 x3 = *(const float4*)&xs[row][kk + 12];
      float4 w3 = *(const float4*)&ws[col][kk + 12];
      a0 += x0.x * w0.x + x0.y * w0.y + x0.z * w0.z + x0.w * w0.w;
      a1 += x1.x * w1.x + x1.y * w1.y + x1.z * w1.z + x1.w * w1.w;
      a2 += x2.x * w2.x + x2.y * w2.y + x2.z * w2.z + x2.w * w2.w;
      a3 += x3.x * w3.x + x3.y * w3.y + x3.z * w3.z + x3.w * w3.w;
    }
  }
  float acc = (a0 + a1) + (a2 + a3);
  const int m = m0 + row;
  if (col < 16) {
    float a = acc + dt_bias[col];
    float sp = fmaxf(a, 0.f) + log1pf(expf(-fabsf(a)));
    ldec[(long)m * HH + col] = -expf(A_log[col]) * sp;
  } else {
    beta[(long)m * HH + (col - 16)] = 1.f / (1.f + expf(-acc));
  }
}

// ---------------------------------------------------------------------------
// Per-chunk parallel precompute. grid = NCHK (1024), 256 threads.
// Forward substitution BLOCKED (BS=8): 24 barriers, bit-identical order.
// ---------------------------------------------------------------------------
__global__ __launch_bounds__(256) void gdn_prep(
    const u16* __restrict__ q, const u16* __restrict__ k,
    const u16* __restrict__ v, const float* __restrict__ beta,
    const float* __restrict__ ldec,
    u16* __restrict__ U0g, u16* __restrict__ Wtg, u16* __restrict__ Btg,
    u16* __restrict__ Qhtg, float* __restrict__ Mtg, float* __restrict__ bvg) {
  const int blk = blockIdx.x;
  const int bh = blk / NC, c = blk % NC;
  const int b = bh >> 4, h = bh & 15;
  const int tid = threadIdx.x;
  const int tx = tid & 15, ty = tid >> 4;
  __shared__ float P0[64][68];   // kst[d][t] -> later U0[t][e]
  __shared__ float P1[64][68];   // qst[d][t] -> later W[t][d]
  __shared__ float Ab[64][68];   // A[t][s] -> later Kh[t][d]
  __shared__ float lam[64], lamx[64], lbet[64];
  const long gb = ((long)(b * TT + c * CH) * HH + h) * DD;

  // stage k,q transposed (bf16 -> fp32)
  {
    const int e4 = (tid & 15) * 4;
    const int t0 = tid >> 4;
#pragma unroll
    for (int p = 0; p < 4; ++p) {
      int t = t0 + p * 16;
      ushort4 kv = *(const ushort4*)&k[gb + (long)t * (HH * DD) + e4];
      ushort4 qv = *(const ushort4*)&q[gb + (long)t * (HH * DD) + e4];
      P0[e4 + 0][t] = b2f(kv.x); P0[e4 + 1][t] = b2f(kv.y);
      P0[e4 + 2][t] = b2f(kv.z); P0[e4 + 3][t] = b2f(kv.w);
      P1[e4 + 0][t] = b2f(qv.x); P1[e4 + 1][t] = b2f(qv.y);
      P1[e4 + 2][t] = b2f(qv.z); P1[e4 + 3][t] = b2f(qv.w);
    }
  }
  float ldv = 0.f, bv_ = 0.f;
  if (tid < 64) {
    ldv = ldec[(long)(b * TT + c * CH + tid) * HH + h];
    bv_ = beta[(long)(b * TT + c * CH + tid) * HH + h];
    lam[tid] = ldv;
  }
  __syncthreads();
  float lsum = 0.f;
  if (tid < 64) {
    for (int s = 0; s <= tid; ++s) lsum += lam[s];
  }
  __syncthreads();
  if (tid < 64) {
    lam[tid] = lsum;
    lamx[tid] = lsum - ldv;
    lbet[tid] = bv_;
  }
  __syncthreads();

  // G[r][c]=k_r.k_c ; Pm[r][c]=k_r.q_c
  float accg[4][4] = {}, accp[4][4] = {};
  for (int d = 0; d < 64; ++d) {
    float4 a4 = *(const float4*)&P0[d][ty * 4];
    float4 bk = *(const float4*)&P0[d][tx * 4];
    float4 bq = *(const float4*)&P1[d][tx * 4];
    float ar[4] = {a4.x, a4.y, a4.z, a4.w};
    float bkr[4] = {bk.x, bk.y, bk.z, bk.w};
    float bqr[4] = {bq.x, bq.y, bq.z, bq.w};
#pragma unroll
    for (int i = 0; i < 4; ++i)
#pragma unroll
      for (int j = 0; j < 4; ++j) {
        accg[i][j] += ar[i] * bkr[j];
        accp[i][j] += ar[i] * bqr[j];
      }
  }
#pragma unroll
  for (int i = 0; i < 4; ++i) {
    int t = ty * 4 + i;
    float bt_ = lbet[t], lx = lamx[t];
#pragma unroll
    for (int j = 0; j < 4; ++j) {
      int s = tx * 4 + j;
      Ab[t][s] = (s < t) ? bt_ * expf(lx - lam[s]) * accg[i][j] : 0.f;
    }
  }
  // Bt[s][t] bf16
  {
    u16* btp = Btg + (long)blk * (CH * CH);
#pragma unroll
    for (int i = 0; i < 4; ++i) {
      int s = ty * 4 + i;
      float ls = lam[s];
      int t0 = tx * 4;
      ushort4 w;
      w.x = f2bf((s <= t0 + 0) ? expf(lam[t0 + 0] - ls) * accp[i][0] : 0.f);
      w.y = f2bf((s <= t0 + 1) ? expf(lam[t0 + 1] - ls) * accp[i][1] : 0.f);
      w.z = f2bf((s <= t0 + 2) ? expf(lam[t0 + 2] - ls) * accp[i][2] : 0.f);
      w.w = f2bf((s <= t0 + 3) ? expf(lam[t0 + 3] - ls) * accp[i][3] : 0.f);
      *(ushort4*)&btp[s * 64 + t0] = w;
    }
  }
  // Qht[d][t] bf16
  {
    u16* qhp = Qhtg + (long)blk * (DD * CH);
    const int t4 = (tid & 15) * 4;
    const int d0 = tid >> 4;
#pragma unroll
    for (int p = 0; p < 4; ++p) {
      int d = d0 + p * 16;
      float4 qv = *(const float4*)&P1[d][t4];
      ushort4 qw;
      qw.x = f2bf(qv.x * expf(lam[t4 + 0]));
      qw.y = f2bf(qv.y * expf(lam[t4 + 1]));
      qw.z = f2bf(qv.z * expf(lam[t4 + 2]));
      qw.w = f2bf(qv.w * expf(lam[t4 + 3]));
      *(ushort4*)&qhp[d * 64 + t4] = qw;
    }
  }
  __syncthreads();
  // re-init: P0[t][e] = beta_t v ; P1[t][d] = beta_t exp(lamx_t) k
  {
    const int e4 = (tid & 15) * 4;
    const int t0 = tid >> 4;
#pragma unroll
    for (int p = 0; p < 4; ++p) {
      int t = t0 + p * 16;
      float bt_ = lbet[t], cx = bt_ * expf(lamx[t]);
      ushort4 vv4 = *(const ushort4*)&v[gb + (long)t * (HH * DD) + e4];
      ushort4 kv4 = *(const ushort4*)&k[gb + (long)t * (HH * DD) + e4];
      float4 vv = make_float4(b2f(vv4.x) * bt_, b2f(vv4.y) * bt_,
                              b2f(vv4.z) * bt_, b2f(vv4.w) * bt_);
      float4 kv = make_float4(b2f(kv4.x) * cx, b2f(kv4.y) * cx,
                              b2f(kv4.z) * cx, b2f(kv4.w) * cx);
      *(float4*)&P0[t][e4] = vv;
      *(float4*)&P1[t][e4] = kv;
    }
  }
  __syncthreads();
  // BLOCKED forward substitution on (I+A): both P0,P1
  {
    const int i = tid >> 5;
    const int j4 = (tid & 31) * 4;
    float* Pj = (j4 < 64) ? (&P0[0][0] + j4) : (&P1[0][0] + (j4 - 64));
#pragma unroll
    for (int base = 0; base < 64; base += 8) {
      const int r = base + i;
      float4 acc = *(const float4*)&Pj[r * 68];
      for (int t = 0; t < base; ++t) {
        float a = Ab[r][t];
        float4 ut = *(const float4*)&Pj[t * 68];
        acc.x -= a * ut.x; acc.y -= a * ut.y;
        acc.z -= a * ut.z; acc.w -= a * ut.w;
      }
      *(float4*)&Pj[r * 68] = acc;
      __syncthreads();
      float4 val[8];
#pragma unroll
      for (int t = 0; t < 8; ++t) {
        float4 vt = *(const float4*)&Pj[(base + t) * 68];
#pragma unroll
        for (int m = 0; m < t; ++m) {
          float a = Ab[base + t][base + m];
          vt.x -= a * val[m].x; vt.y -= a * val[m].y;
          vt.z -= a * val[m].z; vt.w -= a * val[m].w;
        }
        val[t] = vt;
      }
      float4 fin = val[0];
#pragma unroll
      for (int t = 1; t < 8; ++t) if (i == t) fin = val[t];
      __syncthreads();
      *(float4*)&Pj[r * 68] = fin;
      __syncthreads();
    }
  }
  // write U0 (bf16) and Wt (bf16, transposed); stage Kh into Ab
  {
    u16* u0p = U0g + (long)blk * (CH * DD);
    const int e4 = (tid & 15) * 4;
    const int t0 = tid >> 4;
    float lamL = lam[63];
#pragma unroll
    for (int p = 0; p < 4; ++p) {
      int t = t0 + p * 16;
      float4 u4 = *(const float4*)&P0[t][e4];
      ushort4 uw;
      uw.x = f2bf(u4.x); uw.y = f2bf(u4.y);
      uw.z = f2bf(u4.z); uw.w = f2bf(u4.w);
      *(ushort4*)&u0p[t * 64 + e4] = uw;
      float cf = expf(lamL - lam[t]);
      ushort4 kv4 = *(const ushort4*)&k[gb + (long)t * (HH * DD) + e4];
      *(float4*)&Ab[t][e4] = make_float4(b2f(kv4.x) * cf, b2f(kv4.y) * cf,
                                         b2f(kv4.z) * cf, b2f(kv4.w) * cf);
    }
    u16* wtp = Wtg + (long)blk * (DD * CH);
    const int t = tid & 63;
    const int d0 = tid >> 6;
#pragma unroll
    for (int p = 0; p < 16; ++p) {
      int d = d0 + p * 4;
      wtp[d * 64 + t] = f2bf(P1[t][d]);
    }
  }
  __syncthreads();
  // M[d][s] = gL*I - sum_t Kh[t][d]*W[t][s] ; b[d][e] = sum_t Kh[t][d]*U0[t][e]
  {
    float accm[4][4] = {}, accb[4][4] = {};
    for (int t = 0; t < 64; ++t) {
      float4 ka = *(const float4*)&Ab[t][ty * 4];
      float4 wc_ = *(const float4*)&P1[t][tx * 4];
      float4 uv = *(const float4*)&P0[t][tx * 4];
      float kar[4] = {ka.x, ka.y, ka.z, ka.w};
      float wcr[4] = {wc_.x, wc_.y, wc_.z, wc_.w};
      float ucr[4] = {uv.x, uv.y, uv.z, uv.w};
#pragma unroll
      for (int i = 0; i < 4; ++i)
#pragma unroll
        for (int j = 0; j < 4; ++j) {
          accm[i][j] += kar[i] * wcr[j];
          accb[i][j] += kar[i] * ucr[j];
        }
    }
    float gLv = expf(lam[63]);
    float* mp = Mtg + (long)blk * (DD * DD);
    float* bp = bvg + (long)blk * (DD * DD);
#pragma unroll
    for (int i = 0; i < 4; ++i) {
      int rr = ty * 4 + i;    // d
      float4 mv, b4;
      mv.x = ((rr == tx * 4 + 0) ? gLv : 0.f) - accm[i][0];
      mv.y = ((rr == tx * 4 + 1) ? gLv : 0.f) - accm[i][1];
      mv.z = ((rr == tx * 4 + 2) ? gLv : 0.f) - accm[i][2];
      mv.w = ((rr == tx * 4 + 3) ? gLv : 0.f) - accm[i][3];
      *(float4*)&mp[rr * 64 + tx * 4] = mv;   // [d][s]
      b4.x = accb[i][0]; b4.y = accb[i][1];
      b4.z = accb[i][2]; b4.w = accb[i][3];
      *(float4*)&bp[rr * 64 + tx * 4] = b4;   // [d][e]
    }
  }
}

// ---------------------------------------------------------------------------
// Sequential pass: S_{c+1} = M_c S_c + b_c, e-split 8-way (256 blocks).
// ---------------------------------------------------------------------------
__global__ __launch_bounds__(256) void gdn_seq4(
    const float* __restrict__ Mtg, const float* __restrict__ bvg,
    float* __restrict__ Sall) {
  const int bh = blockIdx.x & 31;         // L2-sharing swizzle
  const int esec = blockIdx.x >> 5;       // 0..7
  const int tid = threadIdx.x;
  const int d = tid & 63;
  const int ep = (tid >> 6) * 2;          // 0,2,4,6 within 8-col slice
  const int eo = esec * 8 + ep;
  __shared__ float Ms[64][68];            // [d][s]
  __shared__ float Ss[8][68];             // [e][s]
  float S0 = 0.f, S1 = 0.f;
  const int sr = tid >> 2, sq = (tid & 3) * 16;
  float4 mreg[4];
  {
    const float* mt0 = Mtg + (long)bh * NC * 4096;
#pragma unroll
    for (int p = 0; p < 4; ++p)
      mreg[p] = *(const float4*)&mt0[sr * 64 + sq + p * 4];
  }
  for (int c = 0; c < NC; ++c) {
    const long cb = (long)bh * NC + c;
    float2 bv = *(const float2*)&bvg[cb * 4096 + d * 64 + eo];
    __syncthreads();
#pragma unroll
    for (int p = 0; p < 4; ++p)
      *(float4*)&Ms[sr][sq + p * 4] = mreg[p];
    *(float2*)&Sall[cb * 4096 + d * 64 + eo] = make_float2(S0, S1);
    Ss[ep][d] = S0; Ss[ep + 1][d] = S1;
    __syncthreads();
    if (c + 1 < NC) {
      const float* mtn = Mtg + (cb + 1) * 4096;
#pragma unroll
      for (int p = 0; p < 4; ++p)
        mreg[p] = *(const float4*)&mtn[sr * 64 + sq + p * 4];
    }
    float a0 = bv.x, a1 = bv.y, b0 = 0.f, b1 = 0.f;
#pragma unroll
    for (int sg = 0; sg < 8; ++sg) {
      float4 m4 = *(const float4*)&Ms[d][sg * 4];
      float4 s0 = *(const float4*)&Ss[ep][sg * 4];
      float4 s1 = *(const float4*)&Ss[ep + 1][sg * 4];
      a0 += m4.x * s0.x + m4.y * s0.y + m4.z * s0.z + m4.w * s0.w;
      a1 += m4.x * s1.x + m4.y * s1.y + m4.z * s1.z + m4.w * s1.w;
    }
#pragma unroll
    for (int sg = 8; sg < 16; ++sg) {
      float4 m4 = *(const float4*)&Ms[d][sg * 4];
      float4 s0 = *(const float4*)&Ss[ep][sg * 4];
      float4 s1 = *(const float4*)&Ss[ep + 1][sg * 4];
      b0 += m4.x * s0.x + m4.y * s0.y + m4.z * s0.z + m4.w * s0.w;
      b1 += m4.x * s1.x + m4.y * s1.y + m4.z * s1.z + m4.w * s1.w;
    }
    S0 = a0 + b0; S1 = a1 + b1;
  }
}

// ---------------------------------------------------------------------------
// Fully parallel per-chunk output: u = U0 - W.S ; o = B.u + Qh.S
// ---------------------------------------------------------------------------
__global__ __launch_bounds__(256) void gdn_out(
    const u16* __restrict__ U0g, const u16* __restrict__ Wtg,
    const u16* __restrict__ Btg, const u16* __restrict__ Qhtg,
    const float* __restrict__ Sall, u16* __restrict__ o) {
  const int blk = blockIdx.x;
  const int bh = blk / NC, c = blk % NC;
  const int b = bh >> 4, h = bh & 15;
  const int tid = threadIdx.x;
  const int tx = tid & 15, ty = tid >> 4;
  __shared__ float S[64][64];
  __shared__ float ub[64][64];
  __shared__ float op[64][64];
  const int e4 = (tid & 15) * 4;
  const int t0s = tid >> 4;
  {
    const int r = tid >> 2, qq = (tid & 3) * 16;
#pragma unroll
    for (int p = 0; p < 4; ++p)
      *(float4*)&S[r][qq + p * 4] =
          *(const float4*)&Sall[(long)blk * 4096 + r * 64 + qq + p * 4];
  }
#pragma unroll
  for (int p = 0; p < 4; ++p) {
    int t = t0s + p * 16;
    ushort4 w4 = *(const ushort4*)&Wtg[(long)blk * 4096 + t * 64 + e4];
    *(float4*)&op[t][e4] = make_float4(b2f(w4.x), b2f(w4.y), b2f(w4.z), b2f(w4.w));
  }
  __syncthreads();
  float acc[4][4];
#pragma unroll
  for (int i = 0; i < 4; ++i) {
    ushort4 u4 = *(const ushort4*)&U0g[(long)blk * 4096 + (ty * 4 + i) * 64 + tx * 4];
    acc[i][0] = b2f(u4.x); acc[i][1] = b2f(u4.y);
    acc[i][2] = b2f(u4.z); acc[i][3] = b2f(u4.w);
  }
  for (int d = 0; d < 64; ++d) {
    float4 a4 = *(const float4*)&op[d][ty * 4];
    float4 b4 = *(const float4*)&S[d][tx * 4];
    float ar[4] = {a4.x, a4.y, a4.z, a4.w};
    float br[4] = {b4.x, b4.y, b4.z, b4.w};
#pragma unroll
    for (int i = 0; i < 4; ++i)
#pragma unroll
      for (int j = 0; j < 4; ++j) acc[i][j] -= ar[i] * br[j];
  }
#pragma unroll
  for (int i = 0; i < 4; ++i)
    *(float4*)&ub[ty * 4 + i][tx * 4] =
        make_float4(acc[i][0], acc[i][1], acc[i][2], acc[i][3]);
  __syncthreads();
#pragma unroll
  for (int p = 0; p < 4; ++p) {
    int t = t0s + p * 16;
    ushort4 w4 = *(const ushort4*)&Btg[(long)blk * 4096 + t * 64 + e4];
    *(float4*)&op[t][e4] = make_float4(b2f(w4.x), b2f(w4.y), b2f(w4.z), b2f(w4.w));
  }
  __syncthreads();
  float acco[4][4] = {};
  for (int s = 0; s < 64; ++s) {
    float4 a4 = *(const float4*)&op[s][ty * 4];
    float4 b4 = *(const float4*)&ub[s][tx * 4];
    float ar[4] = {a4.x, a4.y, a4.z, a4.w};
    float br[4] = {b4.x, b4.y, b4.z, b4.w};
#pragma unroll
    for (int i = 0; i < 4; ++i)
#pragma unroll
      for (int j = 0; j < 4; ++j) acco[i][j] += ar[i] * br[j];
  }
  __syncthreads();
#pragma unroll
  for (int p = 0; p < 4; ++p) {
    int t = t0s + p * 16;
    ushort4 w4 = *(const ushort4*)&Qhtg[(long)blk * 4096 + t * 64 + e4];
    *(float4*)&op[t][e4] = make_float4(b2f(w4.x), b2f(w4.y), b2f(w4.z), b2f(w4.w));
  }
  __syncthreads();
  for (int d = 0; d < 64; ++d) {
    float4 a4 = *(const float4*)&op[d][ty * 4];
    float4 b4 = *(const float4*)&S[d][tx * 4];
    float ar[4] = {a4.x, a4.y, a4.z, a4.w};
    float br[4] = {b4.x, b4.y, b4.z, b4.w};
#pragma unroll
    for (int i = 0; i < 4; ++i)
#pragma unroll
      for (int j = 0; j < 4; ++j) acco[i][j] += ar[i] * br[j];
  }
#pragma unroll
  for (int i = 0; i < 4; ++i) {
    int t = ty * 4 + i;
    ushort4 ow;
    ow.x = f2bf(acco[i][0]); ow.y = f2bf(acco[i][1]);
    ow.z = f2bf(acco[i][2]); ow.w = f2bf(acco[i][3]);
    *(ushort4*)&o[((long)(b * TT + c * CH + t) * HH + h) * DD + tx * 4] = ow;
  }
}

// ---------------------------------------------------------------------------
// gated = rms_norm(o) * o_norm_scale * silu(g), bf16 in/out.
// ---------------------------------------------------------------------------
__global__ __launch_bounds__(256) void norm_gate(
    const u16* __restrict__ o, const u16* __restrict__ g,
    const float* __restrict__ scale, u16* __restrict__ outb) {
  const int bt = blockIdx.x;
  const int tid = threadIdx.x;
  const int c4 = tid * 4;
  ushort4 o4u = *(const ushort4*)&o[(long)bt * INNER + c4];
  float4 o4 = make_float4(b2f(o4u.x), b2f(o4u.y), b2f(o4u.z), b2f(o4u.w));
  float ssq = o4.x * o4.x + o4.y * o4.y + o4.z * o4.z + o4.w * o4.w;
  ssq += __shfl_xor(ssq, 1);
  ssq += __shfl_xor(ssq, 2);
  ssq += __shfl_xor(ssq, 4);
  ssq += __shfl_xor(ssq, 8);
  float r = rsqrtf(ssq * (1.f / 64.f) + EPSF);
  float4 sc = *(const float4*)&scale[c4 & 63];
  ushort4 g4u = *(const ushort4*)&g[(long)bt * INNER + c4];
  float4 g4 = make_float4(b2f(g4u.x), b2f(g4u.y), b2f(g4u.z), b2f(g4u.w));
  ushort4 res;
  res.x = f2bf(o4.x * r * sc.x * (g4.x / (1.f + expf(-g4.x))));
  res.y = f2bf(o4.y * r * sc.y * (g4.y / (1.f + expf(-g4.y))));
  res.z = f2bf(o4.z * r * sc.z * (g4.z / (1.f + expf(-g4.z))));
  res.w = f2bf(o4.w * r * sc.w * (g4.w / (1.f + expf(-g4.w))));
  *(ushort4*)&outb[(long)bt * INNER + c4] = res;
}

// ---------------------------------------------------------------------------
extern "C" void kernel_launch(void* const* d_in, const int* in_sizes, int n_in,
                              void* d_out, int out_size, void* d_ws,
                              size_t ws_size, hipStream_t stream) {
  const float* x      = (const float*)d_in[0];
  const float* wq     = (const float*)d_in[1];
  const float* wk     = (const float*)d_in[2];
  const float* wv     = (const float*)d_in[3];
  const float* wg     = (const float*)d_in[4];
  const float* wo     = (const float*)d_in[5];
  const float* wa     = (const float*)d_in[6];
  const float* wb     = (const float*)d_in[7];
  const float* cqw    = (const float*)d_in[8];
  const float* cqb    = (const float*)d_in[9];
  const float* ckw    = (const float*)d_in[10];
  const float* ckb    = (const float*)d_in[11];
  const float* cvw    = (const float*)d_in[12];
  const float* cvb    = (const float*)d_in[13];
  const float* A_log  = (const float*)d_in[14];
  const float* dtb    = (const float*)d_in[15];
  const float* oscale = (const float*)d_in[16];
  float* out = (float*)d_out;

  u16 *pqb, *pkb, *pvb, *qb, *kb, *vb, *gb, *ob;
  u16 *xb, *wbb, *wob, *gatedb, *U0, *Wt, *Bt, *Qht;
  float *beta, *ldec, *Mc, *bc, *Sall;
  hipGetSymbolAddress((void**)&pqb,   HIP_SYMBOL(g_pqb));
  hipGetSymbolAddress((void**)&pkb,   HIP_SYMBOL(g_pkb));
  hipGetSymbolAddress((void**)&pvb,   HIP_SYMBOL(g_pvb));
  hipGetSymbolAddress((void**)&qb,    HIP_SYMBOL(g_qb));
  hipGetSymbolAddress((void**)&kb,    HIP_SYMBOL(g_kb));
  hipGetSymbolAddress((void**)&vb,    HIP_SYMBOL(g_vb));
  hipGetSymbolAddress((void**)&gb,    HIP_SYMBOL(g_gb));
  hipGetSymbolAddress((void**)&ob,    HIP_SYMBOL(g_ob));
  hipGetSymbolAddress((void**)&beta,  HIP_SYMBOL(g_beta));
  hipGetSymbolAddress((void**)&ldec,  HIP_SYMBOL(g_ldec));
  hipGetSymbolAddress((void**)&xb,    HIP_SYMBOL(g_xb));
  hipGetSymbolAddress((void**)&wbb,   HIP_SYMBOL(g_wbb));
  hipGetSymbolAddress((void**)&wob,   HIP_SYMBOL(g_wob));
  hipGetSymbolAddress((void**)&gatedb,HIP_SYMBOL(g_gatedb));
  hipGetSymbolAddress((void**)&U0,    HIP_SYMBOL(g_U0));
  hipGetSymbolAddress((void**)&Wt,    HIP_SYMBOL(g_Wt));
  hipGetSymbolAddress((void**)&Bt,    HIP_SYMBOL(g_Bt));
  hipGetSymbolAddress((void**)&Qht,   HIP_SYMBOL(g_Qht));
  hipGetSymbolAddress((void**)&Mc,    HIP_SYMBOL(g_Mc));
  hipGetSymbolAddress((void**)&bc,    HIP_SYMBOL(g_bc));
  hipGetSymbolAddress((void**)&Sall,  HIP_SYMBOL(g_Sall));

  cast_all<<<9216, 256, 0, stream>>>(x, wq, wk, wv, wg, wo, xb, wbb, wob);

  // fused QKVG projection -> bf16 outputs (BK=64, XCD serpentine)
  bgemm4<u16, 32><<<1024, 256, 0, stream>>>(xb, wbb, pqb, pkb, pvb, gb);

  conv3<<<dim3(BT, 3), 256, 0, stream>>>(pqb, pkb, pvb,
                                         cqw, cqb, ckw, ckb, cvw, cvb,
                                         qb, kb, vb);
  proj_ab3<<<BT / 8, 256, 0, stream>>>(x, wa, wb, dtb, A_log, beta, ldec);

  gdn_prep<<<NCHK, 256, 0, stream>>>(qb, kb, vb, beta, ldec,
                                     U0, Wt, Bt, Qht, Mc, bc);
  gdn_seq4<<<NBH * 8, 256, 0, stream>>>(Mc, bc, Sall);
  gdn_out<<<NCHK, 256, 0, stream>>>(U0, Wt, Bt, Qht, Sall, ob);

  norm_gate<<<BT, 256, 0, stream>>>(ob, gb, oscale, gatedb);

  // final projection: out = gated_bf16 @ wo^T (fp32 out, 256 blocks)
  bgemm4<float, 8><<<256, 256, 0, stream>>>(gatedb, wob, out, out, out, out);
}

// Round 17
// 294.756 us; speedup vs baseline: 1.0125x; 1.0125x over previous
//
#include <hip/hip_runtime.h>
#include <math.h>

#define BB 2
#define TT 2048
#define CC 1024
#define HH 16
#define DD 64
#define INNER 1024
#define BT (BB*TT)   /* 4096 */
#define EPSF 1e-6f
#define CH 64
#define NC (TT/CH)        /* 32 */
#define NBH (BB*HH)       /* 32 */
#define NCHK (NBH*NC)     /* 1024 */

typedef unsigned short u16;
typedef __bf16 bf16x8 __attribute__((ext_vector_type(8)));
typedef float f32x4 __attribute__((ext_vector_type(4)));

__device__ inline u16 f2bf(float f) {   // RNE float->bf16
  unsigned u = __builtin_bit_cast(unsigned, f);
  return (u16)((u + 0x7fffu + ((u >> 16) & 1u)) >> 16);
}
__device__ inline float b2f(u16 b) {
  unsigned u = ((unsigned)b) << 16;
  return __builtin_bit_cast(float, u);
}
__device__ inline void gll16(const u16* g, u16* l) {
  __builtin_amdgcn_global_load_lds(
      (const __attribute__((address_space(1))) void*)g,
      (__attribute__((address_space(3))) void*)l, 16, 0, 0);
}

// Static device scratch (fully overwritten every call; deterministic).
__device__ u16   g_pqb[BT * INNER];      // pre_q bf16
__device__ u16   g_pkb[BT * INNER];      // pre_k
__device__ u16   g_pvb[BT * INNER];      // pre_v
__device__ u16   g_qb [BT * INNER];      // q bf16 (post conv+l2)
__device__ u16   g_kb [BT * INNER];
__device__ u16   g_vb [BT * INNER];
__device__ u16   g_gb [BT * INNER];      // g projection bf16
__device__ u16   g_ob [BT * INNER];      // o bf16
__device__ float g_beta[BT * HH];
__device__ float g_ldec[BT * HH];
__device__ u16   g_xb[BT * CC];          // x in bf16
__device__ u16   g_wbb[4 * INNER * CC];  // wq|wk|wv|wg in bf16
__device__ u16   g_wob[CC * INNER];      // wo in bf16
__device__ u16   g_gatedb[BT * INNER];   // gated activations bf16
// per-chunk tensors: output path bf16, state path fp32
__device__ u16   g_U0 [NCHK * CH * DD];
__device__ u16   g_Wt [NCHK * DD * CH];
__device__ u16   g_Bt [NCHK * CH * CH];
__device__ u16   g_Qht[NCHK * DD * CH];
__device__ float g_Mc [NCHK * DD * DD];  // M[d][s] row-major (d = row)
__device__ float g_bc [NCHK * DD * DD];  // b[d][e]
__device__ float g_Sall[NCHK * DD * DD]; // chunk-start states [d][e]

// ---------------------------------------------------------------------------
// Fused cast of x and all weights to bf16.
// ---------------------------------------------------------------------------
__global__ __launch_bounds__(256) void cast_all(
    const float* __restrict__ x, const float* __restrict__ wq,
    const float* __restrict__ wk, const float* __restrict__ wv,
    const float* __restrict__ wg, const float* __restrict__ wo,
    u16* __restrict__ xb, u16* __restrict__ wb, u16* __restrict__ wob) {
  long i = ((long)blockIdx.x * 256 + threadIdx.x) * 4;
  const float* src;
  u16* dst;
  if (i < 4194304)      { src = x  + i;             dst = xb + i; }
  else if (i < 5242880) { src = wq + (i - 4194304); dst = wb + (i - 4194304); }
  else if (i < 6291456) { src = wk + (i - 5242880); dst = wb + (i - 4194304); }
  else if (i < 7340032) { src = wv + (i - 6291456); dst = wb + (i - 4194304); }
  else if (i < 8388608) { src = wg + (i - 7340032); dst = wb + (i - 4194304); }
  else                  { src = wo + (i - 8388608); dst = wob + (i - 8388608); }
  float4 v = *(const float4*)src;
  ushort4 o;
  o.x = f2bf(v.x); o.y = f2bf(v.y); o.z = f2bf(v.z); o.w = f2bf(v.w);
  *(ushort4*)dst = o;
}

// ---------------------------------------------------------------------------
// bf16 MFMA GEMM: BK=64, source-swizzled LDS (0 bank conflicts), XCD
// serpentine region remap. C[m,n] = sum_k A[m,k]*B[n,k], K=1024, 128x128.
// ---------------------------------------------------------------------------
template <typename OutT, int NBN>
__global__ __launch_bounds__(256) void bgemm4(
    const u16* __restrict__ A, const u16* __restrict__ B,
    OutT* __restrict__ c0, OutT* __restrict__ c1,
    OutT* __restrict__ c2, OutT* __restrict__ c3) {
  __shared__ u16 lA[128 * 64];
  __shared__ u16 lB[128 * 64];
  const int tid = threadIdx.x;
  const int bid = blockIdx.x;
  int bm, bn;
  if constexpr (NBN == 32) {
    const int xcd = bid & 7;
    const int idx = bid >> 3;          // 0..127
    const int in_ = idx >> 4;          // 0..7
    int im = idx & 15;
    im = (in_ & 1) ? (15 - im) : im;
    bm = ((xcd >> 2) * 16 + im) * 128;
    bn = ((xcd & 3) * 8 + in_) * 128;
  } else {
    const int xcd = bid & 7;
    const int idx = bid >> 3;          // 0..31
    const int in_ = idx >> 2;          // 0..7
    int im = idx & 3;
    im = (in_ & 1) ? (3 - im) : im;
    bm = (xcd * 4 + im) * 128;
    bn = in_ * 128;
  }
  const int lane = tid & 63;
  const int wave = tid >> 6;
  const int wr = (wave >> 1) * 64, wc = (wave & 1) * 64;
  const int lr = lane & 15;
  const int kq = lane >> 4;            // 0..3
  const int srow0 = tid >> 3;          // 0..31
  const int gcol = ((tid & 7) ^ (srow0 & 7)) * 8;
  const u16* gA0 = &A[(long)(bm + srow0) * CC + gcol];
  const u16* gB0 = &B[(long)(bn + srow0) * CC + gcol];
  u16* lA0 = &lA[tid * 8];
  u16* lB0 = &lB[tid * 8];
  f32x4 acc[4][4] = {};

  for (int k0 = 0; k0 < CC; k0 += 64) {
    __syncthreads();                  // protect prev-iter LDS reads
#pragma unroll
    for (int p = 0; p < 4; ++p) {
      gll16(gA0 + (long)p * 32 * CC + k0, lA0 + p * 2048);
      gll16(gB0 + (long)p * 32 * CC + k0, lB0 + p * 2048);
    }
    __syncthreads();                  // drains vmcnt before reads
#pragma unroll
    for (int ks = 0; ks < 2; ++ks) {
      const int sl = ((ks * 4 + kq) ^ (lr & 7)) * 8;
      bf16x8 af[4], bf_[4];
#pragma unroll
      for (int m = 0; m < 4; ++m)
        af[m] = __builtin_bit_cast(bf16x8,
            *(const uint4*)&lA[(wr + m * 16 + lr) * 64 + sl]);
#pragma unroll
      for (int n = 0; n < 4; ++n)
        bf_[n] = __builtin_bit_cast(bf16x8,
            *(const uint4*)&lB[(wc + n * 16 + lr) * 64 + sl]);
#pragma unroll
      for (int m = 0; m < 4; ++m)
#pragma unroll
        for (int n = 0; n < 4; ++n)
          acc[m][n] = __builtin_amdgcn_mfma_f32_16x16x32_bf16(
              af[m], bf_[n], acc[m][n], 0, 0, 0);
    }
  }
  OutT* cp = (bn < 1024) ? c0 : (bn < 2048) ? c1 : (bn < 3072) ? c2 : c3;
  const int ccol0 = (bn & 1023) + wc;
  const int crow0 = bm + wr + kq * 4;
#pragma unroll
  for (int m = 0; m < 4; ++m)
#pragma unroll
    for (int n = 0; n < 4; ++n) {
      int col = ccol0 + n * 16 + lr;
#pragma unroll
      for (int r = 0; r < 4; ++r) {
        long idx2 = (long)(crow0 + m * 16 + r) * INNER + col;
        if constexpr (sizeof(OutT) == 2) cp[idx2] = f2bf(acc[m][n][r]);
        else                             cp[idx2] = acc[m][n][r];
      }
    }
}

// ---------------------------------------------------------------------------
// Fused causal depthwise conv1d(K=4) + SiLU (+per-head L2 norm for q,k).
// ---------------------------------------------------------------------------
__global__ __launch_bounds__(256) void conv3(
    const u16* __restrict__ pq, const u16* __restrict__ pk,
    const u16* __restrict__ pv,
    const float* __restrict__ cqw, const float* __restrict__ cqb,
    const float* __restrict__ ckw, const float* __restrict__ ckb,
    const float* __restrict__ cvw, const float* __restrict__ cvb,
    u16* __restrict__ oq, u16* __restrict__ ok, u16* __restrict__ ov) {
  const int which = blockIdx.y;
  const u16* pre = which == 0 ? pq : which == 1 ? pk : pv;
  const float* cw = which == 0 ? cqw : which == 1 ? ckw : cvw;
  const float* cb = which == 0 ? cqb : which == 1 ? ckb : cvb;
  u16* out = which == 0 ? oq : which == 1 ? ok : ov;
  const int do_l2 = (which < 2);

  const int bt = blockIdx.x;
  const int b = bt / TT, t = bt % TT;
  const int tid = threadIdx.x;
  const int c4 = tid * 4;
  float xt[4][4];
#pragma unroll
  for (int j = 0; j < 4; ++j) {
    int ts = t - 3 + j;
    if (ts >= 0) {
      ushort4 u = *(const ushort4*)&pre[(long)(b * TT + ts) * INNER + c4];
      xt[j][0] = b2f(u.x); xt[j][1] = b2f(u.y);
      xt[j][2] = b2f(u.z); xt[j][3] = b2f(u.w);
    } else {
      xt[j][0] = xt[j][1] = xt[j][2] = xt[j][3] = 0.f;
    }
  }
  float4 bias4 = *(const float4*)&cb[c4];
  const float* bp = (const float*)&bias4;
  float y[4];
#pragma unroll
  for (int ci = 0; ci < 4; ++ci) {
    float4 w4 = *(const float4*)&cw[(c4 + ci) * 4];
    float acc = bp[ci];
    acc += w4.x * xt[0][ci];
    acc += w4.y * xt[1][ci];
    acc += w4.z * xt[2][ci];
    acc += w4.w * xt[3][ci];
    y[ci] = acc / (1.f + expf(-acc));   // SiLU
  }
  if (do_l2) {
    float ssq = y[0]*y[0] + y[1]*y[1] + y[2]*y[2] + y[3]*y[3];
    ssq += __shfl_xor(ssq, 1);
    ssq += __shfl_xor(ssq, 2);
    ssq += __shfl_xor(ssq, 4);
    ssq += __shfl_xor(ssq, 8);   // 16 threads = one head (64 channels)
    float r = rsqrtf(ssq + EPSF);
    y[0] *= r; y[1] *= r; y[2] *= r; y[3] *= r;
  }
  ushort4 res;
  res.x = f2bf(y[0]); res.y = f2bf(y[1]);
  res.z = f2bf(y[2]); res.w = f2bf(y[3]);
  *(ushort4*)&out[(long)bt * INNER + c4] = res;
}

// ---------------------------------------------------------------------------
// beta = sigmoid(x@wb.T); ldec = -exp(A_log)*softplus(x@wa.T + dt_bias)
// ---------------------------------------------------------------------------
__global__ __launch_bounds__(256) void proj_ab3(
    const float* __restrict__ x, const float* __restrict__ wa,
    const float* __restrict__ wb, const float* __restrict__ dt_bias,
    const float* __restrict__ A_log, float* __restrict__ beta,
    float* __restrict__ ldec) {
  const int m0 = blockIdx.x * 8;
  const int tid = threadIdx.x;
  __shared__ float xs[8][132];
  __shared__ float ws[32][132];
  const int row = tid >> 5;
  const int col = tid & 31;
  float a0 = 0.f, a1 = 0.f, a2 = 0.f, a3 = 0.f;
  const int sxr = tid >> 5, sxc = (tid & 31) * 4;
  for (int k0 = 0; k0 < CC; k0 += 128) {
    __syncthreads();
    *(float4*)&xs[sxr][sxc] = *(const float4*)&x[(long)(m0 + sxr) * CC + k0 + sxc];
#pragma unroll
    for (int p = 0; p < 4; ++p) {
      int idx = tid + p * 256;
      int wr = idx >> 5, wc4 = (idx & 31) * 4;
      const float* wsrc = (wr < 16) ? &wa[(long)wr * CC] : &wb[(long)(wr - 16) * CC];
      *(float4*)&ws[wr][wc4] = *(const float4*)&wsrc[k0 + wc4];
    }
    __syncthreads();
#pragma unroll
    for (int kk = 0; kk < 128; kk += 16) {
      float4 x0 = *(const float4*)&xs[row][kk + 0];
      float4 w0 = *(const float4*)&ws[col][kk + 0];
      float4 x1 = *(const float4*)&xs[row][kk + 4];
      float4 w1 = *(const float4*)&ws[col][kk + 4];
      float4 x2 = *(const float4*)&xs[row][kk + 8];
      float4 w2 = *(const float4*)&ws[col][kk + 8];
      float4 x3 = *(const float4*)&xs[row][kk + 12];
      float4 w3 = *(const float4*)&ws[col][kk + 12];
      a0 += x0.x * w0.x + x0.y * w0.y + x0.z * w0.z + x0.w * w0.w;
      a1 += x1.x * w1.x + x1.y * w1.y + x1.z * w1.z + x1.w * w1.w;
      a2 += x2.x * w2.x + x2.y * w2.y + x2.z * w2.z + x2.w * w2.w;
      a3 += x3.x * w3.x + x3.y * w3.y + x3.z * w3.z + x3.w * w3.w;
    }
  }
  float acc = (a0 + a1) + (a2 + a3);
  const int m = m0 + row;
  if (col < 16) {
    float a = acc + dt_bias[col];
    float sp = fmaxf(a, 0.f) + log1pf(expf(-fabsf(a)));
    ldec[(long)m * HH + col] = -expf(A_log[col]) * sp;
  } else {
    beta[(long)m * HH + (col - 16)] = 1.f / (1.f + expf(-acc));
  }
}

// ---------------------------------------------------------------------------
// Per-chunk parallel precompute. grid = NCHK (1024), 256 threads.
// G = K.K^T and Pm = K.Q^T now via MFMA (bf16 inputs read from global,
// fp32 accum — same values, different sum order). kst staging eliminated;
// qst kept only for Qht. Substitution + M/b unchanged (fp32-exact path).
// ---------------------------------------------------------------------------
__global__ __launch_bounds__(256) void gdn_prep(
    const u16* __restrict__ q, const u16* __restrict__ k,
    const u16* __restrict__ v, const float* __restrict__ beta,
    const float* __restrict__ ldec,
    u16* __restrict__ U0g, u16* __restrict__ Wtg, u16* __restrict__ Btg,
    u16* __restrict__ Qhtg, float* __restrict__ Mtg, float* __restrict__ bvg) {
  const int blk = blockIdx.x;
  const int bh = blk / NC, c = blk % NC;
  const int b = bh >> 4, h = bh & 15;
  const int tid = threadIdx.x;
  const int tx = tid & 15, ty = tid >> 4;
  __shared__ float P0[64][68];   // beta*v  -> U0[t][e]
  __shared__ float P1[64][68];   // qst[d][t], then beta*exp(lamx)*k -> W[t][d]
  __shared__ float Ab[64][68];   // A[t][s] -> later Kh[t][d]
  __shared__ float lam[64], lamx[64], lbet[64];
  const long gb = ((long)(b * TT + c * CH) * HH + h) * DD;

  // stage q transposed (bf16 -> fp32) for Qht only
  {
    const int e4 = (tid & 15) * 4;
    const int t0 = tid >> 4;
#pragma unroll
    for (int p = 0; p < 4; ++p) {
      int t = t0 + p * 16;
      ushort4 qv = *(const ushort4*)&q[gb + (long)t * (HH * DD) + e4];
      P1[e4 + 0][t] = b2f(qv.x); P1[e4 + 1][t] = b2f(qv.y);
      P1[e4 + 2][t] = b2f(qv.z); P1[e4 + 3][t] = b2f(qv.w);
    }
  }
  float ldv = 0.f, bv_ = 0.f;
  if (tid < 64) {
    ldv = ldec[(long)(b * TT + c * CH + tid) * HH + h];
    bv_ = beta[(long)(b * TT + c * CH + tid) * HH + h];
    lam[tid] = ldv;
  }
  __syncthreads();
  float lsum = 0.f;
  if (tid < 64) {
    for (int s = 0; s <= tid; ++s) lsum += lam[s];
  }
  __syncthreads();
  if (tid < 64) {
    lam[tid] = lsum;
    lamx[tid] = lsum - ldv;
    lbet[tid] = bv_;
  }
  __syncthreads();

  // MFMA: G = K.K^T, Pm = K.Q^T (each wave owns a 32x32 quadrant).
  // Fragment layout (verified m89): A/B lane holds row (lane&15) of its
  // 16-row group, k-elems (lane>>4)*8; C/D: col=lane&15, row=(lane>>4)*4+r.
  {
    const int lane = tid & 63;
    const int wave = tid >> 6;
    const int lr = lane & 15;
    const int kq = lane >> 4;
    const int mwr = (wave >> 1) * 32, mwc = (wave & 1) * 32;
    bf16x8 af[2][2], bk_[2][2], bq_[2][2];
#pragma unroll
    for (int m = 0; m < 2; ++m)
#pragma unroll
      for (int ks = 0; ks < 2; ++ks) {
        long rbase = gb + (long)(mwr + m * 16 + lr) * (HH * DD) + ks * 32 + kq * 8;
        long cbase = gb + (long)(mwc + m * 16 + lr) * (HH * DD) + ks * 32 + kq * 8;
        af[m][ks]  = __builtin_bit_cast(bf16x8, *(const uint4*)&k[rbase]);
        bk_[m][ks] = __builtin_bit_cast(bf16x8, *(const uint4*)&k[cbase]);
        bq_[m][ks] = __builtin_bit_cast(bf16x8, *(const uint4*)&q[cbase]);
      }
    f32x4 gf[2][2] = {}, pf[2][2] = {};
#pragma unroll
    for (int ks = 0; ks < 2; ++ks)
#pragma unroll
      for (int m = 0; m < 2; ++m)
#pragma unroll
        for (int n = 0; n < 2; ++n) {
          gf[m][n] = __builtin_amdgcn_mfma_f32_16x16x32_bf16(
              af[m][ks], bk_[n][ks], gf[m][n], 0, 0, 0);
          pf[m][n] = __builtin_amdgcn_mfma_f32_16x16x32_bf16(
              af[m][ks], bq_[n][ks], pf[m][n], 0, 0, 0);
        }
    // A[t][s] (LDS, fp32) and Bt[s][t] (global bf16), scaled.
    u16* btp = Btg + (long)blk * (CH * CH);
#pragma unroll
    for (int m = 0; m < 2; ++m)
#pragma unroll
      for (int n = 0; n < 2; ++n)
#pragma unroll
        for (int r = 0; r < 4; ++r) {
          int t = mwr + m * 16 + kq * 4 + r;   // C row (K index for both)
          int s = mwc + n * 16 + lr;           // C col
          Ab[t][s] = (s < t) ? lbet[t] * expf(lamx[t] - lam[s]) * gf[m][n][r]
                             : 0.f;
          // Pm row = K index (ps), col = Q index (pt)
          btp[t * 64 + s] = f2bf(
              (t <= s) ? expf(lam[s] - lam[t]) * pf[m][n][r] : 0.f);
        }
  }
  // Qht[d][t] bf16 (from qst in P1)
  {
    u16* qhp = Qhtg + (long)blk * (DD * CH);
    const int t4 = (tid & 15) * 4;
    const int d0 = tid >> 4;
#pragma unroll
    for (int p = 0; p < 4; ++p) {
      int d = d0 + p * 16;
      float4 qv = *(const float4*)&P1[d][t4];
      ushort4 qw;
      qw.x = f2bf(qv.x * expf(lam[t4 + 0]));
      qw.y = f2bf(qv.y * expf(lam[t4 + 1]));
      qw.z = f2bf(qv.z * expf(lam[t4 + 2]));
      qw.w = f2bf(qv.w * expf(lam[t4 + 3]));
      *(ushort4*)&qhp[d * 64 + t4] = qw;
    }
  }
  __syncthreads();
  // re-init: P0[t][e] = beta_t v ; P1[t][d] = beta_t exp(lamx_t) k
  {
    const int e4 = (tid & 15) * 4;
    const int t0 = tid >> 4;
#pragma unroll
    for (int p = 0; p < 4; ++p) {
      int t = t0 + p * 16;
      float bt_ = lbet[t], cx = bt_ * expf(lamx[t]);
      ushort4 vv4 = *(const ushort4*)&v[gb + (long)t * (HH * DD) + e4];
      ushort4 kv4 = *(const ushort4*)&k[gb + (long)t * (HH * DD) + e4];
      float4 vv = make_float4(b2f(vv4.x) * bt_, b2f(vv4.y) * bt_,
                              b2f(vv4.z) * bt_, b2f(vv4.w) * bt_);
      float4 kv = make_float4(b2f(kv4.x) * cx, b2f(kv4.y) * cx,
                              b2f(kv4.z) * cx, b2f(kv4.w) * cx);
      *(float4*)&P0[t][e4] = vv;
      *(float4*)&P1[t][e4] = kv;
    }
  }
  __syncthreads();
  // BLOCKED forward substitution on (I+A): both P0,P1
  {
    const int i = tid >> 5;
    const int j4 = (tid & 31) * 4;
    float* Pj = (j4 < 64) ? (&P0[0][0] + j4) : (&P1[0][0] + (j4 - 64));
#pragma unroll
    for (int base = 0; base < 64; base += 8) {
      const int r = base + i;
      float4 acc = *(const float4*)&Pj[r * 68];
      for (int t = 0; t < base; ++t) {
        float a = Ab[r][t];
        float4 ut = *(const float4*)&Pj[t * 68];
        acc.x -= a * ut.x; acc.y -= a * ut.y;
        acc.z -= a * ut.z; acc.w -= a * ut.w;
      }
      *(float4*)&Pj[r * 68] = acc;
      __syncthreads();
      float4 val[8];
#pragma unroll
      for (int t = 0; t < 8; ++t) {
        float4 vt = *(const float4*)&Pj[(base + t) * 68];
#pragma unroll
        for (int m = 0; m < t; ++m) {
          float a = Ab[base + t][base + m];
          vt.x -= a * val[m].x; vt.y -= a * val[m].y;
          vt.z -= a * val[m].z; vt.w -= a * val[m].w;
        }
        val[t] = vt;
      }
      float4 fin = val[0];
#pragma unroll
      for (int t = 1; t < 8; ++t) if (i == t) fin = val[t];
      __syncthreads();
      *(float4*)&Pj[r * 68] = fin;
      __syncthreads();
    }
  }
  // write U0 (bf16) and Wt (bf16, transposed); stage Kh into Ab
  {
    u16* u0p = U0g + (long)blk * (CH * DD);
    const int e4 = (tid & 15) * 4;
    const int t0 = tid >> 4;
    float lamL = lam[63];
#pragma unroll
    for (int p = 0; p < 4; ++p) {
      int t = t0 + p * 16;
      float4 u4 = *(const float4*)&P0[t][e4];
      ushort4 uw;
      uw.x = f2bf(u4.x); uw.y = f2bf(u4.y);
      uw.z = f2bf(u4.z); uw.w = f2bf(u4.w);
      *(ushort4*)&u0p[t * 64 + e4] = uw;
      float cf = expf(lamL - lam[t]);
      ushort4 kv4 = *(const ushort4*)&k[gb + (long)t * (HH * DD) + e4];
      *(float4*)&Ab[t][e4] = make_float4(b2f(kv4.x) * cf, b2f(kv4.y) * cf,
                                         b2f(kv4.z) * cf, b2f(kv4.w) * cf);
    }
    u16* wtp = Wtg + (long)blk * (DD * CH);
    const int t = tid & 63;
    const int d0 = tid >> 6;
#pragma unroll
    for (int p = 0; p < 16; ++p) {
      int d = d0 + p * 4;
      wtp[d * 64 + t] = f2bf(P1[t][d]);
    }
  }
  __syncthreads();
  // M[d][s] = gL*I - sum_t Kh[t][d]*W[t][s] ; b[d][e] = sum_t Kh[t][d]*U0[t][e]
  {
    float accm[4][4] = {}, accb[4][4] = {};
    for (int t = 0; t < 64; ++t) {
      float4 ka = *(const float4*)&Ab[t][ty * 4];
      float4 wc_ = *(const float4*)&P1[t][tx * 4];
      float4 uv = *(const float4*)&P0[t][tx * 4];
      float kar[4] = {ka.x, ka.y, ka.z, ka.w};
      float wcr[4] = {wc_.x, wc_.y, wc_.z, wc_.w};
      float ucr[4] = {uv.x, uv.y, uv.z, uv.w};
#pragma unroll
      for (int i = 0; i < 4; ++i)
#pragma unroll
        for (int j = 0; j < 4; ++j) {
          accm[i][j] += kar[i] * wcr[j];
          accb[i][j] += kar[i] * ucr[j];
        }
    }
    float gLv = expf(lam[63]);
    float* mp = Mtg + (long)blk * (DD * DD);
    float* bp = bvg + (long)blk * (DD * DD);
#pragma unroll
    for (int i = 0; i < 4; ++i) {
      int rr = ty * 4 + i;    // d
      float4 mv, b4;
      mv.x = ((rr == tx * 4 + 0) ? gLv : 0.f) - accm[i][0];
      mv.y = ((rr == tx * 4 + 1) ? gLv : 0.f) - accm[i][1];
      mv.z = ((rr == tx * 4 + 2) ? gLv : 0.f) - accm[i][2];
      mv.w = ((rr == tx * 4 + 3) ? gLv : 0.f) - accm[i][3];
      *(float4*)&mp[rr * 64 + tx * 4] = mv;   // [d][s]
      b4.x = accb[i][0]; b4.y = accb[i][1];
      b4.z = accb[i][2]; b4.w = accb[i][3];
      *(float4*)&bp[rr * 64 + tx * 4] = b4;   // [d][e]
    }
  }
}

// ---------------------------------------------------------------------------
// Sequential pass: S_{c+1} = M_c S_c + b_c, e-split 8-way (256 blocks).
// ---------------------------------------------------------------------------
__global__ __launch_bounds__(256) void gdn_seq4(
    const float* __restrict__ Mtg, const float* __restrict__ bvg,
    float* __restrict__ Sall) {
  const int bh = blockIdx.x & 31;         // L2-sharing swizzle
  const int esec = blockIdx.x >> 5;       // 0..7
  const int tid = threadIdx.x;
  const int d = tid & 63;
  const int ep = (tid >> 6) * 2;          // 0,2,4,6 within 8-col slice
  const int eo = esec * 8 + ep;
  __shared__ float Ms[64][68];            // [d][s]
  __shared__ float Ss[8][68];             // [e][s]
  float S0 = 0.f, S1 = 0.f;
  const int sr = tid >> 2, sq = (tid & 3) * 16;
  float4 mreg[4];
  {
    const float* mt0 = Mtg + (long)bh * NC * 4096;
#pragma unroll
    for (int p = 0; p < 4; ++p)
      mreg[p] = *(const float4*)&mt0[sr * 64 + sq + p * 4];
  }
  for (int c = 0; c < NC; ++c) {
    const long cb = (long)bh * NC + c;
    float2 bv = *(const float2*)&bvg[cb * 4096 + d * 64 + eo];
    __syncthreads();
#pragma unroll
    for (int p = 0; p < 4; ++p)
      *(float4*)&Ms[sr][sq + p * 4] = mreg[p];
    *(float2*)&Sall[cb * 4096 + d * 64 + eo] = make_float2(S0, S1);
    Ss[ep][d] = S0; Ss[ep + 1][d] = S1;
    __syncthreads();
    if (c + 1 < NC) {
      const float* mtn = Mtg + (cb + 1) * 4096;
#pragma unroll
      for (int p = 0; p < 4; ++p)
        mreg[p] = *(const float4*)&mtn[sr * 64 + sq + p * 4];
    }
    float a0 = bv.x, a1 = bv.y, b0 = 0.f, b1 = 0.f;
#pragma unroll
    for (int sg = 0; sg < 8; ++sg) {
      float4 m4 = *(const float4*)&Ms[d][sg * 4];
      float4 s0 = *(const float4*)&Ss[ep][sg * 4];
      float4 s1 = *(const float4*)&Ss[ep + 1][sg * 4];
      a0 += m4.x * s0.x + m4.y * s0.y + m4.z * s0.z + m4.w * s0.w;
      a1 += m4.x * s1.x + m4.y * s1.y + m4.z * s1.z + m4.w * s1.w;
    }
#pragma unroll
    for (int sg = 8; sg < 16; ++sg) {
      float4 m4 = *(const float4*)&Ms[d][sg * 4];
      float4 s0 = *(const float4*)&Ss[ep][sg * 4];
      float4 s1 = *(const float4*)&Ss[ep + 1][sg * 4];
      b0 += m4.x * s0.x + m4.y * s0.y + m4.z * s0.z + m4.w * s0.w;
      b1 += m4.x * s1.x + m4.y * s1.y + m4.z * s1.z + m4.w * s1.w;
    }
    S0 = a0 + b0; S1 = a1 + b1;
  }
}

// ---------------------------------------------------------------------------
// Fully parallel per-chunk output: u = U0 - W.S ; o = B.u + Qh.S
// ---------------------------------------------------------------------------
__global__ __launch_bounds__(256) void gdn_out(
    const u16* __restrict__ U0g, const u16* __restrict__ Wtg,
    const u16* __restrict__ Btg, const u16* __restrict__ Qhtg,
    const float* __restrict__ Sall, u16* __restrict__ o) {
  const int blk = blockIdx.x;
  const int bh = blk / NC, c = blk % NC;
  const int b = bh >> 4, h = bh & 15;
  const int tid = threadIdx.x;
  const int tx = tid & 15, ty = tid >> 4;
  __shared__ float S[64][64];
  __shared__ float ub[64][64];
  __shared__ float op[64][64];
  const int e4 = (tid & 15) * 4;
  const int t0s = tid >> 4;
  {
    const int r = tid >> 2, qq = (tid & 3) * 16;
#pragma unroll
    for (int p = 0; p < 4; ++p)
      *(float4*)&S[r][qq + p * 4] =
          *(const float4*)&Sall[(long)blk * 4096 + r * 64 + qq + p * 4];
  }
#pragma unroll
  for (int p = 0; p < 4; ++p) {
    int t = t0s + p * 16;
    ushort4 w4 = *(const ushort4*)&Wtg[(long)blk * 4096 + t * 64 + e4];
    *(float4*)&op[t][e4] = make_float4(b2f(w4.x), b2f(w4.y), b2f(w4.z), b2f(w4.w));
  }
  __syncthreads();
  float acc[4][4];
#pragma unroll
  for (int i = 0; i < 4; ++i) {
    ushort4 u4 = *(const ushort4*)&U0g[(long)blk * 4096 + (ty * 4 + i) * 64 + tx * 4];
    acc[i][0] = b2f(u4.x); acc[i][1] = b2f(u4.y);
    acc[i][2] = b2f(u4.z); acc[i][3] = b2f(u4.w);
  }
  for (int d = 0; d < 64; ++d) {
    float4 a4 = *(const float4*)&op[d][ty * 4];
    float4 b4 = *(const float4*)&S[d][tx * 4];
    float ar[4] = {a4.x, a4.y, a4.z, a4.w};
    float br[4] = {b4.x, b4.y, b4.z, b4.w};
#pragma unroll
    for (int i = 0; i < 4; ++i)
#pragma unroll
      for (int j = 0; j < 4; ++j) acc[i][j] -= ar[i] * br[j];
  }
#pragma unroll
  for (int i = 0; i < 4; ++i)
    *(float4*)&ub[ty * 4 + i][tx * 4] =
        make_float4(acc[i][0], acc[i][1], acc[i][2], acc[i][3]);
  __syncthreads();
#pragma unroll
  for (int p = 0; p < 4; ++p) {
    int t = t0s + p * 16;
    ushort4 w4 = *(const ushort4*)&Btg[(long)blk * 4096 + t * 64 + e4];
    *(float4*)&op[t][e4] = make_float4(b2f(w4.x), b2f(w4.y), b2f(w4.z), b2f(w4.w));
  }
  __syncthreads();
  float acco[4][4] = {};
  for (int s = 0; s < 64; ++s) {
    float4 a4 = *(const float4*)&op[s][ty * 4];
    float4 b4 = *(const float4*)&ub[s][tx * 4];
    float ar[4] = {a4.x, a4.y, a4.z, a4.w};
    float br[4] = {b4.x, b4.y, b4.z, b4.w};
#pragma unroll
    for (int i = 0; i < 4; ++i)
#pragma unroll
      for (int j = 0; j < 4; ++j) acco[i][j] += ar[i] * br[j];
  }
  __syncthreads();
#pragma unroll
  for (int p = 0; p < 4; ++p) {
    int t = t0s + p * 16;
    ushort4 w4 = *(const ushort4*)&Qhtg[(long)blk * 4096 + t * 64 + e4];
    *(float4*)&op[t][e4] = make_float4(b2f(w4.x), b2f(w4.y), b2f(w4.z), b2f(w4.w));
  }
  __syncthreads();
  for (int d = 0; d < 64; ++d) {
    float4 a4 = *(const float4*)&op[d][ty * 4];
    float4 b4 = *(const float4*)&S[d][tx * 4];
    float ar[4] = {a4.x, a4.y, a4.z, a4.w};
    float br[4] = {b4.x, b4.y, b4.z, b4.w};
#pragma unroll
    for (int i = 0; i < 4; ++i)
#pragma unroll
      for (int j = 0; j < 4; ++j) acco[i][j] += ar[i] * br[j];
  }
#pragma unroll
  for (int i = 0; i < 4; ++i) {
    int t = ty * 4 + i;
    ushort4 ow;
    ow.x = f2bf(acco[i][0]); ow.y = f2bf(acco[i][1]);
    ow.z = f2bf(acco[i][2]); ow.w = f2bf(acco[i][3]);
    *(ushort4*)&o[((long)(b * TT + c * CH + t) * HH + h) * DD + tx * 4] = ow;
  }
}

// ---------------------------------------------------------------------------
// gated = rms_norm(o) * o_norm_scale * silu(g), bf16 in/out.
// ---------------------------------------------------------------------------
__global__ __launch_bounds__(256) void norm_gate(
    const u16* __restrict__ o, const u16* __restrict__ g,
    const float* __restrict__ scale, u16* __restrict__ outb) {
  const int bt = blockIdx.x;
  const int tid = threadIdx.x;
  const int c4 = tid * 4;
  ushort4 o4u = *(const ushort4*)&o[(long)bt * INNER + c4];
  float4 o4 = make_float4(b2f(o4u.x), b2f(o4u.y), b2f(o4u.z), b2f(o4u.w));
  float ssq = o4.x * o4.x + o4.y * o4.y + o4.z * o4.z + o4.w * o4.w;
  ssq += __shfl_xor(ssq, 1);
  ssq += __shfl_xor(ssq, 2);
  ssq += __shfl_xor(ssq, 4);
  ssq += __shfl_xor(ssq, 8);
  float r = rsqrtf(ssq * (1.f / 64.f) + EPSF);
  float4 sc = *(const float4*)&scale[c4 & 63];
  ushort4 g4u = *(const ushort4*)&g[(long)bt * INNER + c4];
  float4 g4 = make_float4(b2f(g4u.x), b2f(g4u.y), b2f(g4u.z), b2f(g4u.w));
  ushort4 res;
  res.x = f2bf(o4.x * r * sc.x * (g4.x / (1.f + expf(-g4.x))));
  res.y = f2bf(o4.y * r * sc.y * (g4.y / (1.f + expf(-g4.y))));
  res.z = f2bf(o4.z * r * sc.z * (g4.z / (1.f + expf(-g4.z))));
  res.w = f2bf(o4.w * r * sc.w * (g4.w / (1.f + expf(-g4.w))));
  *(ushort4*)&outb[(long)bt * INNER + c4] = res;
}

// ---------------------------------------------------------------------------
extern "C" void kernel_launch(void* const* d_in, const int* in_sizes, int n_in,
                              void* d_out, int out_size, void* d_ws,
                              size_t ws_size, hipStream_t stream) {
  const float* x      = (const float*)d_in[0];
  const float* wq     = (const float*)d_in[1];
  const float* wk     = (const float*)d_in[2];
  const float* wv     = (const float*)d_in[3];
  const float* wg     = (const float*)d_in[4];
  const float* wo     = (const float*)d_in[5];
  const float* wa     = (const float*)d_in[6];
  const float* wb     = (const float*)d_in[7];
  const float* cqw    = (const float*)d_in[8];
  const float* cqb    = (const float*)d_in[9];
  const float* ckw    = (const float*)d_in[10];
  const float* ckb    = (const float*)d_in[11];
  const float* cvw    = (const float*)d_in[12];
  const float* cvb    = (const float*)d_in[13];
  const float* A_log  = (const float*)d_in[14];
  const float* dtb    = (const float*)d_in[15];
  const float* oscale = (const float*)d_in[16];
  float* out = (float*)d_out;

  u16 *pqb, *pkb, *pvb, *qb, *kb, *vb, *gb, *ob;
  u16 *xb, *wbb, *wob, *gatedb, *U0, *Wt, *Bt, *Qht;
  float *beta, *ldec, *Mc, *bc, *Sall;
  hipGetSymbolAddress((void**)&pqb,   HIP_SYMBOL(g_pqb));
  hipGetSymbolAddress((void**)&pkb,   HIP_SYMBOL(g_pkb));
  hipGetSymbolAddress((void**)&pvb,   HIP_SYMBOL(g_pvb));
  hipGetSymbolAddress((void**)&qb,    HIP_SYMBOL(g_qb));
  hipGetSymbolAddress((void**)&kb,    HIP_SYMBOL(g_kb));
  hipGetSymbolAddress((void**)&vb,    HIP_SYMBOL(g_vb));
  hipGetSymbolAddress((void**)&gb,    HIP_SYMBOL(g_gb));
  hipGetSymbolAddress((void**)&ob,    HIP_SYMBOL(g_ob));
  hipGetSymbolAddress((void**)&beta,  HIP_SYMBOL(g_beta));
  hipGetSymbolAddress((void**)&ldec,  HIP_SYMBOL(g_ldec));
  hipGetSymbolAddress((void**)&xb,    HIP_SYMBOL(g_xb));
  hipGetSymbolAddress((void**)&wbb,   HIP_SYMBOL(g_wbb));
  hipGetSymbolAddress((void**)&wob,   HIP_SYMBOL(g_wob));
  hipGetSymbolAddress((void**)&gatedb,HIP_SYMBOL(g_gatedb));
  hipGetSymbolAddress((void**)&U0,    HIP_SYMBOL(g_U0));
  hipGetSymbolAddress((void**)&Wt,    HIP_SYMBOL(g_Wt));
  hipGetSymbolAddress((void**)&Bt,    HIP_SYMBOL(g_Bt));
  hipGetSymbolAddress((void**)&Qht,   HIP_SYMBOL(g_Qht));
  hipGetSymbolAddress((void**)&Mc,    HIP_SYMBOL(g_Mc));
  hipGetSymbolAddress((void**)&bc,    HIP_SYMBOL(g_bc));
  hipGetSymbolAddress((void**)&Sall,  HIP_SYMBOL(g_Sall));

  cast_all<<<9216, 256, 0, stream>>>(x, wq, wk, wv, wg, wo, xb, wbb, wob);

  // fused QKVG projection -> bf16 outputs (BK=64, XCD serpentine)
  bgemm4<u16, 32><<<1024, 256, 0, stream>>>(xb, wbb, pqb, pkb, pvb, gb);

  conv3<<<dim3(BT, 3), 256, 0, stream>>>(pqb, pkb, pvb,
                                         cqw, cqb, ckw, ckb, cvw, cvb,
                                         qb, kb, vb);
  proj_ab3<<<BT / 8, 256, 0, stream>>>(x, wa, wb, dtb, A_log, beta, ldec);

  gdn_prep<<<NCHK, 256, 0, stream>>>(qb, kb, vb, beta, ldec,
                                     U0, Wt, Bt, Qht, Mc, bc);
  gdn_seq4<<<NBH * 8, 256, 0, stream>>>(Mc, bc, Sall);
  gdn_out<<<NCHK, 256, 0, stream>>>(U0, Wt, Bt, Qht, Sall, ob);

  norm_gate<<<BT, 256, 0, stream>>>(ob, gb, oscale, gatedb);

  // final projection: out = gated_bf16 @ wo^T (fp32 out, 256 blocks)
  bgemm4<float, 8><<<256, 256, 0, stream>>>(gatedb, wob, out, out, out, out);
}

// Round 18
// 273.682 us; speedup vs baseline: 1.0905x; 1.0770x over previous
//
#include <hip/hip_runtime.h>
#include <math.h>

#define BB 2
#define TT 2048
#define CC 1024
#define HH 16
#define DD 64
#define INNER 1024
#define BT (BB*TT)   /* 4096 */
#define EPSF 1e-6f
#define CH 64
#define NC (TT/CH)        /* 32 */
#define NBH (BB*HH)       /* 32 */
#define NCHK (NBH*NC)     /* 1024 */

typedef unsigned short u16;
typedef __bf16 bf16x8 __attribute__((ext_vector_type(8)));
typedef float f32x4 __attribute__((ext_vector_type(4)));

__device__ inline u16 f2bf(float f) {   // RNE float->bf16
  unsigned u = __builtin_bit_cast(unsigned, f);
  return (u16)((u + 0x7fffu + ((u >> 16) & 1u)) >> 16);
}
__device__ inline float b2f(u16 b) {
  unsigned u = ((unsigned)b) << 16;
  return __builtin_bit_cast(float, u);
}
__device__ inline void gll16(const u16* g, u16* l) {
  __builtin_amdgcn_global_load_lds(
      (const __attribute__((address_space(1))) void*)g,
      (__attribute__((address_space(3))) void*)l, 16, 0, 0);
}

// Static device scratch (fully overwritten every call; deterministic).
__device__ u16   g_pqb[BT * INNER];      // pre_q bf16
__device__ u16   g_pkb[BT * INNER];      // pre_k
__device__ u16   g_pvb[BT * INNER];      // pre_v
__device__ u16   g_qb [BT * INNER];      // q bf16 (post conv+l2)
__device__ u16   g_kb [BT * INNER];
__device__ u16   g_vb [BT * INNER];
__device__ u16   g_gb [BT * INNER];      // g projection bf16
__device__ u16   g_ob [BT * INNER];      // o bf16
__device__ float g_beta[BT * HH];
__device__ float g_ldec[BT * HH];
__device__ u16   g_xb[BT * CC];          // x in bf16
__device__ u16   g_wbb[4 * INNER * CC];  // wq|wk|wv|wg in bf16
__device__ u16   g_wob[CC * INNER];      // wo in bf16
__device__ u16   g_gatedb[BT * INNER];   // gated activations bf16
// per-chunk tensors: output path bf16, state path fp32
__device__ u16   g_U0 [NCHK * CH * DD];
__device__ u16   g_Wt [NCHK * DD * CH];
__device__ u16   g_Bt [NCHK * CH * CH];
__device__ u16   g_Qht[NCHK * DD * CH];
__device__ float g_Mc [NCHK * DD * DD];  // M[d][s] row-major (d = row)
__device__ float g_bc [NCHK * DD * DD];  // b[d][e]
__device__ float g_Sall[NCHK * DD * DD]; // chunk-start states [d][e]

// ---------------------------------------------------------------------------
// Fused cast of x and all weights to bf16.
// ---------------------------------------------------------------------------
__global__ __launch_bounds__(256) void cast_all(
    const float* __restrict__ x, const float* __restrict__ wq,
    const float* __restrict__ wk, const float* __restrict__ wv,
    const float* __restrict__ wg, const float* __restrict__ wo,
    u16* __restrict__ xb, u16* __restrict__ wb, u16* __restrict__ wob) {
  long i = ((long)blockIdx.x * 256 + threadIdx.x) * 4;
  const float* src;
  u16* dst;
  if (i < 4194304)      { src = x  + i;             dst = xb + i; }
  else if (i < 5242880) { src = wq + (i - 4194304); dst = wb + (i - 4194304); }
  else if (i < 6291456) { src = wk + (i - 5242880); dst = wb + (i - 4194304); }
  else if (i < 7340032) { src = wv + (i - 6291456); dst = wb + (i - 4194304); }
  else if (i < 8388608) { src = wg + (i - 7340032); dst = wb + (i - 4194304); }
  else                  { src = wo + (i - 8388608); dst = wob + (i - 8388608); }
  float4 v = *(const float4*)src;
  ushort4 o;
  o.x = f2bf(v.x); o.y = f2bf(v.y); o.z = f2bf(v.z); o.w = f2bf(v.w);
  *(ushort4*)dst = o;
}

// ---------------------------------------------------------------------------
// bf16 MFMA GEMM: BK=64, source-swizzled LDS (0 bank conflicts), XCD
// serpentine region remap. C[m,n] = sum_k A[m,k]*B[n,k], K=1024, 128x128.
// ---------------------------------------------------------------------------
template <typename OutT, int NBN>
__global__ __launch_bounds__(256) void bgemm4(
    const u16* __restrict__ A, const u16* __restrict__ B,
    OutT* __restrict__ c0, OutT* __restrict__ c1,
    OutT* __restrict__ c2, OutT* __restrict__ c3) {
  __shared__ u16 lA[128 * 64];
  __shared__ u16 lB[128 * 64];
  const int tid = threadIdx.x;
  const int bid = blockIdx.x;
  int bm, bn;
  if constexpr (NBN == 32) {
    const int xcd = bid & 7;
    const int idx = bid >> 3;          // 0..127
    const int in_ = idx >> 4;          // 0..7
    int im = idx & 15;
    im = (in_ & 1) ? (15 - im) : im;
    bm = ((xcd >> 2) * 16 + im) * 128;
    bn = ((xcd & 3) * 8 + in_) * 128;
  } else {
    const int xcd = bid & 7;
    const int idx = bid >> 3;          // 0..31
    const int in_ = idx >> 2;          // 0..7
    int im = idx & 3;
    im = (in_ & 1) ? (3 - im) : im;
    bm = (xcd * 4 + im) * 128;
    bn = in_ * 128;
  }
  const int lane = tid & 63;
  const int wave = tid >> 6;
  const int wr = (wave >> 1) * 64, wc = (wave & 1) * 64;
  const int lr = lane & 15;
  const int kq = lane >> 4;            // 0..3
  const int srow0 = tid >> 3;          // 0..31
  const int gcol = ((tid & 7) ^ (srow0 & 7)) * 8;
  const u16* gA0 = &A[(long)(bm + srow0) * CC + gcol];
  const u16* gB0 = &B[(long)(bn + srow0) * CC + gcol];
  u16* lA0 = &lA[tid * 8];
  u16* lB0 = &lB[tid * 8];
  f32x4 acc[4][4] = {};

  for (int k0 = 0; k0 < CC; k0 += 64) {
    __syncthreads();                  // protect prev-iter LDS reads
#pragma unroll
    for (int p = 0; p < 4; ++p) {
      gll16(gA0 + (long)p * 32 * CC + k0, lA0 + p * 2048);
      gll16(gB0 + (long)p * 32 * CC + k0, lB0 + p * 2048);
    }
    __syncthreads();                  // drains vmcnt before reads
#pragma unroll
    for (int ks = 0; ks < 2; ++ks) {
      const int sl = ((ks * 4 + kq) ^ (lr & 7)) * 8;
      bf16x8 af[4], bf_[4];
#pragma unroll
      for (int m = 0; m < 4; ++m)
        af[m] = __builtin_bit_cast(bf16x8,
            *(const uint4*)&lA[(wr + m * 16 + lr) * 64 + sl]);
#pragma unroll
      for (int n = 0; n < 4; ++n)
        bf_[n] = __builtin_bit_cast(bf16x8,
            *(const uint4*)&lB[(wc + n * 16 + lr) * 64 + sl]);
#pragma unroll
      for (int m = 0; m < 4; ++m)
#pragma unroll
        for (int n = 0; n < 4; ++n)
          acc[m][n] = __builtin_amdgcn_mfma_f32_16x16x32_bf16(
              af[m], bf_[n], acc[m][n], 0, 0, 0);
    }
  }
  OutT* cp = (bn < 1024) ? c0 : (bn < 2048) ? c1 : (bn < 3072) ? c2 : c3;
  const int ccol0 = (bn & 1023) + wc;
  const int crow0 = bm + wr + kq * 4;
#pragma unroll
  for (int m = 0; m < 4; ++m)
#pragma unroll
    for (int n = 0; n < 4; ++n) {
      int col = ccol0 + n * 16 + lr;
#pragma unroll
      for (int r = 0; r < 4; ++r) {
        long idx2 = (long)(crow0 + m * 16 + r) * INNER + col;
        if constexpr (sizeof(OutT) == 2) cp[idx2] = f2bf(acc[m][n][r]);
        else                             cp[idx2] = acc[m][n][r];
      }
    }
}

// ---------------------------------------------------------------------------
// Fused causal depthwise conv1d(K=4) + SiLU (+per-head L2 norm for q,k).
// ---------------------------------------------------------------------------
__global__ __launch_bounds__(256) void conv3(
    const u16* __restrict__ pq, const u16* __restrict__ pk,
    const u16* __restrict__ pv,
    const float* __restrict__ cqw, const float* __restrict__ cqb,
    const float* __restrict__ ckw, const float* __restrict__ ckb,
    const float* __restrict__ cvw, const float* __restrict__ cvb,
    u16* __restrict__ oq, u16* __restrict__ ok, u16* __restrict__ ov) {
  const int which = blockIdx.y;
  const u16* pre = which == 0 ? pq : which == 1 ? pk : pv;
  const float* cw = which == 0 ? cqw : which == 1 ? ckw : cvw;
  const float* cb = which == 0 ? cqb : which == 1 ? ckb : cvb;
  u16* out = which == 0 ? oq : which == 1 ? ok : ov;
  const int do_l2 = (which < 2);

  const int bt = blockIdx.x;
  const int b = bt / TT, t = bt % TT;
  const int tid = threadIdx.x;
  const int c4 = tid * 4;
  float xt[4][4];
#pragma unroll
  for (int j = 0; j < 4; ++j) {
    int ts = t - 3 + j;
    if (ts >= 0) {
      ushort4 u = *(const ushort4*)&pre[(long)(b * TT + ts) * INNER + c4];
      xt[j][0] = b2f(u.x); xt[j][1] = b2f(u.y);
      xt[j][2] = b2f(u.z); xt[j][3] = b2f(u.w);
    } else {
      xt[j][0] = xt[j][1] = xt[j][2] = xt[j][3] = 0.f;
    }
  }
  float4 bias4 = *(const float4*)&cb[c4];
  const float* bp = (const float*)&bias4;
  float y[4];
#pragma unroll
  for (int ci = 0; ci < 4; ++ci) {
    float4 w4 = *(const float4*)&cw[(c4 + ci) * 4];
    float acc = bp[ci];
    acc += w4.x * xt[0][ci];
    acc += w4.y * xt[1][ci];
    acc += w4.z * xt[2][ci];
    acc += w4.w * xt[3][ci];
    y[ci] = acc / (1.f + expf(-acc));   // SiLU
  }
  if (do_l2) {
    float ssq = y[0]*y[0] + y[1]*y[1] + y[2]*y[2] + y[3]*y[3];
    ssq += __shfl_xor(ssq, 1);
    ssq += __shfl_xor(ssq, 2);
    ssq += __shfl_xor(ssq, 4);
    ssq += __shfl_xor(ssq, 8);   // 16 threads = one head (64 channels)
    float r = rsqrtf(ssq + EPSF);
    y[0] *= r; y[1] *= r; y[2] *= r; y[3] *= r;
  }
  ushort4 res;
  res.x = f2bf(y[0]); res.y = f2bf(y[1]);
  res.z = f2bf(y[2]); res.w = f2bf(y[3]);
  *(ushort4*)&out[(long)bt * INNER + c4] = res;
}

// ---------------------------------------------------------------------------
// beta = sigmoid(x@wb.T); ldec = -exp(A_log)*softplus(x@wa.T + dt_bias)
// ---------------------------------------------------------------------------
__global__ __launch_bounds__(256) void proj_ab3(
    const float* __restrict__ x, const float* __restrict__ wa,
    const float* __restrict__ wb, const float* __restrict__ dt_bias,
    const float* __restrict__ A_log, float* __restrict__ beta,
    float* __restrict__ ldec) {
  const int m0 = blockIdx.x * 8;
  const int tid = threadIdx.x;
  __shared__ float xs[8][132];
  __shared__ float ws[32][132];
  const int row = tid >> 5;
  const int col = tid & 31;
  float a0 = 0.f, a1 = 0.f, a2 = 0.f, a3 = 0.f;
  const int sxr = tid >> 5, sxc = (tid & 31) * 4;
  for (int k0 = 0; k0 < CC; k0 += 128) {
    __syncthreads();
    *(float4*)&xs[sxr][sxc] = *(const float4*)&x[(long)(m0 + sxr) * CC + k0 + sxc];
#pragma unroll
    for (int p = 0; p < 4; ++p) {
      int idx = tid + p * 256;
      int wr = idx >> 5, wc4 = (idx & 31) * 4;
      const float* wsrc = (wr < 16) ? &wa[(long)wr * CC] : &wb[(long)(wr - 16) * CC];
      *(float4*)&ws[wr][wc4] = *(const float4*)&wsrc[k0 + wc4];
    }
    __syncthreads();
#pragma unroll
    for (int kk = 0; kk < 128; kk += 16) {
      float4 x0 = *(const float4*)&xs[row][kk + 0];
      float4 w0 = *(const float4*)&ws[col][kk + 0];
      float4 x1 = *(const float4*)&xs[row][kk + 4];
      float4 w1 = *(const float4*)&ws[col][kk + 4];
      float4 x2 = *(const float4*)&xs[row][kk + 8];
      float4 w2 = *(const float4*)&ws[col][kk + 8];
      float4 x3 = *(const float4*)&xs[row][kk + 12];
      float4 w3 = *(const float4*)&ws[col][kk + 12];
      a0 += x0.x * w0.x + x0.y * w0.y + x0.z * w0.z + x0.w * w0.w;
      a1 += x1.x * w1.x + x1.y * w1.y + x1.z * w1.z + x1.w * w1.w;
      a2 += x2.x * w2.x + x2.y * w2.y + x2.z * w2.z + x2.w * w2.w;
      a3 += x3.x * w3.x + x3.y * w3.y + x3.z * w3.z + x3.w * w3.w;
    }
  }
  float acc = (a0 + a1) + (a2 + a3);
  const int m = m0 + row;
  if (col < 16) {
    float a = acc + dt_bias[col];
    float sp = fmaxf(a, 0.f) + log1pf(expf(-fabsf(a)));
    ldec[(long)m * HH + col] = -expf(A_log[col]) * sp;
  } else {
    beta[(long)m * HH + (col - 16)] = 1.f / (1.f + expf(-acc));
  }
}

// ---------------------------------------------------------------------------
// Per-chunk parallel precompute. grid = NCHK (1024), 256 threads.
// G/Pm via MFMA; substitution + M/b fp32-exact.
// ---------------------------------------------------------------------------
__global__ __launch_bounds__(256) void gdn_prep(
    const u16* __restrict__ q, const u16* __restrict__ k,
    const u16* __restrict__ v, const float* __restrict__ beta,
    const float* __restrict__ ldec,
    u16* __restrict__ U0g, u16* __restrict__ Wtg, u16* __restrict__ Btg,
    u16* __restrict__ Qhtg, float* __restrict__ Mtg, float* __restrict__ bvg) {
  const int blk = blockIdx.x;
  const int bh = blk / NC, c = blk % NC;
  const int b = bh >> 4, h = bh & 15;
  const int tid = threadIdx.x;
  const int tx = tid & 15, ty = tid >> 4;
  __shared__ float P0[64][68];   // beta*v  -> U0[t][e]
  __shared__ float P1[64][68];   // qst[d][t], then beta*exp(lamx)*k -> W[t][d]
  __shared__ float Ab[64][68];   // A[t][s] -> later Kh[t][d]
  __shared__ float lam[64], lamx[64], lbet[64];
  const long gb = ((long)(b * TT + c * CH) * HH + h) * DD;

  // stage q transposed (bf16 -> fp32) for Qht only
  {
    const int e4 = (tid & 15) * 4;
    const int t0 = tid >> 4;
#pragma unroll
    for (int p = 0; p < 4; ++p) {
      int t = t0 + p * 16;
      ushort4 qv = *(const ushort4*)&q[gb + (long)t * (HH * DD) + e4];
      P1[e4 + 0][t] = b2f(qv.x); P1[e4 + 1][t] = b2f(qv.y);
      P1[e4 + 2][t] = b2f(qv.z); P1[e4 + 3][t] = b2f(qv.w);
    }
  }
  float ldv = 0.f, bv_ = 0.f;
  if (tid < 64) {
    ldv = ldec[(long)(b * TT + c * CH + tid) * HH + h];
    bv_ = beta[(long)(b * TT + c * CH + tid) * HH + h];
    lam[tid] = ldv;
  }
  __syncthreads();
  float lsum = 0.f;
  if (tid < 64) {
    for (int s = 0; s <= tid; ++s) lsum += lam[s];
  }
  __syncthreads();
  if (tid < 64) {
    lam[tid] = lsum;
    lamx[tid] = lsum - ldv;
    lbet[tid] = bv_;
  }
  __syncthreads();

  // MFMA: G = K.K^T, Pm = K.Q^T (each wave owns a 32x32 quadrant).
  {
    const int lane = tid & 63;
    const int wave = tid >> 6;
    const int lr = lane & 15;
    const int kq = lane >> 4;
    const int mwr = (wave >> 1) * 32, mwc = (wave & 1) * 32;
    bf16x8 af[2][2], bk_[2][2], bq_[2][2];
#pragma unroll
    for (int m = 0; m < 2; ++m)
#pragma unroll
      for (int ks = 0; ks < 2; ++ks) {
        long rbase = gb + (long)(mwr + m * 16 + lr) * (HH * DD) + ks * 32 + kq * 8;
        long cbase = gb + (long)(mwc + m * 16 + lr) * (HH * DD) + ks * 32 + kq * 8;
        af[m][ks]  = __builtin_bit_cast(bf16x8, *(const uint4*)&k[rbase]);
        bk_[m][ks] = __builtin_bit_cast(bf16x8, *(const uint4*)&k[cbase]);
        bq_[m][ks] = __builtin_bit_cast(bf16x8, *(const uint4*)&q[cbase]);
      }
    f32x4 gf[2][2] = {}, pf[2][2] = {};
#pragma unroll
    for (int ks = 0; ks < 2; ++ks)
#pragma unroll
      for (int m = 0; m < 2; ++m)
#pragma unroll
        for (int n = 0; n < 2; ++n) {
          gf[m][n] = __builtin_amdgcn_mfma_f32_16x16x32_bf16(
              af[m][ks], bk_[n][ks], gf[m][n], 0, 0, 0);
          pf[m][n] = __builtin_amdgcn_mfma_f32_16x16x32_bf16(
              af[m][ks], bq_[n][ks], pf[m][n], 0, 0, 0);
        }
    u16* btp = Btg + (long)blk * (CH * CH);
#pragma unroll
    for (int m = 0; m < 2; ++m)
#pragma unroll
      for (int n = 0; n < 2; ++n)
#pragma unroll
        for (int r = 0; r < 4; ++r) {
          int t = mwr + m * 16 + kq * 4 + r;   // C row (K index for both)
          int s = mwc + n * 16 + lr;           // C col
          Ab[t][s] = (s < t) ? lbet[t] * expf(lamx[t] - lam[s]) * gf[m][n][r]
                             : 0.f;
          btp[t * 64 + s] = f2bf(
              (t <= s) ? expf(lam[s] - lam[t]) * pf[m][n][r] : 0.f);
        }
  }
  // Qht[d][t] bf16 (from qst in P1)
  {
    u16* qhp = Qhtg + (long)blk * (DD * CH);
    const int t4 = (tid & 15) * 4;
    const int d0 = tid >> 4;
#pragma unroll
    for (int p = 0; p < 4; ++p) {
      int d = d0 + p * 16;
      float4 qv = *(const float4*)&P1[d][t4];
      ushort4 qw;
      qw.x = f2bf(qv.x * expf(lam[t4 + 0]));
      qw.y = f2bf(qv.y * expf(lam[t4 + 1]));
      qw.z = f2bf(qv.z * expf(lam[t4 + 2]));
      qw.w = f2bf(qv.w * expf(lam[t4 + 3]));
      *(ushort4*)&qhp[d * 64 + t4] = qw;
    }
  }
  __syncthreads();
  // re-init: P0[t][e] = beta_t v ; P1[t][d] = beta_t exp(lamx_t) k
  {
    const int e4 = (tid & 15) * 4;
    const int t0 = tid >> 4;
#pragma unroll
    for (int p = 0; p < 4; ++p) {
      int t = t0 + p * 16;
      float bt_ = lbet[t], cx = bt_ * expf(lamx[t]);
      ushort4 vv4 = *(const ushort4*)&v[gb + (long)t * (HH * DD) + e4];
      ushort4 kv4 = *(const ushort4*)&k[gb + (long)t * (HH * DD) + e4];
      float4 vv = make_float4(b2f(vv4.x) * bt_, b2f(vv4.y) * bt_,
                              b2f(vv4.z) * bt_, b2f(vv4.w) * bt_);
      float4 kv = make_float4(b2f(kv4.x) * cx, b2f(kv4.y) * cx,
                              b2f(kv4.z) * cx, b2f(kv4.w) * cx);
      *(float4*)&P0[t][e4] = vv;
      *(float4*)&P1[t][e4] = kv;
    }
  }
  __syncthreads();
  // BLOCKED forward substitution on (I+A): both P0,P1
  {
    const int i = tid >> 5;
    const int j4 = (tid & 31) * 4;
    float* Pj = (j4 < 64) ? (&P0[0][0] + j4) : (&P1[0][0] + (j4 - 64));
#pragma unroll
    for (int base = 0; base < 64; base += 8) {
      const int r = base + i;
      float4 acc = *(const float4*)&Pj[r * 68];
      for (int t = 0; t < base; ++t) {
        float a = Ab[r][t];
        float4 ut = *(const float4*)&Pj[t * 68];
        acc.x -= a * ut.x; acc.y -= a * ut.y;
        acc.z -= a * ut.z; acc.w -= a * ut.w;
      }
      *(float4*)&Pj[r * 68] = acc;
      __syncthreads();
      float4 val[8];
#pragma unroll
      for (int t = 0; t < 8; ++t) {
        float4 vt = *(const float4*)&Pj[(base + t) * 68];
#pragma unroll
        for (int m = 0; m < t; ++m) {
          float a = Ab[base + t][base + m];
          vt.x -= a * val[m].x; vt.y -= a * val[m].y;
          vt.z -= a * val[m].z; vt.w -= a * val[m].w;
        }
        val[t] = vt;
      }
      float4 fin = val[0];
#pragma unroll
      for (int t = 1; t < 8; ++t) if (i == t) fin = val[t];
      __syncthreads();
      *(float4*)&Pj[r * 68] = fin;
      __syncthreads();
    }
  }
  // write U0 (bf16) and Wt (bf16, transposed); stage Kh into Ab
  {
    u16* u0p = U0g + (long)blk * (CH * DD);
    const int e4 = (tid & 15) * 4;
    const int t0 = tid >> 4;
    float lamL = lam[63];
#pragma unroll
    for (int p = 0; p < 4; ++p) {
      int t = t0 + p * 16;
      float4 u4 = *(const float4*)&P0[t][e4];
      ushort4 uw;
      uw.x = f2bf(u4.x); uw.y = f2bf(u4.y);
      uw.z = f2bf(u4.z); uw.w = f2bf(u4.w);
      *(ushort4*)&u0p[t * 64 + e4] = uw;
      float cf = expf(lamL - lam[t]);
      ushort4 kv4 = *(const ushort4*)&k[gb + (long)t * (HH * DD) + e4];
      *(float4*)&Ab[t][e4] = make_float4(b2f(kv4.x) * cf, b2f(kv4.y) * cf,
                                         b2f(kv4.z) * cf, b2f(kv4.w) * cf);
    }
    u16* wtp = Wtg + (long)blk * (DD * CH);
    const int t = tid & 63;
    const int d0 = tid >> 6;
#pragma unroll
    for (int p = 0; p < 16; ++p) {
      int d = d0 + p * 4;
      wtp[d * 64 + t] = f2bf(P1[t][d]);
    }
  }
  __syncthreads();
  // M[d][s] = gL*I - sum_t Kh[t][d]*W[t][s] ; b[d][e] = sum_t Kh[t][d]*U0[t][e]
  {
    float accm[4][4] = {}, accb[4][4] = {};
    for (int t = 0; t < 64; ++t) {
      float4 ka = *(const float4*)&Ab[t][ty * 4];
      float4 wc_ = *(const float4*)&P1[t][tx * 4];
      float4 uv = *(const float4*)&P0[t][tx * 4];
      float kar[4] = {ka.x, ka.y, ka.z, ka.w};
      float wcr[4] = {wc_.x, wc_.y, wc_.z, wc_.w};
      float ucr[4] = {uv.x, uv.y, uv.z, uv.w};
#pragma unroll
      for (int i = 0; i < 4; ++i)
#pragma unroll
        for (int j = 0; j < 4; ++j) {
          accm[i][j] += kar[i] * wcr[j];
          accb[i][j] += kar[i] * ucr[j];
        }
    }
    float gLv = expf(lam[63]);
    float* mp = Mtg + (long)blk * (DD * DD);
    float* bp = bvg + (long)blk * (DD * DD);
#pragma unroll
    for (int i = 0; i < 4; ++i) {
      int rr = ty * 4 + i;    // d
      float4 mv, b4;
      mv.x = ((rr == tx * 4 + 0) ? gLv : 0.f) - accm[i][0];
      mv.y = ((rr == tx * 4 + 1) ? gLv : 0.f) - accm[i][1];
      mv.z = ((rr == tx * 4 + 2) ? gLv : 0.f) - accm[i][2];
      mv.w = ((rr == tx * 4 + 3) ? gLv : 0.f) - accm[i][3];
      *(float4*)&mp[rr * 64 + tx * 4] = mv;   // [d][s]
      b4.x = accb[i][0]; b4.y = accb[i][1];
      b4.z = accb[i][2]; b4.w = accb[i][3];
      *(float4*)&bp[rr * 64 + tx * 4] = b4;   // [d][e]
    }
  }
}

// ---------------------------------------------------------------------------
// Sequential pass v5: S_{c+1} = M_c S_c + b_c, e-split 16-way (512 blocks,
// 2 blocks/CU). M quarter-row lives in REGISTERS (prefetched; never staged
// to LDS). Thread (wave w, lane l): d = w*16+(l&15), q = l>>4 owns
// M[d][16q..16q+15]; partial sums over its s-quarter reduce IN-WAVE via
// shfl_xor(16/32) (q-groups are lanes l^16/l^32/l^48). Only Ss[4][68] in
// LDS: reads are 16-lane broadcast (free), writes conflict-free.
// ---------------------------------------------------------------------------
__global__ __launch_bounds__(256) void gdn_seq5(
    const float* __restrict__ Mtg, const float* __restrict__ bvg,
    float* __restrict__ Sall) {
  const int bh = blockIdx.x & 31;         // XCD/L2-sharing swizzle
  const int esec = blockIdx.x >> 5;       // 0..15
  const int tid = threadIdx.x;
  const int lane = tid & 63;
  const int w = tid >> 6;
  const int d = w * 16 + (lane & 15);
  const int q = lane >> 4;                // 0..3 (s-quarter)
  const int eo = esec * 4;
  __shared__ float Ss[4][68];             // [e][s]
  float S0 = 0.f, S1 = 0.f, S2 = 0.f, S3 = 0.f;
  float4 mreg[4], mnext[4];
  float4 breg, bnext;
  {
    const float* mt0 = Mtg + (long)bh * NC * 4096;
#pragma unroll
    for (int p = 0; p < 4; ++p)
      mreg[p] = *(const float4*)&mt0[d * 64 + q * 16 + p * 4];
    breg = *(const float4*)&bvg[(long)bh * NC * 4096 + d * 64 + eo];
  }
  for (int c = 0; c < NC; ++c) {
    const long cb = (long)bh * NC + c;
    // publish chunk-start state S_c
    if (q == 0) {
      *(float4*)&Sall[cb * 4096 + d * 64 + eo] = make_float4(S0, S1, S2, S3);
      Ss[0][d] = S0; Ss[1][d] = S1; Ss[2][d] = S2; Ss[3][d] = S3;
    }
    __syncthreads();
    if (c + 1 < NC) {                     // prefetch next M,b under compute
      const float* mtn = Mtg + (cb + 1) * 4096;
#pragma unroll
      for (int p = 0; p < 4; ++p)
        mnext[p] = *(const float4*)&mtn[d * 64 + q * 16 + p * 4];
      bnext = *(const float4*)&bvg[(cb + 1) * 4096 + d * 64 + eo];
    }
    // partials over this thread's s-quarter
    float p0 = 0.f, p1 = 0.f, p2 = 0.f, p3 = 0.f;
#pragma unroll
    for (int j = 0; j < 4; ++j) {
      float4 m4 = mreg[j];
      float4 s0 = *(const float4*)&Ss[0][q * 16 + j * 4];
      float4 s1 = *(const float4*)&Ss[1][q * 16 + j * 4];
      float4 s2 = *(const float4*)&Ss[2][q * 16 + j * 4];
      float4 s3 = *(const float4*)&Ss[3][q * 16 + j * 4];
      p0 += m4.x * s0.x + m4.y * s0.y + m4.z * s0.z + m4.w * s0.w;
      p1 += m4.x * s1.x + m4.y * s1.y + m4.z * s1.z + m4.w * s1.w;
      p2 += m4.x * s2.x + m4.y * s2.y + m4.z * s2.z + m4.w * s2.w;
      p3 += m4.x * s3.x + m4.y * s3.y + m4.z * s3.z + m4.w * s3.w;
    }
    // in-wave butterfly across the 4 q-groups
    p0 += __shfl_xor(p0, 16); p0 += __shfl_xor(p0, 32);
    p1 += __shfl_xor(p1, 16); p1 += __shfl_xor(p1, 32);
    p2 += __shfl_xor(p2, 16); p2 += __shfl_xor(p2, 32);
    p3 += __shfl_xor(p3, 16); p3 += __shfl_xor(p3, 32);
    S0 = breg.x + p0; S1 = breg.y + p1;
    S2 = breg.z + p2; S3 = breg.w + p3;
    __syncthreads();                      // all Ss reads done before rewrite
    mreg[0] = mnext[0]; mreg[1] = mnext[1];
    mreg[2] = mnext[2]; mreg[3] = mnext[3];
    breg = bnext;
  }
}

// ---------------------------------------------------------------------------
// Fully parallel per-chunk output: u = U0 - W.S ; o = B.u + Qh.S
// ---------------------------------------------------------------------------
__global__ __launch_bounds__(256) void gdn_out(
    const u16* __restrict__ U0g, const u16* __restrict__ Wtg,
    const u16* __restrict__ Btg, const u16* __restrict__ Qhtg,
    const float* __restrict__ Sall, u16* __restrict__ o) {
  const int blk = blockIdx.x;
  const int bh = blk / NC, c = blk % NC;
  const int b = bh >> 4, h = bh & 15;
  const int tid = threadIdx.x;
  const int tx = tid & 15, ty = tid >> 4;
  __shared__ float S[64][64];
  __shared__ float ub[64][64];
  __shared__ float op[64][64];
  const int e4 = (tid & 15) * 4;
  const int t0s = tid >> 4;
  {
    const int r = tid >> 2, qq = (tid & 3) * 16;
#pragma unroll
    for (int p = 0; p < 4; ++p)
      *(float4*)&S[r][qq + p * 4] =
          *(const float4*)&Sall[(long)blk * 4096 + r * 64 + qq + p * 4];
  }
#pragma unroll
  for (int p = 0; p < 4; ++p) {
    int t = t0s + p * 16;
    ushort4 w4 = *(const ushort4*)&Wtg[(long)blk * 4096 + t * 64 + e4];
    *(float4*)&op[t][e4] = make_float4(b2f(w4.x), b2f(w4.y), b2f(w4.z), b2f(w4.w));
  }
  __syncthreads();
  float acc[4][4];
#pragma unroll
  for (int i = 0; i < 4; ++i) {
    ushort4 u4 = *(const ushort4*)&U0g[(long)blk * 4096 + (ty * 4 + i) * 64 + tx * 4];
    acc[i][0] = b2f(u4.x); acc[i][1] = b2f(u4.y);
    acc[i][2] = b2f(u4.z); acc[i][3] = b2f(u4.w);
  }
  for (int d = 0; d < 64; ++d) {
    float4 a4 = *(const float4*)&op[d][ty * 4];
    float4 b4 = *(const float4*)&S[d][tx * 4];
    float ar[4] = {a4.x, a4.y, a4.z, a4.w};
    float br[4] = {b4.x, b4.y, b4.z, b4.w};
#pragma unroll
    for (int i = 0; i < 4; ++i)
#pragma unroll
      for (int j = 0; j < 4; ++j) acc[i][j] -= ar[i] * br[j];
  }
#pragma unroll
  for (int i = 0; i < 4; ++i)
    *(float4*)&ub[ty * 4 + i][tx * 4] =
        make_float4(acc[i][0], acc[i][1], acc[i][2], acc[i][3]);
  __syncthreads();
#pragma unroll
  for (int p = 0; p < 4; ++p) {
    int t = t0s + p * 16;
    ushort4 w4 = *(const ushort4*)&Btg[(long)blk * 4096 + t * 64 + e4];
    *(float4*)&op[t][e4] = make_float4(b2f(w4.x), b2f(w4.y), b2f(w4.z), b2f(w4.w));
  }
  __syncthreads();
  float acco[4][4] = {};
  for (int s = 0; s < 64; ++s) {
    float4 a4 = *(const float4*)&op[s][ty * 4];
    float4 b4 = *(const float4*)&ub[s][tx * 4];
    float ar[4] = {a4.x, a4.y, a4.z, a4.w};
    float br[4] = {b4.x, b4.y, b4.z, b4.w};
#pragma unroll
    for (int i = 0; i < 4; ++i)
#pragma unroll
      for (int j = 0; j < 4; ++j) acco[i][j] += ar[i] * br[j];
  }
  __syncthreads();
#pragma unroll
  for (int p = 0; p < 4; ++p) {
    int t = t0s + p * 16;
    ushort4 w4 = *(const ushort4*)&Qhtg[(long)blk * 4096 + t * 64 + e4];
    *(float4*)&op[t][e4] = make_float4(b2f(w4.x), b2f(w4.y), b2f(w4.z), b2f(w4.w));
  }
  __syncthreads();
  for (int d = 0; d < 64; ++d) {
    float4 a4 = *(const float4*)&op[d][ty * 4];
    float4 b4 = *(const float4*)&S[d][tx * 4];
    float ar[4] = {a4.x, a4.y, a4.z, a4.w};
    float br[4] = {b4.x, b4.y, b4.z, b4.w};
#pragma unroll
    for (int i = 0; i < 4; ++i)
#pragma unroll
      for (int j = 0; j < 4; ++j) acco[i][j] += ar[i] * br[j];
  }
#pragma unroll
  for (int i = 0; i < 4; ++i) {
    int t = ty * 4 + i;
    ushort4 ow;
    ow.x = f2bf(acco[i][0]); ow.y = f2bf(acco[i][1]);
    ow.z = f2bf(acco[i][2]); ow.w = f2bf(acco[i][3]);
    *(ushort4*)&o[((long)(b * TT + c * CH + t) * HH + h) * DD + tx * 4] = ow;
  }
}

// ---------------------------------------------------------------------------
// gated = rms_norm(o) * o_norm_scale * silu(g), bf16 in/out.
// ---------------------------------------------------------------------------
__global__ __launch_bounds__(256) void norm_gate(
    const u16* __restrict__ o, const u16* __restrict__ g,
    const float* __restrict__ scale, u16* __restrict__ outb) {
  const int bt = blockIdx.x;
  const int tid = threadIdx.x;
  const int c4 = tid * 4;
  ushort4 o4u = *(const ushort4*)&o[(long)bt * INNER + c4];
  float4 o4 = make_float4(b2f(o4u.x), b2f(o4u.y), b2f(o4u.z), b2f(o4u.w));
  float ssq = o4.x * o4.x + o4.y * o4.y + o4.z * o4.z + o4.w * o4.w;
  ssq += __shfl_xor(ssq, 1);
  ssq += __shfl_xor(ssq, 2);
  ssq += __shfl_xor(ssq, 4);
  ssq += __shfl_xor(ssq, 8);
  float r = rsqrtf(ssq * (1.f / 64.f) + EPSF);
  float4 sc = *(const float4*)&scale[c4 & 63];
  ushort4 g4u = *(const ushort4*)&g[(long)bt * INNER + c4];
  float4 g4 = make_float4(b2f(g4u.x), b2f(g4u.y), b2f(g4u.z), b2f(g4u.w));
  ushort4 res;
  res.x = f2bf(o4.x * r * sc.x * (g4.x / (1.f + expf(-g4.x))));
  res.y = f2bf(o4.y * r * sc.y * (g4.y / (1.f + expf(-g4.y))));
  res.z = f2bf(o4.z * r * sc.z * (g4.z / (1.f + expf(-g4.z))));
  res.w = f2bf(o4.w * r * sc.w * (g4.w / (1.f + expf(-g4.w))));
  *(ushort4*)&outb[(long)bt * INNER + c4] = res;
}

// ---------------------------------------------------------------------------
extern "C" void kernel_launch(void* const* d_in, const int* in_sizes, int n_in,
                              void* d_out, int out_size, void* d_ws,
                              size_t ws_size, hipStream_t stream) {
  const float* x      = (const float*)d_in[0];
  const float* wq     = (const float*)d_in[1];
  const float* wk     = (const float*)d_in[2];
  const float* wv     = (const float*)d_in[3];
  const float* wg     = (const float*)d_in[4];
  const float* wo     = (const float*)d_in[5];
  const float* wa     = (const float*)d_in[6];
  const float* wb     = (const float*)d_in[7];
  const float* cqw    = (const float*)d_in[8];
  const float* cqb    = (const float*)d_in[9];
  const float* ckw    = (const float*)d_in[10];
  const float* ckb    = (const float*)d_in[11];
  const float* cvw    = (const float*)d_in[12];
  const float* cvb    = (const float*)d_in[13];
  const float* A_log  = (const float*)d_in[14];
  const float* dtb    = (const float*)d_in[15];
  const float* oscale = (const float*)d_in[16];
  float* out = (float*)d_out;

  u16 *pqb, *pkb, *pvb, *qb, *kb, *vb, *gb, *ob;
  u16 *xb, *wbb, *wob, *gatedb, *U0, *Wt, *Bt, *Qht;
  float *beta, *ldec, *Mc, *bc, *Sall;
  hipGetSymbolAddress((void**)&pqb,   HIP_SYMBOL(g_pqb));
  hipGetSymbolAddress((void**)&pkb,   HIP_SYMBOL(g_pkb));
  hipGetSymbolAddress((void**)&pvb,   HIP_SYMBOL(g_pvb));
  hipGetSymbolAddress((void**)&qb,    HIP_SYMBOL(g_qb));
  hipGetSymbolAddress((void**)&kb,    HIP_SYMBOL(g_kb));
  hipGetSymbolAddress((void**)&vb,    HIP_SYMBOL(g_vb));
  hipGetSymbolAddress((void**)&gb,    HIP_SYMBOL(g_gb));
  hipGetSymbolAddress((void**)&ob,    HIP_SYMBOL(g_ob));
  hipGetSymbolAddress((void**)&beta,  HIP_SYMBOL(g_beta));
  hipGetSymbolAddress((void**)&ldec,  HIP_SYMBOL(g_ldec));
  hipGetSymbolAddress((void**)&xb,    HIP_SYMBOL(g_xb));
  hipGetSymbolAddress((void**)&wbb,   HIP_SYMBOL(g_wbb));
  hipGetSymbolAddress((void**)&wob,   HIP_SYMBOL(g_wob));
  hipGetSymbolAddress((void**)&gatedb,HIP_SYMBOL(g_gatedb));
  hipGetSymbolAddress((void**)&U0,    HIP_SYMBOL(g_U0));
  hipGetSymbolAddress((void**)&Wt,    HIP_SYMBOL(g_Wt));
  hipGetSymbolAddress((void**)&Bt,    HIP_SYMBOL(g_Bt));
  hipGetSymbolAddress((void**)&Qht,   HIP_SYMBOL(g_Qht));
  hipGetSymbolAddress((void**)&Mc,    HIP_SYMBOL(g_Mc));
  hipGetSymbolAddress((void**)&bc,    HIP_SYMBOL(g_bc));
  hipGetSymbolAddress((void**)&Sall,  HIP_SYMBOL(g_Sall));

  cast_all<<<9216, 256, 0, stream>>>(x, wq, wk, wv, wg, wo, xb, wbb, wob);

  // fused QKVG projection -> bf16 outputs (BK=64, XCD serpentine)
  bgemm4<u16, 32><<<1024, 256, 0, stream>>>(xb, wbb, pqb, pkb, pvb, gb);

  conv3<<<dim3(BT, 3), 256, 0, stream>>>(pqb, pkb, pvb,
                                         cqw, cqb, ckw, ckb, cvw, cvb,
                                         qb, kb, vb);
  proj_ab3<<<BT / 8, 256, 0, stream>>>(x, wa, wb, dtb, A_log, beta, ldec);

  gdn_prep<<<NCHK, 256, 0, stream>>>(qb, kb, vb, beta, ldec,
                                     U0, Wt, Bt, Qht, Mc, bc);
  gdn_seq5<<<NBH * 16, 256, 0, stream>>>(Mc, bc, Sall);
  gdn_out<<<NCHK, 256, 0, stream>>>(U0, Wt, Bt, Qht, Sall, ob);

  norm_gate<<<BT, 256, 0, stream>>>(ob, gb, oscale, gatedb);

  // final projection: out = gated_bf16 @ wo^T (fp32 out, 256 blocks)
  bgemm4<float, 8><<<256, 256, 0, stream>>>(gatedb, wob, out, out, out, out);
}

// Round 19
// 270.268 us; speedup vs baseline: 1.1043x; 1.0126x over previous
//
#include <hip/hip_runtime.h>
#include <math.h>

#define BB 2
#define TT 2048
#define CC 1024
#define HH 16
#define DD 64
#define INNER 1024
#define BT (BB*TT)   /* 4096 */
#define EPSF 1e-6f
#define CH 64
#define NC (TT/CH)        /* 32 */
#define NBH (BB*HH)       /* 32 */
#define NCHK (NBH*NC)     /* 1024 */

typedef unsigned short u16;
typedef __bf16 bf16x8 __attribute__((ext_vector_type(8)));
typedef float f32x4 __attribute__((ext_vector_type(4)));

__device__ inline u16 f2bf(float f) {   // RNE float->bf16
  unsigned u = __builtin_bit_cast(unsigned, f);
  return (u16)((u + 0x7fffu + ((u >> 16) & 1u)) >> 16);
}
__device__ inline float b2f(u16 b) {
  unsigned u = ((unsigned)b) << 16;
  return __builtin_bit_cast(float, u);
}
__device__ inline void gll16(const u16* g, u16* l) {
  __builtin_amdgcn_global_load_lds(
      (const __attribute__((address_space(1))) void*)g,
      (__attribute__((address_space(3))) void*)l, 16, 0, 0);
}

// Static device scratch (fully overwritten every call; deterministic).
__device__ u16   g_pqb[BT * INNER];      // pre_q bf16
__device__ u16   g_pkb[BT * INNER];      // pre_k
__device__ u16   g_pvb[BT * INNER];      // pre_v
__device__ u16   g_qb [BT * INNER];      // q bf16 (post conv+l2)
__device__ u16   g_kb [BT * INNER];
__device__ u16   g_vb [BT * INNER];
__device__ u16   g_gb [BT * INNER];      // g projection bf16
__device__ float g_beta[BT * HH];
__device__ float g_ldec[BT * HH];
__device__ u16   g_xb[BT * CC];          // x in bf16
__device__ u16   g_wbb[4 * INNER * CC];  // wq|wk|wv|wg in bf16
__device__ u16   g_wob[CC * INNER];      // wo in bf16
__device__ u16   g_gatedb[BT * INNER];   // gated activations bf16
// per-chunk tensors: output path bf16, state path fp32
__device__ u16   g_U0 [NCHK * CH * DD];
__device__ u16   g_Wt [NCHK * DD * CH];
__device__ u16   g_Bt [NCHK * CH * CH];
__device__ u16   g_Qht[NCHK * DD * CH];
__device__ float g_Mc [NCHK * DD * DD];  // M[d][s] row-major (d = row)
__device__ float g_bc [NCHK * DD * DD];  // b[d][e]
__device__ float g_Sall[NCHK * DD * DD]; // chunk-start states [d][e]

// ---------------------------------------------------------------------------
// Fused cast of x and all weights to bf16.
// ---------------------------------------------------------------------------
__global__ __launch_bounds__(256) void cast_all(
    const float* __restrict__ x, const float* __restrict__ wq,
    const float* __restrict__ wk, const float* __restrict__ wv,
    const float* __restrict__ wg, const float* __restrict__ wo,
    u16* __restrict__ xb, u16* __restrict__ wb, u16* __restrict__ wob) {
  long i = ((long)blockIdx.x * 256 + threadIdx.x) * 4;
  const float* src;
  u16* dst;
  if (i < 4194304)      { src = x  + i;             dst = xb + i; }
  else if (i < 5242880) { src = wq + (i - 4194304); dst = wb + (i - 4194304); }
  else if (i < 6291456) { src = wk + (i - 5242880); dst = wb + (i - 4194304); }
  else if (i < 7340032) { src = wv + (i - 6291456); dst = wb + (i - 4194304); }
  else if (i < 8388608) { src = wg + (i - 7340032); dst = wb + (i - 4194304); }
  else                  { src = wo + (i - 8388608); dst = wob + (i - 8388608); }
  float4 v = *(const float4*)src;
  ushort4 o;
  o.x = f2bf(v.x); o.y = f2bf(v.y); o.z = f2bf(v.z); o.w = f2bf(v.w);
  *(ushort4*)dst = o;
}

// ---------------------------------------------------------------------------
// bf16 MFMA GEMM: BK=64, source-swizzled LDS (0 bank conflicts), XCD
// serpentine region remap. C[m,n] = sum_k A[m,k]*B[n,k], K=1024, 128x128.
// ---------------------------------------------------------------------------
template <typename OutT, int NBN>
__global__ __launch_bounds__(256) void bgemm4(
    const u16* __restrict__ A, const u16* __restrict__ B,
    OutT* __restrict__ c0, OutT* __restrict__ c1,
    OutT* __restrict__ c2, OutT* __restrict__ c3) {
  __shared__ u16 lA[128 * 64];
  __shared__ u16 lB[128 * 64];
  const int tid = threadIdx.x;
  const int bid = blockIdx.x;
  int bm, bn;
  if constexpr (NBN == 32) {
    const int xcd = bid & 7;
    const int idx = bid >> 3;          // 0..127
    const int in_ = idx >> 4;          // 0..7
    int im = idx & 15;
    im = (in_ & 1) ? (15 - im) : im;
    bm = ((xcd >> 2) * 16 + im) * 128;
    bn = ((xcd & 3) * 8 + in_) * 128;
  } else {
    const int xcd = bid & 7;
    const int idx = bid >> 3;          // 0..31
    const int in_ = idx >> 2;          // 0..7
    int im = idx & 3;
    im = (in_ & 1) ? (3 - im) : im;
    bm = (xcd * 4 + im) * 128;
    bn = in_ * 128;
  }
  const int lane = tid & 63;
  const int wave = tid >> 6;
  const int wr = (wave >> 1) * 64, wc = (wave & 1) * 64;
  const int lr = lane & 15;
  const int kq = lane >> 4;            // 0..3
  const int srow0 = tid >> 3;          // 0..31
  const int gcol = ((tid & 7) ^ (srow0 & 7)) * 8;
  const u16* gA0 = &A[(long)(bm + srow0) * CC + gcol];
  const u16* gB0 = &B[(long)(bn + srow0) * CC + gcol];
  u16* lA0 = &lA[tid * 8];
  u16* lB0 = &lB[tid * 8];
  f32x4 acc[4][4] = {};

  for (int k0 = 0; k0 < CC; k0 += 64) {
    __syncthreads();                  // protect prev-iter LDS reads
#pragma unroll
    for (int p = 0; p < 4; ++p) {
      gll16(gA0 + (long)p * 32 * CC + k0, lA0 + p * 2048);
      gll16(gB0 + (long)p * 32 * CC + k0, lB0 + p * 2048);
    }
    __syncthreads();                  // drains vmcnt before reads
#pragma unroll
    for (int ks = 0; ks < 2; ++ks) {
      const int sl = ((ks * 4 + kq) ^ (lr & 7)) * 8;
      bf16x8 af[4], bf_[4];
#pragma unroll
      for (int m = 0; m < 4; ++m)
        af[m] = __builtin_bit_cast(bf16x8,
            *(const uint4*)&lA[(wr + m * 16 + lr) * 64 + sl]);
#pragma unroll
      for (int n = 0; n < 4; ++n)
        bf_[n] = __builtin_bit_cast(bf16x8,
            *(const uint4*)&lB[(wc + n * 16 + lr) * 64 + sl]);
#pragma unroll
      for (int m = 0; m < 4; ++m)
#pragma unroll
        for (int n = 0; n < 4; ++n)
          acc[m][n] = __builtin_amdgcn_mfma_f32_16x16x32_bf16(
              af[m], bf_[n], acc[m][n], 0, 0, 0);
    }
  }
  OutT* cp = (bn < 1024) ? c0 : (bn < 2048) ? c1 : (bn < 3072) ? c2 : c3;
  const int ccol0 = (bn & 1023) + wc;
  const int crow0 = bm + wr + kq * 4;
#pragma unroll
  for (int m = 0; m < 4; ++m)
#pragma unroll
    for (int n = 0; n < 4; ++n) {
      int col = ccol0 + n * 16 + lr;
#pragma unroll
      for (int r = 0; r < 4; ++r) {
        long idx2 = (long)(crow0 + m * 16 + r) * INNER + col;
        if constexpr (sizeof(OutT) == 2) cp[idx2] = f2bf(acc[m][n][r]);
        else                             cp[idx2] = acc[m][n][r];
      }
    }
}

// ---------------------------------------------------------------------------
// Fused causal depthwise conv1d(K=4) + SiLU (+per-head L2 norm for q,k).
// ---------------------------------------------------------------------------
__global__ __launch_bounds__(256) void conv3(
    const u16* __restrict__ pq, const u16* __restrict__ pk,
    const u16* __restrict__ pv,
    const float* __restrict__ cqw, const float* __restrict__ cqb,
    const float* __restrict__ ckw, const float* __restrict__ ckb,
    const float* __restrict__ cvw, const float* __restrict__ cvb,
    u16* __restrict__ oq, u16* __restrict__ ok, u16* __restrict__ ov) {
  const int which = blockIdx.y;
  const u16* pre = which == 0 ? pq : which == 1 ? pk : pv;
  const float* cw = which == 0 ? cqw : which == 1 ? ckw : cvw;
  const float* cb = which == 0 ? cqb : which == 1 ? ckb : cvb;
  u16* out = which == 0 ? oq : which == 1 ? ok : ov;
  const int do_l2 = (which < 2);

  const int bt = blockIdx.x;
  const int b = bt / TT, t = bt % TT;
  const int tid = threadIdx.x;
  const int c4 = tid * 4;
  float xt[4][4];
#pragma unroll
  for (int j = 0; j < 4; ++j) {
    int ts = t - 3 + j;
    if (ts >= 0) {
      ushort4 u = *(const ushort4*)&pre[(long)(b * TT + ts) * INNER + c4];
      xt[j][0] = b2f(u.x); xt[j][1] = b2f(u.y);
      xt[j][2] = b2f(u.z); xt[j][3] = b2f(u.w);
    } else {
      xt[j][0] = xt[j][1] = xt[j][2] = xt[j][3] = 0.f;
    }
  }
  float4 bias4 = *(const float4*)&cb[c4];
  const float* bp = (const float*)&bias4;
  float y[4];
#pragma unroll
  for (int ci = 0; ci < 4; ++ci) {
    float4 w4 = *(const float4*)&cw[(c4 + ci) * 4];
    float acc = bp[ci];
    acc += w4.x * xt[0][ci];
    acc += w4.y * xt[1][ci];
    acc += w4.z * xt[2][ci];
    acc += w4.w * xt[3][ci];
    y[ci] = acc / (1.f + expf(-acc));   // SiLU
  }
  if (do_l2) {
    float ssq = y[0]*y[0] + y[1]*y[1] + y[2]*y[2] + y[3]*y[3];
    ssq += __shfl_xor(ssq, 1);
    ssq += __shfl_xor(ssq, 2);
    ssq += __shfl_xor(ssq, 4);
    ssq += __shfl_xor(ssq, 8);   // 16 threads = one head (64 channels)
    float r = rsqrtf(ssq + EPSF);
    y[0] *= r; y[1] *= r; y[2] *= r; y[3] *= r;
  }
  ushort4 res;
  res.x = f2bf(y[0]); res.y = f2bf(y[1]);
  res.z = f2bf(y[2]); res.w = f2bf(y[3]);
  *(ushort4*)&out[(long)bt * INNER + c4] = res;
}

// ---------------------------------------------------------------------------
// beta = sigmoid(x@wb.T); ldec = -exp(A_log)*softplus(x@wa.T + dt_bias)
// ---------------------------------------------------------------------------
__global__ __launch_bounds__(256) void proj_ab3(
    const float* __restrict__ x, const float* __restrict__ wa,
    const float* __restrict__ wb, const float* __restrict__ dt_bias,
    const float* __restrict__ A_log, float* __restrict__ beta,
    float* __restrict__ ldec) {
  const int m0 = blockIdx.x * 8;
  const int tid = threadIdx.x;
  __shared__ float xs[8][132];
  __shared__ float ws[32][132];
  const int row = tid >> 5;
  const int col = tid & 31;
  float a0 = 0.f, a1 = 0.f, a2 = 0.f, a3 = 0.f;
  const int sxr = tid >> 5, sxc = (tid & 31) * 4;
  for (int k0 = 0; k0 < CC; k0 += 128) {
    __syncthreads();
    *(float4*)&xs[sxr][sxc] = *(const float4*)&x[(long)(m0 + sxr) * CC + k0 + sxc];
#pragma unroll
    for (int p = 0; p < 4; ++p) {
      int idx = tid + p * 256;
      int wr = idx >> 5, wc4 = (idx & 31) * 4;
      const float* wsrc = (wr < 16) ? &wa[(long)wr * CC] : &wb[(long)(wr - 16) * CC];
      *(float4*)&ws[wr][wc4] = *(const float4*)&wsrc[k0 + wc4];
    }
    __syncthreads();
#pragma unroll
    for (int kk = 0; kk < 128; kk += 16) {
      float4 x0 = *(const float4*)&xs[row][kk + 0];
      float4 w0 = *(const float4*)&ws[col][kk + 0];
      float4 x1 = *(const float4*)&xs[row][kk + 4];
      float4 w1 = *(const float4*)&ws[col][kk + 4];
      float4 x2 = *(const float4*)&xs[row][kk + 8];
      float4 w2 = *(const float4*)&ws[col][kk + 8];
      float4 x3 = *(const float4*)&xs[row][kk + 12];
      float4 w3 = *(const float4*)&ws[col][kk + 12];
      a0 += x0.x * w0.x + x0.y * w0.y + x0.z * w0.z + x0.w * w0.w;
      a1 += x1.x * w1.x + x1.y * w1.y + x1.z * w1.z + x1.w * w1.w;
      a2 += x2.x * w2.x + x2.y * w2.y + x2.z * w2.z + x2.w * w2.w;
      a3 += x3.x * w3.x + x3.y * w3.y + x3.z * w3.z + x3.w * w3.w;
    }
  }
  float acc = (a0 + a1) + (a2 + a3);
  const int m = m0 + row;
  if (col < 16) {
    float a = acc + dt_bias[col];
    float sp = fmaxf(a, 0.f) + log1pf(expf(-fabsf(a)));
    ldec[(long)m * HH + col] = -expf(A_log[col]) * sp;
  } else {
    beta[(long)m * HH + (col - 16)] = 1.f / (1.f + expf(-acc));
  }
}

// ---------------------------------------------------------------------------
// Per-chunk parallel precompute. grid = NCHK (1024), 256 threads.
// G/Pm via MFMA; substitution BLOCKED BS=16 (12 barriers), bit-identical
// order (t ascending per row); M/b fp32-exact.
// ---------------------------------------------------------------------------
__global__ __launch_bounds__(256) void gdn_prep(
    const u16* __restrict__ q, const u16* __restrict__ k,
    const u16* __restrict__ v, const float* __restrict__ beta,
    const float* __restrict__ ldec,
    u16* __restrict__ U0g, u16* __restrict__ Wtg, u16* __restrict__ Btg,
    u16* __restrict__ Qhtg, float* __restrict__ Mtg, float* __restrict__ bvg) {
  const int blk = blockIdx.x;
  const int bh = blk / NC, c = blk % NC;
  const int b = bh >> 4, h = bh & 15;
  const int tid = threadIdx.x;
  const int tx = tid & 15, ty = tid >> 4;
  __shared__ float P0[64][68];   // beta*v  -> U0[t][e]
  __shared__ float P1[64][68];   // qst[d][t], then beta*exp(lamx)*k -> W[t][d]
  __shared__ float Ab[64][68];   // A[t][s] -> later Kh[t][d]
  __shared__ float lam[64], lamx[64], lbet[64];
  const long gb = ((long)(b * TT + c * CH) * HH + h) * DD;

  // stage q transposed (bf16 -> fp32) for Qht only
  {
    const int e4 = (tid & 15) * 4;
    const int t0 = tid >> 4;
#pragma unroll
    for (int p = 0; p < 4; ++p) {
      int t = t0 + p * 16;
      ushort4 qv = *(const ushort4*)&q[gb + (long)t * (HH * DD) + e4];
      P1[e4 + 0][t] = b2f(qv.x); P1[e4 + 1][t] = b2f(qv.y);
      P1[e4 + 2][t] = b2f(qv.z); P1[e4 + 3][t] = b2f(qv.w);
    }
  }
  float ldv = 0.f, bv_ = 0.f;
  if (tid < 64) {
    ldv = ldec[(long)(b * TT + c * CH + tid) * HH + h];
    bv_ = beta[(long)(b * TT + c * CH + tid) * HH + h];
    lam[tid] = ldv;
  }
  __syncthreads();
  float lsum = 0.f;
  if (tid < 64) {
    for (int s = 0; s <= tid; ++s) lsum += lam[s];
  }
  __syncthreads();
  if (tid < 64) {
    lam[tid] = lsum;
    lamx[tid] = lsum - ldv;
    lbet[tid] = bv_;
  }
  __syncthreads();

  // MFMA: G = K.K^T, Pm = K.Q^T (each wave owns a 32x32 quadrant).
  {
    const int lane = tid & 63;
    const int wave = tid >> 6;
    const int lr = lane & 15;
    const int kq = lane >> 4;
    const int mwr = (wave >> 1) * 32, mwc = (wave & 1) * 32;
    bf16x8 af[2][2], bk_[2][2], bq_[2][2];
#pragma unroll
    for (int m = 0; m < 2; ++m)
#pragma unroll
      for (int ks = 0; ks < 2; ++ks) {
        long rbase = gb + (long)(mwr + m * 16 + lr) * (HH * DD) + ks * 32 + kq * 8;
        long cbase = gb + (long)(mwc + m * 16 + lr) * (HH * DD) + ks * 32 + kq * 8;
        af[m][ks]  = __builtin_bit_cast(bf16x8, *(const uint4*)&k[rbase]);
        bk_[m][ks] = __builtin_bit_cast(bf16x8, *(const uint4*)&k[cbase]);
        bq_[m][ks] = __builtin_bit_cast(bf16x8, *(const uint4*)&q[cbase]);
      }
    f32x4 gf[2][2] = {}, pf[2][2] = {};
#pragma unroll
    for (int ks = 0; ks < 2; ++ks)
#pragma unroll
      for (int m = 0; m < 2; ++m)
#pragma unroll
        for (int n = 0; n < 2; ++n) {
          gf[m][n] = __builtin_amdgcn_mfma_f32_16x16x32_bf16(
              af[m][ks], bk_[n][ks], gf[m][n], 0, 0, 0);
          pf[m][n] = __builtin_amdgcn_mfma_f32_16x16x32_bf16(
              af[m][ks], bq_[n][ks], pf[m][n], 0, 0, 0);
        }
    u16* btp = Btg + (long)blk * (CH * CH);
#pragma unroll
    for (int m = 0; m < 2; ++m)
#pragma unroll
      for (int n = 0; n < 2; ++n)
#pragma unroll
        for (int r = 0; r < 4; ++r) {
          int t = mwr + m * 16 + kq * 4 + r;   // C row (K index for both)
          int s = mwc + n * 16 + lr;           // C col
          Ab[t][s] = (s < t) ? lbet[t] * expf(lamx[t] - lam[s]) * gf[m][n][r]
                             : 0.f;
          btp[t * 64 + s] = f2bf(
              (t <= s) ? expf(lam[s] - lam[t]) * pf[m][n][r] : 0.f);
        }
  }
  // Qht[d][t] bf16 (from qst in P1)
  {
    u16* qhp = Qhtg + (long)blk * (DD * CH);
    const int t4 = (tid & 15) * 4;
    const int d0 = tid >> 4;
#pragma unroll
    for (int p = 0; p < 4; ++p) {
      int d = d0 + p * 16;
      float4 qv = *(const float4*)&P1[d][t4];
      ushort4 qw;
      qw.x = f2bf(qv.x * expf(lam[t4 + 0]));
      qw.y = f2bf(qv.y * expf(lam[t4 + 1]));
      qw.z = f2bf(qv.z * expf(lam[t4 + 2]));
      qw.w = f2bf(qv.w * expf(lam[t4 + 3]));
      *(ushort4*)&qhp[d * 64 + t4] = qw;
    }
  }
  __syncthreads();
  // re-init: P0[t][e] = beta_t v ; P1[t][d] = beta_t exp(lamx_t) k
  {
    const int e4 = (tid & 15) * 4;
    const int t0 = tid >> 4;
#pragma unroll
    for (int p = 0; p < 4; ++p) {
      int t = t0 + p * 16;
      float bt_ = lbet[t], cx = bt_ * expf(lamx[t]);
      ushort4 vv4 = *(const ushort4*)&v[gb + (long)t * (HH * DD) + e4];
      ushort4 kv4 = *(const ushort4*)&k[gb + (long)t * (HH * DD) + e4];
      float4 vv = make_float4(b2f(vv4.x) * bt_, b2f(vv4.y) * bt_,
                              b2f(vv4.z) * bt_, b2f(vv4.w) * bt_);
      float4 kv = make_float4(b2f(kv4.x) * cx, b2f(kv4.y) * cx,
                              b2f(kv4.z) * cx, b2f(kv4.w) * cx);
      *(float4*)&P0[t][e4] = vv;
      *(float4*)&P1[t][e4] = kv;
    }
  }
  __syncthreads();
  // BLOCKED forward substitution on (I+A), BS=16: thread (i, j4) owns rows
  // base+i and base+i+8; summation t ascending per row (bit-identical).
  {
    const int i = tid >> 5;
    const int j4 = (tid & 31) * 4;
    float* Pj = (j4 < 64) ? (&P0[0][0] + j4) : (&P1[0][0] + (j4 - 64));
#pragma unroll
    for (int base = 0; base < 64; base += 16) {
      const int r0 = base + i, r1 = base + i + 8;
      float4 a0 = *(const float4*)&Pj[r0 * 68];
      float4 a1 = *(const float4*)&Pj[r1 * 68];
      for (int t = 0; t < base; ++t) {
        float c0 = Ab[r0][t], c1 = Ab[r1][t];
        float4 ut = *(const float4*)&Pj[t * 68];
        a0.x -= c0 * ut.x; a0.y -= c0 * ut.y;
        a0.z -= c0 * ut.z; a0.w -= c0 * ut.w;
        a1.x -= c1 * ut.x; a1.y -= c1 * ut.y;
        a1.z -= c1 * ut.z; a1.w -= c1 * ut.w;
      }
      *(float4*)&Pj[r0 * 68] = a0;
      *(float4*)&Pj[r1 * 68] = a1;
      __syncthreads();
      // intra-block: redundant in-register solve of the 16x16 unit-lower blk
      float4 val[16];
#pragma unroll
      for (int t = 0; t < 16; ++t) {
        float4 vt = *(const float4*)&Pj[(base + t) * 68];
#pragma unroll
        for (int m = 0; m < t; ++m) {
          float a = Ab[base + t][base + m];
          vt.x -= a * val[m].x; vt.y -= a * val[m].y;
          vt.z -= a * val[m].z; vt.w -= a * val[m].w;
        }
        val[t] = vt;
      }
      float4 f0 = val[0], f1 = val[8];
#pragma unroll
      for (int t = 1; t < 8; ++t)
        if (i == t) { f0 = val[t]; f1 = val[t + 8]; }
      __syncthreads();
      *(float4*)&Pj[r0 * 68] = f0;
      *(float4*)&Pj[r1 * 68] = f1;
      __syncthreads();
    }
  }
  // write U0 (bf16) and Wt (bf16, transposed); stage Kh into Ab
  {
    u16* u0p = U0g + (long)blk * (CH * DD);
    const int e4 = (tid & 15) * 4;
    const int t0 = tid >> 4;
    float lamL = lam[63];
#pragma unroll
    for (int p = 0; p < 4; ++p) {
      int t = t0 + p * 16;
      float4 u4 = *(const float4*)&P0[t][e4];
      ushort4 uw;
      uw.x = f2bf(u4.x); uw.y = f2bf(u4.y);
      uw.z = f2bf(u4.z); uw.w = f2bf(u4.w);
      *(ushort4*)&u0p[t * 64 + e4] = uw;
      float cf = expf(lamL - lam[t]);
      ushort4 kv4 = *(const ushort4*)&k[gb + (long)t * (HH * DD) + e4];
      *(float4*)&Ab[t][e4] = make_float4(b2f(kv4.x) * cf, b2f(kv4.y) * cf,
                                         b2f(kv4.z) * cf, b2f(kv4.w) * cf);
    }
    u16* wtp = Wtg + (long)blk * (DD * CH);
    const int t = tid & 63;
    const int d0 = tid >> 6;
#pragma unroll
    for (int p = 0; p < 16; ++p) {
      int d = d0 + p * 4;
      wtp[d * 64 + t] = f2bf(P1[t][d]);
    }
  }
  __syncthreads();
  // M[d][s] = gL*I - sum_t Kh[t][d]*W[t][s] ; b[d][e] = sum_t Kh[t][d]*U0[t][e]
  {
    float accm[4][4] = {}, accb[4][4] = {};
    for (int t = 0; t < 64; ++t) {
      float4 ka = *(const float4*)&Ab[t][ty * 4];
      float4 wc_ = *(const float4*)&P1[t][tx * 4];
      float4 uv = *(const float4*)&P0[t][tx * 4];
      float kar[4] = {ka.x, ka.y, ka.z, ka.w};
      float wcr[4] = {wc_.x, wc_.y, wc_.z, wc_.w};
      float ucr[4] = {uv.x, uv.y, uv.z, uv.w};
#pragma unroll
      for (int i = 0; i < 4; ++i)
#pragma unroll
        for (int j = 0; j < 4; ++j) {
          accm[i][j] += kar[i] * wcr[j];
          accb[i][j] += kar[i] * ucr[j];
        }
    }
    float gLv = expf(lam[63]);
    float* mp = Mtg + (long)blk * (DD * DD);
    float* bp = bvg + (long)blk * (DD * DD);
#pragma unroll
    for (int i = 0; i < 4; ++i) {
      int rr = ty * 4 + i;    // d
      float4 mv, b4;
      mv.x = ((rr == tx * 4 + 0) ? gLv : 0.f) - accm[i][0];
      mv.y = ((rr == tx * 4 + 1) ? gLv : 0.f) - accm[i][1];
      mv.z = ((rr == tx * 4 + 2) ? gLv : 0.f) - accm[i][2];
      mv.w = ((rr == tx * 4 + 3) ? gLv : 0.f) - accm[i][3];
      *(float4*)&mp[rr * 64 + tx * 4] = mv;   // [d][s]
      b4.x = accb[i][0]; b4.y = accb[i][1];
      b4.z = accb[i][2]; b4.w = accb[i][3];
      *(float4*)&bp[rr * 64 + tx * 4] = b4;   // [d][e]
    }
  }
}

// ---------------------------------------------------------------------------
// Sequential pass v5: S_{c+1} = M_c S_c + b_c, e-split 16-way (512 blocks).
// M quarter-row in registers; in-wave shfl reduction; Ss broadcast LDS.
// ---------------------------------------------------------------------------
__global__ __launch_bounds__(256) void gdn_seq5(
    const float* __restrict__ Mtg, const float* __restrict__ bvg,
    float* __restrict__ Sall) {
  const int bh = blockIdx.x & 31;         // XCD/L2-sharing swizzle
  const int esec = blockIdx.x >> 5;       // 0..15
  const int tid = threadIdx.x;
  const int lane = tid & 63;
  const int w = tid >> 6;
  const int d = w * 16 + (lane & 15);
  const int q = lane >> 4;                // 0..3 (s-quarter)
  const int eo = esec * 4;
  __shared__ float Ss[4][68];             // [e][s]
  float S0 = 0.f, S1 = 0.f, S2 = 0.f, S3 = 0.f;
  float4 mreg[4], mnext[4];
  float4 breg, bnext;
  {
    const float* mt0 = Mtg + (long)bh * NC * 4096;
#pragma unroll
    for (int p = 0; p < 4; ++p)
      mreg[p] = *(const float4*)&mt0[d * 64 + q * 16 + p * 4];
    breg = *(const float4*)&bvg[(long)bh * NC * 4096 + d * 64 + eo];
  }
  for (int c = 0; c < NC; ++c) {
    const long cb = (long)bh * NC + c;
    if (q == 0) {
      *(float4*)&Sall[cb * 4096 + d * 64 + eo] = make_float4(S0, S1, S2, S3);
      Ss[0][d] = S0; Ss[1][d] = S1; Ss[2][d] = S2; Ss[3][d] = S3;
    }
    __syncthreads();
    if (c + 1 < NC) {
      const float* mtn = Mtg + (cb + 1) * 4096;
#pragma unroll
      for (int p = 0; p < 4; ++p)
        mnext[p] = *(const float4*)&mtn[d * 64 + q * 16 + p * 4];
      bnext = *(const float4*)&bvg[(cb + 1) * 4096 + d * 64 + eo];
    }
    float p0 = 0.f, p1 = 0.f, p2 = 0.f, p3 = 0.f;
#pragma unroll
    for (int j = 0; j < 4; ++j) {
      float4 m4 = mreg[j];
      float4 s0 = *(const float4*)&Ss[0][q * 16 + j * 4];
      float4 s1 = *(const float4*)&Ss[1][q * 16 + j * 4];
      float4 s2 = *(const float4*)&Ss[2][q * 16 + j * 4];
      float4 s3 = *(const float4*)&Ss[3][q * 16 + j * 4];
      p0 += m4.x * s0.x + m4.y * s0.y + m4.z * s0.z + m4.w * s0.w;
      p1 += m4.x * s1.x + m4.y * s1.y + m4.z * s1.z + m4.w * s1.w;
      p2 += m4.x * s2.x + m4.y * s2.y + m4.z * s2.z + m4.w * s2.w;
      p3 += m4.x * s3.x + m4.y * s3.y + m4.z * s3.z + m4.w * s3.w;
    }
    p0 += __shfl_xor(p0, 16); p0 += __shfl_xor(p0, 32);
    p1 += __shfl_xor(p1, 16); p1 += __shfl_xor(p1, 32);
    p2 += __shfl_xor(p2, 16); p2 += __shfl_xor(p2, 32);
    p3 += __shfl_xor(p3, 16); p3 += __shfl_xor(p3, 32);
    S0 = breg.x + p0; S1 = breg.y + p1;
    S2 = breg.z + p2; S3 = breg.w + p3;
    __syncthreads();
    mreg[0] = mnext[0]; mreg[1] = mnext[1];
    mreg[2] = mnext[2]; mreg[3] = mnext[3];
    breg = bnext;
  }
}

// ---------------------------------------------------------------------------
// Fully parallel per-chunk output: u = U0 - W.S ; o = B.u + Qh.S, then
// FUSED rms_norm(o)*scale*silu(g) -> gated bf16 (norm_gate eliminated).
// Per output row t, e-cols live in 16 consecutive lanes -> shfl reduce.
// ---------------------------------------------------------------------------
__global__ __launch_bounds__(256) void gdn_out(
    const u16* __restrict__ U0g, const u16* __restrict__ Wtg,
    const u16* __restrict__ Btg, const u16* __restrict__ Qhtg,
    const float* __restrict__ Sall, const u16* __restrict__ gg,
    const float* __restrict__ scale, u16* __restrict__ gated) {
  const int blk = blockIdx.x;
  const int bh = blk / NC, c = blk % NC;
  const int b = bh >> 4, h = bh & 15;
  const int tid = threadIdx.x;
  const int tx = tid & 15, ty = tid >> 4;
  __shared__ float S[64][64];
  __shared__ float ub[64][64];
  __shared__ float op[64][64];
  const int e4 = (tid & 15) * 4;
  const int t0s = tid >> 4;
  {
    const int r = tid >> 2, qq = (tid & 3) * 16;
#pragma unroll
    for (int p = 0; p < 4; ++p)
      *(float4*)&S[r][qq + p * 4] =
          *(const float4*)&Sall[(long)blk * 4096 + r * 64 + qq + p * 4];
  }
#pragma unroll
  for (int p = 0; p < 4; ++p) {
    int t = t0s + p * 16;
    ushort4 w4 = *(const ushort4*)&Wtg[(long)blk * 4096 + t * 64 + e4];
    *(float4*)&op[t][e4] = make_float4(b2f(w4.x), b2f(w4.y), b2f(w4.z), b2f(w4.w));
  }
  __syncthreads();
  float acc[4][4];
#pragma unroll
  for (int i = 0; i < 4; ++i) {
    ushort4 u4 = *(const ushort4*)&U0g[(long)blk * 4096 + (ty * 4 + i) * 64 + tx * 4];
    acc[i][0] = b2f(u4.x); acc[i][1] = b2f(u4.y);
    acc[i][2] = b2f(u4.z); acc[i][3] = b2f(u4.w);
  }
  for (int d = 0; d < 64; ++d) {
    float4 a4 = *(const float4*)&op[d][ty * 4];
    float4 b4 = *(const float4*)&S[d][tx * 4];
    float ar[4] = {a4.x, a4.y, a4.z, a4.w};
    float br[4] = {b4.x, b4.y, b4.z, b4.w};
#pragma unroll
    for (int i = 0; i < 4; ++i)
#pragma unroll
      for (int j = 0; j < 4; ++j) acc[i][j] -= ar[i] * br[j];
  }
#pragma unroll
  for (int i = 0; i < 4; ++i)
    *(float4*)&ub[ty * 4 + i][tx * 4] =
        make_float4(acc[i][0], acc[i][1], acc[i][2], acc[i][3]);
  __syncthreads();
#pragma unroll
  for (int p = 0; p < 4; ++p) {
    int t = t0s + p * 16;
    ushort4 w4 = *(const ushort4*)&Btg[(long)blk * 4096 + t * 64 + e4];
    *(float4*)&op[t][e4] = make_float4(b2f(w4.x), b2f(w4.y), b2f(w4.z), b2f(w4.w));
  }
  __syncthreads();
  float acco[4][4] = {};
  for (int s = 0; s < 64; ++s) {
    float4 a4 = *(const float4*)&op[s][ty * 4];
    float4 b4 = *(const float4*)&ub[s][tx * 4];
    float ar[4] = {a4.x, a4.y, a4.z, a4.w};
    float br[4] = {b4.x, b4.y, b4.z, b4.w};
#pragma unroll
    for (int i = 0; i < 4; ++i)
#pragma unroll
      for (int j = 0; j < 4; ++j) acco[i][j] += ar[i] * br[j];
  }
  __syncthreads();
#pragma unroll
  for (int p = 0; p < 4; ++p) {
    int t = t0s + p * 16;
    ushort4 w4 = *(const ushort4*)&Qhtg[(long)blk * 4096 + t * 64 + e4];
    *(float4*)&op[t][e4] = make_float4(b2f(w4.x), b2f(w4.y), b2f(w4.z), b2f(w4.w));
  }
  __syncthreads();
  for (int d = 0; d < 64; ++d) {
    float4 a4 = *(const float4*)&op[d][ty * 4];
    float4 b4 = *(const float4*)&S[d][tx * 4];
    float ar[4] = {a4.x, a4.y, a4.z, a4.w};
    float br[4] = {b4.x, b4.y, b4.z, b4.w};
#pragma unroll
    for (int i = 0; i < 4; ++i)
#pragma unroll
      for (int j = 0; j < 4; ++j) acco[i][j] += ar[i] * br[j];
  }
  // fused epilogue: rms over e (16 lanes), * scale * silu(g), bf16 out
  float4 sc = *(const float4*)&scale[tx * 4];
#pragma unroll
  for (int i = 0; i < 4; ++i) {
    int t = ty * 4 + i;
    float ssq = acco[i][0] * acco[i][0] + acco[i][1] * acco[i][1] +
                acco[i][2] * acco[i][2] + acco[i][3] * acco[i][3];
    ssq += __shfl_xor(ssq, 1);
    ssq += __shfl_xor(ssq, 2);
    ssq += __shfl_xor(ssq, 4);
    ssq += __shfl_xor(ssq, 8);
    float r = rsqrtf(ssq * (1.f / 64.f) + EPSF);
    long gidx = ((long)(b * TT + c * CH + t) * HH + h) * DD + tx * 4;
    ushort4 g4u = *(const ushort4*)&gg[gidx];
    float4 g4 = make_float4(b2f(g4u.x), b2f(g4u.y), b2f(g4u.z), b2f(g4u.w));
    ushort4 res;
    res.x = f2bf(acco[i][0] * r * sc.x * (g4.x / (1.f + expf(-g4.x))));
    res.y = f2bf(acco[i][1] * r * sc.y * (g4.y / (1.f + expf(-g4.y))));
    res.z = f2bf(acco[i][2] * r * sc.z * (g4.z / (1.f + expf(-g4.z))));
    res.w = f2bf(acco[i][3] * r * sc.w * (g4.w / (1.f + expf(-g4.w))));
    *(ushort4*)&gated[gidx] = res;
  }
}

// ---------------------------------------------------------------------------
extern "C" void kernel_launch(void* const* d_in, const int* in_sizes, int n_in,
                              void* d_out, int out_size, void* d_ws,
                              size_t ws_size, hipStream_t stream) {
  const float* x      = (const float*)d_in[0];
  const float* wq     = (const float*)d_in[1];
  const float* wk     = (const float*)d_in[2];
  const float* wv     = (const float*)d_in[3];
  const float* wg     = (const float*)d_in[4];
  const float* wo     = (const float*)d_in[5];
  const float* wa     = (const float*)d_in[6];
  const float* wb     = (const float*)d_in[7];
  const float* cqw    = (const float*)d_in[8];
  const float* cqb    = (const float*)d_in[9];
  const float* ckw    = (const float*)d_in[10];
  const float* ckb    = (const float*)d_in[11];
  const float* cvw    = (const float*)d_in[12];
  const float* cvb    = (const float*)d_in[13];
  const float* A_log  = (const float*)d_in[14];
  const float* dtb    = (const float*)d_in[15];
  const float* oscale = (const float*)d_in[16];
  float* out = (float*)d_out;

  u16 *pqb, *pkb, *pvb, *qb, *kb, *vb, *gb;
  u16 *xb, *wbb, *wob, *gatedb, *U0, *Wt, *Bt, *Qht;
  float *beta, *ldec, *Mc, *bc, *Sall;
  hipGetSymbolAddress((void**)&pqb,   HIP_SYMBOL(g_pqb));
  hipGetSymbolAddress((void**)&pkb,   HIP_SYMBOL(g_pkb));
  hipGetSymbolAddress((void**)&pvb,   HIP_SYMBOL(g_pvb));
  hipGetSymbolAddress((void**)&qb,    HIP_SYMBOL(g_qb));
  hipGetSymbolAddress((void**)&kb,    HIP_SYMBOL(g_kb));
  hipGetSymbolAddress((void**)&vb,    HIP_SYMBOL(g_vb));
  hipGetSymbolAddress((void**)&gb,    HIP_SYMBOL(g_gb));
  hipGetSymbolAddress((void**)&beta,  HIP_SYMBOL(g_beta));
  hipGetSymbolAddress((void**)&ldec,  HIP_SYMBOL(g_ldec));
  hipGetSymbolAddress((void**)&xb,    HIP_SYMBOL(g_xb));
  hipGetSymbolAddress((void**)&wbb,   HIP_SYMBOL(g_wbb));
  hipGetSymbolAddress((void**)&wob,   HIP_SYMBOL(g_wob));
  hipGetSymbolAddress((void**)&gatedb,HIP_SYMBOL(g_gatedb));
  hipGetSymbolAddress((void**)&U0,    HIP_SYMBOL(g_U0));
  hipGetSymbolAddress((void**)&Wt,    HIP_SYMBOL(g_Wt));
  hipGetSymbolAddress((void**)&Bt,    HIP_SYMBOL(g_Bt));
  hipGetSymbolAddress((void**)&Qht,   HIP_SYMBOL(g_Qht));
  hipGetSymbolAddress((void**)&Mc,    HIP_SYMBOL(g_Mc));
  hipGetSymbolAddress((void**)&bc,    HIP_SYMBOL(g_bc));
  hipGetSymbolAddress((void**)&Sall,  HIP_SYMBOL(g_Sall));

  cast_all<<<9216, 256, 0, stream>>>(x, wq, wk, wv, wg, wo, xb, wbb, wob);

  // fused QKVG projection -> bf16 outputs (BK=64, XCD serpentine)
  bgemm4<u16, 32><<<1024, 256, 0, stream>>>(xb, wbb, pqb, pkb, pvb, gb);

  conv3<<<dim3(BT, 3), 256, 0, stream>>>(pqb, pkb, pvb,
                                         cqw, cqb, ckw, ckb, cvw, cvb,
                                         qb, kb, vb);
  proj_ab3<<<BT / 8, 256, 0, stream>>>(x, wa, wb, dtb, A_log, beta, ldec);

  gdn_prep<<<NCHK, 256, 0, stream>>>(qb, kb, vb, beta, ldec,
                                     U0, Wt, Bt, Qht, Mc, bc);
  gdn_seq5<<<NBH * 16, 256, 0, stream>>>(Mc, bc, Sall);
  // gdn_out now fuses rms_norm * scale * silu(g) -> gatedb
  gdn_out<<<NCHK, 256, 0, stream>>>(U0, Wt, Bt, Qht, Sall, gb, oscale, gatedb);

  // final projection: out = gated_bf16 @ wo^T (fp32 out, 256 blocks)
  bgemm4<float, 8><<<256, 256, 0, stream>>>(gatedb, wob, out, out, out, out);
}

// Round 20
// 266.654 us; speedup vs baseline: 1.1192x; 1.0136x over previous
//
#include <hip/hip_runtime.h>
#include <math.h>

#define BB 2
#define TT 2048
#define CC 1024
#define HH 16
#define DD 64
#define INNER 1024
#define BT (BB*TT)   /* 4096 */
#define EPSF 1e-6f
#define CH 64
#define NC (TT/CH)        /* 32 */
#define NBH (BB*HH)       /* 32 */
#define NCHK (NBH*NC)     /* 1024 */

typedef unsigned short u16;
typedef __bf16 bf16x8 __attribute__((ext_vector_type(8)));
typedef float f32x4 __attribute__((ext_vector_type(4)));

__device__ inline u16 f2bf(float f) {   // RNE float->bf16
  unsigned u = __builtin_bit_cast(unsigned, f);
  return (u16)((u + 0x7fffu + ((u >> 16) & 1u)) >> 16);
}
__device__ inline float b2f(u16 b) {
  unsigned u = ((unsigned)b) << 16;
  return __builtin_bit_cast(float, u);
}
__device__ inline void gll16(const u16* g, u16* l) {
  __builtin_amdgcn_global_load_lds(
      (const __attribute__((address_space(1))) void*)g,
      (__attribute__((address_space(3))) void*)l, 16, 0, 0);
}

// Static device scratch (fully overwritten every call; deterministic).
__device__ u16   g_pqb[BT * INNER];      // pre_q bf16
__device__ u16   g_pkb[BT * INNER];      // pre_k
__device__ u16   g_pvb[BT * INNER];      // pre_v
__device__ u16   g_qb [BT * INNER];      // q bf16 (post conv+l2)
__device__ u16   g_kb [BT * INNER];
__device__ u16   g_vb [BT * INNER];
__device__ u16   g_gb [BT * INNER];      // g projection bf16
__device__ float g_beta[BT * HH];
__device__ float g_ldec[BT * HH];
__device__ u16   g_xb[BT * CC];          // x in bf16
__device__ u16   g_wbb[4 * INNER * CC];  // wq|wk|wv|wg in bf16
__device__ u16   g_wob[CC * INNER];      // wo in bf16
__device__ u16   g_gatedb[BT * INNER];   // gated activations bf16
// per-chunk tensors: output path bf16, state path fp32
__device__ u16   g_U0 [NCHK * CH * DD];
__device__ u16   g_Wt [NCHK * DD * CH];
__device__ u16   g_Bt [NCHK * CH * CH];
__device__ u16   g_Qht[NCHK * DD * CH];
__device__ float g_Mc [NCHK * DD * DD];  // M[d][s] row-major (d = row)
__device__ float g_bc [NCHK * DD * DD];  // b[d][e]
__device__ float g_Sall[NCHK * DD * DD]; // chunk-start states [d][e]

// ---------------------------------------------------------------------------
// Fused cast of x and all weights to bf16.
// ---------------------------------------------------------------------------
__global__ __launch_bounds__(256) void cast_all(
    const float* __restrict__ x, const float* __restrict__ wq,
    const float* __restrict__ wk, const float* __restrict__ wv,
    const float* __restrict__ wg, const float* __restrict__ wo,
    u16* __restrict__ xb, u16* __restrict__ wb, u16* __restrict__ wob) {
  long i = ((long)blockIdx.x * 256 + threadIdx.x) * 4;
  const float* src;
  u16* dst;
  if (i < 4194304)      { src = x  + i;             dst = xb + i; }
  else if (i < 5242880) { src = wq + (i - 4194304); dst = wb + (i - 4194304); }
  else if (i < 6291456) { src = wk + (i - 5242880); dst = wb + (i - 4194304); }
  else if (i < 7340032) { src = wv + (i - 6291456); dst = wb + (i - 4194304); }
  else if (i < 8388608) { src = wg + (i - 7340032); dst = wb + (i - 4194304); }
  else                  { src = wo + (i - 8388608); dst = wob + (i - 8388608); }
  float4 v = *(const float4*)src;
  ushort4 o;
  o.x = f2bf(v.x); o.y = f2bf(v.y); o.z = f2bf(v.z); o.w = f2bf(v.w);
  *(ushort4*)dst = o;
}

// ---------------------------------------------------------------------------
// bf16 MFMA GEMM: BK=64, source-swizzled LDS (0 bank conflicts), XCD
// serpentine region remap. C[m,n] = sum_k A[m,k]*B[n,k], K=1024, 128x128.
// ---------------------------------------------------------------------------
template <typename OutT, int NBN>
__global__ __launch_bounds__(256) void bgemm4(
    const u16* __restrict__ A, const u16* __restrict__ B,
    OutT* __restrict__ c0, OutT* __restrict__ c1,
    OutT* __restrict__ c2, OutT* __restrict__ c3) {
  __shared__ u16 lA[128 * 64];
  __shared__ u16 lB[128 * 64];
  const int tid = threadIdx.x;
  const int bid = blockIdx.x;
  int bm, bn;
  if constexpr (NBN == 32) {
    const int xcd = bid & 7;
    const int idx = bid >> 3;          // 0..127
    const int in_ = idx >> 4;          // 0..7
    int im = idx & 15;
    im = (in_ & 1) ? (15 - im) : im;
    bm = ((xcd >> 2) * 16 + im) * 128;
    bn = ((xcd & 3) * 8 + in_) * 128;
  } else {
    const int xcd = bid & 7;
    const int idx = bid >> 3;          // 0..31
    const int in_ = idx >> 2;          // 0..7
    int im = idx & 3;
    im = (in_ & 1) ? (3 - im) : im;
    bm = (xcd * 4 + im) * 128;
    bn = in_ * 128;
  }
  const int lane = tid & 63;
  const int wave = tid >> 6;
  const int wr = (wave >> 1) * 64, wc = (wave & 1) * 64;
  const int lr = lane & 15;
  const int kq = lane >> 4;            // 0..3
  const int srow0 = tid >> 3;          // 0..31
  const int gcol = ((tid & 7) ^ (srow0 & 7)) * 8;
  const u16* gA0 = &A[(long)(bm + srow0) * CC + gcol];
  const u16* gB0 = &B[(long)(bn + srow0) * CC + gcol];
  u16* lA0 = &lA[tid * 8];
  u16* lB0 = &lB[tid * 8];
  f32x4 acc[4][4] = {};

  for (int k0 = 0; k0 < CC; k0 += 64) {
    __syncthreads();                  // protect prev-iter LDS reads
#pragma unroll
    for (int p = 0; p < 4; ++p) {
      gll16(gA0 + (long)p * 32 * CC + k0, lA0 + p * 2048);
      gll16(gB0 + (long)p * 32 * CC + k0, lB0 + p * 2048);
    }
    __syncthreads();                  // drains vmcnt before reads
#pragma unroll
    for (int ks = 0; ks < 2; ++ks) {
      const int sl = ((ks * 4 + kq) ^ (lr & 7)) * 8;
      bf16x8 af[4], bf_[4];
#pragma unroll
      for (int m = 0; m < 4; ++m)
        af[m] = __builtin_bit_cast(bf16x8,
            *(const uint4*)&lA[(wr + m * 16 + lr) * 64 + sl]);
#pragma unroll
      for (int n = 0; n < 4; ++n)
        bf_[n] = __builtin_bit_cast(bf16x8,
            *(const uint4*)&lB[(wc + n * 16 + lr) * 64 + sl]);
#pragma unroll
      for (int m = 0; m < 4; ++m)
#pragma unroll
        for (int n = 0; n < 4; ++n)
          acc[m][n] = __builtin_amdgcn_mfma_f32_16x16x32_bf16(
              af[m], bf_[n], acc[m][n], 0, 0, 0);
    }
  }
  OutT* cp = (bn < 1024) ? c0 : (bn < 2048) ? c1 : (bn < 3072) ? c2 : c3;
  const int ccol0 = (bn & 1023) + wc;
  const int crow0 = bm + wr + kq * 4;
#pragma unroll
  for (int m = 0; m < 4; ++m)
#pragma unroll
    for (int n = 0; n < 4; ++n) {
      int col = ccol0 + n * 16 + lr;
#pragma unroll
      for (int r = 0; r < 4; ++r) {
        long idx2 = (long)(crow0 + m * 16 + r) * INNER + col;
        if constexpr (sizeof(OutT) == 2) cp[idx2] = f2bf(acc[m][n][r]);
        else                             cp[idx2] = acc[m][n][r];
      }
    }
}

// ---------------------------------------------------------------------------
// Fused causal depthwise conv1d(K=4) + SiLU (+per-head L2 norm for q,k).
// ---------------------------------------------------------------------------
__global__ __launch_bounds__(256) void conv3(
    const u16* __restrict__ pq, const u16* __restrict__ pk,
    const u16* __restrict__ pv,
    const float* __restrict__ cqw, const float* __restrict__ cqb,
    const float* __restrict__ ckw, const float* __restrict__ ckb,
    const float* __restrict__ cvw, const float* __restrict__ cvb,
    u16* __restrict__ oq, u16* __restrict__ ok, u16* __restrict__ ov) {
  const int which = blockIdx.y;
  const u16* pre = which == 0 ? pq : which == 1 ? pk : pv;
  const float* cw = which == 0 ? cqw : which == 1 ? ckw : cvw;
  const float* cb = which == 0 ? cqb : which == 1 ? ckb : cvb;
  u16* out = which == 0 ? oq : which == 1 ? ok : ov;
  const int do_l2 = (which < 2);

  const int bt = blockIdx.x;
  const int b = bt / TT, t = bt % TT;
  const int tid = threadIdx.x;
  const int c4 = tid * 4;
  float xt[4][4];
#pragma unroll
  for (int j = 0; j < 4; ++j) {
    int ts = t - 3 + j;
    if (ts >= 0) {
      ushort4 u = *(const ushort4*)&pre[(long)(b * TT + ts) * INNER + c4];
      xt[j][0] = b2f(u.x); xt[j][1] = b2f(u.y);
      xt[j][2] = b2f(u.z); xt[j][3] = b2f(u.w);
    } else {
      xt[j][0] = xt[j][1] = xt[j][2] = xt[j][3] = 0.f;
    }
  }
  float4 bias4 = *(const float4*)&cb[c4];
  const float* bp = (const float*)&bias4;
  float y[4];
#pragma unroll
  for (int ci = 0; ci < 4; ++ci) {
    float4 w4 = *(const float4*)&cw[(c4 + ci) * 4];
    float acc = bp[ci];
    acc += w4.x * xt[0][ci];
    acc += w4.y * xt[1][ci];
    acc += w4.z * xt[2][ci];
    acc += w4.w * xt[3][ci];
    y[ci] = acc / (1.f + __expf(-acc));   // SiLU (fast exp)
  }
  if (do_l2) {
    float ssq = y[0]*y[0] + y[1]*y[1] + y[2]*y[2] + y[3]*y[3];
    ssq += __shfl_xor(ssq, 1);
    ssq += __shfl_xor(ssq, 2);
    ssq += __shfl_xor(ssq, 4);
    ssq += __shfl_xor(ssq, 8);   // 16 threads = one head (64 channels)
    float r = rsqrtf(ssq + EPSF);
    y[0] *= r; y[1] *= r; y[2] *= r; y[3] *= r;
  }
  ushort4 res;
  res.x = f2bf(y[0]); res.y = f2bf(y[1]);
  res.z = f2bf(y[2]); res.w = f2bf(y[3]);
  *(ushort4*)&out[(long)bt * INNER + c4] = res;
}

// ---------------------------------------------------------------------------
// beta = sigmoid(x@wb.T); ldec = -exp(A_log)*softplus(x@wa.T + dt_bias)
// (kept precise: ldec errors are amplified by exp(A_log) and prefix sums)
// ---------------------------------------------------------------------------
__global__ __launch_bounds__(256) void proj_ab3(
    const float* __restrict__ x, const float* __restrict__ wa,
    const float* __restrict__ wb, const float* __restrict__ dt_bias,
    const float* __restrict__ A_log, float* __restrict__ beta,
    float* __restrict__ ldec) {
  const int m0 = blockIdx.x * 8;
  const int tid = threadIdx.x;
  __shared__ float xs[8][132];
  __shared__ float ws[32][132];
  const int row = tid >> 5;
  const int col = tid & 31;
  float a0 = 0.f, a1 = 0.f, a2 = 0.f, a3 = 0.f;
  const int sxr = tid >> 5, sxc = (tid & 31) * 4;
  for (int k0 = 0; k0 < CC; k0 += 128) {
    __syncthreads();
    *(float4*)&xs[sxr][sxc] = *(const float4*)&x[(long)(m0 + sxr) * CC + k0 + sxc];
#pragma unroll
    for (int p = 0; p < 4; ++p) {
      int idx = tid + p * 256;
      int wr = idx >> 5, wc4 = (idx & 31) * 4;
      const float* wsrc = (wr < 16) ? &wa[(long)wr * CC] : &wb[(long)(wr - 16) * CC];
      *(float4*)&ws[wr][wc4] = *(const float4*)&wsrc[k0 + wc4];
    }
    __syncthreads();
#pragma unroll
    for (int kk = 0; kk < 128; kk += 16) {
      float4 x0 = *(const float4*)&xs[row][kk + 0];
      float4 w0 = *(const float4*)&ws[col][kk + 0];
      float4 x1 = *(const float4*)&xs[row][kk + 4];
      float4 w1 = *(const float4*)&ws[col][kk + 4];
      float4 x2 = *(const float4*)&xs[row][kk + 8];
      float4 w2 = *(const float4*)&ws[col][kk + 8];
      float4 x3 = *(const float4*)&xs[row][kk + 12];
      float4 w3 = *(const float4*)&ws[col][kk + 12];
      a0 += x0.x * w0.x + x0.y * w0.y + x0.z * w0.z + x0.w * w0.w;
      a1 += x1.x * w1.x + x1.y * w1.y + x1.z * w1.z + x1.w * w1.w;
      a2 += x2.x * w2.x + x2.y * w2.y + x2.z * w2.z + x2.w * w2.w;
      a3 += x3.x * w3.x + x3.y * w3.y + x3.z * w3.z + x3.w * w3.w;
    }
  }
  float acc = (a0 + a1) + (a2 + a3);
  const int m = m0 + row;
  if (col < 16) {
    float a = acc + dt_bias[col];
    float sp = fmaxf(a, 0.f) + log1pf(expf(-fabsf(a)));
    ldec[(long)m * HH + col] = -expf(A_log[col]) * sp;
  } else {
    beta[(long)m * HH + (col - 16)] = 1.f / (1.f + expf(-acc));
  }
}

// ---------------------------------------------------------------------------
// Per-chunk parallel precompute. grid = NCHK (1024), 256 threads.
// G/Pm via MFMA; lam via wave-0 shfl scan; all scale exps via __expf
// (v_exp_f32, 2-ulp: negligible vs bf16). Substitution BS=16 (12 barriers).
// ---------------------------------------------------------------------------
__global__ __launch_bounds__(256) void gdn_prep(
    const u16* __restrict__ q, const u16* __restrict__ k,
    const u16* __restrict__ v, const float* __restrict__ beta,
    const float* __restrict__ ldec,
    u16* __restrict__ U0g, u16* __restrict__ Wtg, u16* __restrict__ Btg,
    u16* __restrict__ Qhtg, float* __restrict__ Mtg, float* __restrict__ bvg) {
  const int blk = blockIdx.x;
  const int bh = blk / NC, c = blk % NC;
  const int b = bh >> 4, h = bh & 15;
  const int tid = threadIdx.x;
  const int tx = tid & 15, ty = tid >> 4;
  __shared__ float P0[64][68];   // beta*v  -> U0[t][e]
  __shared__ float P1[64][68];   // qst[d][t], then beta*exp(lamx)*k -> W[t][d]
  __shared__ float Ab[64][68];   // A[t][s] -> later Kh[t][d]
  __shared__ float lam[64], lamx[64], lbet[64];
  const long gb = ((long)(b * TT + c * CH) * HH + h) * DD;

  // stage q transposed (bf16 -> fp32) for Qht only
  {
    const int e4 = (tid & 15) * 4;
    const int t0 = tid >> 4;
#pragma unroll
    for (int p = 0; p < 4; ++p) {
      int t = t0 + p * 16;
      ushort4 qv = *(const ushort4*)&q[gb + (long)t * (HH * DD) + e4];
      P1[e4 + 0][t] = b2f(qv.x); P1[e4 + 1][t] = b2f(qv.y);
      P1[e4 + 2][t] = b2f(qv.z); P1[e4 + 3][t] = b2f(qv.w);
    }
  }
  // lam inclusive prefix via wave-0 Hillis-Steele shfl scan (6 steps)
  if (tid < 64) {
    float ldv = ldec[(long)(b * TT + c * CH + tid) * HH + h];
    float bv_ = beta[(long)(b * TT + c * CH + tid) * HH + h];
    float v_ = ldv;
#pragma unroll
    for (int off = 1; off < 64; off <<= 1) {
      float o = __shfl_up(v_, off);
      if (tid >= off) v_ += o;
    }
    lam[tid] = v_;
    lamx[tid] = v_ - ldv;
    lbet[tid] = bv_;
  }
  __syncthreads();

  // MFMA: G = K.K^T, Pm = K.Q^T (each wave owns a 32x32 quadrant).
  {
    const int lane = tid & 63;
    const int wave = tid >> 6;
    const int lr = lane & 15;
    const int kq = lane >> 4;
    const int mwr = (wave >> 1) * 32, mwc = (wave & 1) * 32;
    bf16x8 af[2][2], bk_[2][2], bq_[2][2];
#pragma unroll
    for (int m = 0; m < 2; ++m)
#pragma unroll
      for (int ks = 0; ks < 2; ++ks) {
        long rbase = gb + (long)(mwr + m * 16 + lr) * (HH * DD) + ks * 32 + kq * 8;
        long cbase = gb + (long)(mwc + m * 16 + lr) * (HH * DD) + ks * 32 + kq * 8;
        af[m][ks]  = __builtin_bit_cast(bf16x8, *(const uint4*)&k[rbase]);
        bk_[m][ks] = __builtin_bit_cast(bf16x8, *(const uint4*)&k[cbase]);
        bq_[m][ks] = __builtin_bit_cast(bf16x8, *(const uint4*)&q[cbase]);
      }
    f32x4 gf[2][2] = {}, pf[2][2] = {};
#pragma unroll
    for (int ks = 0; ks < 2; ++ks)
#pragma unroll
      for (int m = 0; m < 2; ++m)
#pragma unroll
        for (int n = 0; n < 2; ++n) {
          gf[m][n] = __builtin_amdgcn_mfma_f32_16x16x32_bf16(
              af[m][ks], bk_[n][ks], gf[m][n], 0, 0, 0);
          pf[m][n] = __builtin_amdgcn_mfma_f32_16x16x32_bf16(
              af[m][ks], bq_[n][ks], pf[m][n], 0, 0, 0);
        }
    u16* btp = Btg + (long)blk * (CH * CH);
#pragma unroll
    for (int m = 0; m < 2; ++m)
#pragma unroll
      for (int n = 0; n < 2; ++n)
#pragma unroll
        for (int r = 0; r < 4; ++r) {
          int t = mwr + m * 16 + kq * 4 + r;   // C row (K index for both)
          int s = mwc + n * 16 + lr;           // C col
          Ab[t][s] = (s < t)
              ? lbet[t] * __expf(lamx[t] - lam[s]) * gf[m][n][r] : 0.f;
          btp[t * 64 + s] = f2bf(
              (t <= s) ? __expf(lam[s] - lam[t]) * pf[m][n][r] : 0.f);
        }
  }
  // Qht[d][t] bf16 (from qst in P1)
  {
    u16* qhp = Qhtg + (long)blk * (DD * CH);
    const int t4 = (tid & 15) * 4;
    const int d0 = tid >> 4;
    float e0 = __expf(lam[t4 + 0]), e1 = __expf(lam[t4 + 1]);
    float e2 = __expf(lam[t4 + 2]), e3 = __expf(lam[t4 + 3]);
#pragma unroll
    for (int p = 0; p < 4; ++p) {
      int d = d0 + p * 16;
      float4 qv = *(const float4*)&P1[d][t4];
      ushort4 qw;
      qw.x = f2bf(qv.x * e0);
      qw.y = f2bf(qv.y * e1);
      qw.z = f2bf(qv.z * e2);
      qw.w = f2bf(qv.w * e3);
      *(ushort4*)&qhp[d * 64 + t4] = qw;
    }
  }
  __syncthreads();
  // re-init: P0[t][e] = beta_t v ; P1[t][d] = beta_t exp(lamx_t) k
  {
    const int e4 = (tid & 15) * 4;
    const int t0 = tid >> 4;
#pragma unroll
    for (int p = 0; p < 4; ++p) {
      int t = t0 + p * 16;
      float bt_ = lbet[t], cx = bt_ * __expf(lamx[t]);
      ushort4 vv4 = *(const ushort4*)&v[gb + (long)t * (HH * DD) + e4];
      ushort4 kv4 = *(const ushort4*)&k[gb + (long)t * (HH * DD) + e4];
      float4 vv = make_float4(b2f(vv4.x) * bt_, b2f(vv4.y) * bt_,
                              b2f(vv4.z) * bt_, b2f(vv4.w) * bt_);
      float4 kv = make_float4(b2f(kv4.x) * cx, b2f(kv4.y) * cx,
                              b2f(kv4.z) * cx, b2f(kv4.w) * cx);
      *(float4*)&P0[t][e4] = vv;
      *(float4*)&P1[t][e4] = kv;
    }
  }
  __syncthreads();
  // BLOCKED forward substitution on (I+A), BS=16: thread (i, j4) owns rows
  // base+i and base+i+8; summation t ascending per row (bit-identical).
  {
    const int i = tid >> 5;
    const int j4 = (tid & 31) * 4;
    float* Pj = (j4 < 64) ? (&P0[0][0] + j4) : (&P1[0][0] + (j4 - 64));
#pragma unroll
    for (int base = 0; base < 64; base += 16) {
      const int r0 = base + i, r1 = base + i + 8;
      float4 a0 = *(const float4*)&Pj[r0 * 68];
      float4 a1 = *(const float4*)&Pj[r1 * 68];
      for (int t = 0; t < base; ++t) {
        float c0 = Ab[r0][t], c1 = Ab[r1][t];
        float4 ut = *(const float4*)&Pj[t * 68];
        a0.x -= c0 * ut.x; a0.y -= c0 * ut.y;
        a0.z -= c0 * ut.z; a0.w -= c0 * ut.w;
        a1.x -= c1 * ut.x; a1.y -= c1 * ut.y;
        a1.z -= c1 * ut.z; a1.w -= c1 * ut.w;
      }
      *(float4*)&Pj[r0 * 68] = a0;
      *(float4*)&Pj[r1 * 68] = a1;
      __syncthreads();
      // intra-block: redundant in-register solve of the 16x16 unit-lower blk
      float4 val[16];
#pragma unroll
      for (int t = 0; t < 16; ++t) {
        float4 vt = *(const float4*)&Pj[(base + t) * 68];
#pragma unroll
        for (int m = 0; m < t; ++m) {
          float a = Ab[base + t][base + m];
          vt.x -= a * val[m].x; vt.y -= a * val[m].y;
          vt.z -= a * val[m].z; vt.w -= a * val[m].w;
        }
        val[t] = vt;
      }
      float4 f0 = val[0], f1 = val[8];
#pragma unroll
      for (int t = 1; t < 8; ++t)
        if (i == t) { f0 = val[t]; f1 = val[t + 8]; }
      __syncthreads();
      *(float4*)&Pj[r0 * 68] = f0;
      *(float4*)&Pj[r1 * 68] = f1;
      __syncthreads();
    }
  }
  // write U0 (bf16) and Wt (bf16, transposed); stage Kh into Ab
  {
    u16* u0p = U0g + (long)blk * (CH * DD);
    const int e4 = (tid & 15) * 4;
    const int t0 = tid >> 4;
    float lamL = lam[63];
#pragma unroll
    for (int p = 0; p < 4; ++p) {
      int t = t0 + p * 16;
      float4 u4 = *(const float4*)&P0[t][e4];
      ushort4 uw;
      uw.x = f2bf(u4.x); uw.y = f2bf(u4.y);
      uw.z = f2bf(u4.z); uw.w = f2bf(u4.w);
      *(ushort4*)&u0p[t * 64 + e4] = uw;
      float cf = __expf(lamL - lam[t]);
      ushort4 kv4 = *(const ushort4*)&k[gb + (long)t * (HH * DD) + e4];
      *(float4*)&Ab[t][e4] = make_float4(b2f(kv4.x) * cf, b2f(kv4.y) * cf,
                                         b2f(kv4.z) * cf, b2f(kv4.w) * cf);
    }
    u16* wtp = Wtg + (long)blk * (DD * CH);
    const int t = tid & 63;
    const int d0 = tid >> 6;
#pragma unroll
    for (int p = 0; p < 16; ++p) {
      int d = d0 + p * 4;
      wtp[d * 64 + t] = f2bf(P1[t][d]);
    }
  }
  __syncthreads();
  // M[d][s] = gL*I - sum_t Kh[t][d]*W[t][s] ; b[d][e] = sum_t Kh[t][d]*U0[t][e]
  {
    float accm[4][4] = {}, accb[4][4] = {};
    for (int t = 0; t < 64; ++t) {
      float4 ka = *(const float4*)&Ab[t][ty * 4];
      float4 wc_ = *(const float4*)&P1[t][tx * 4];
      float4 uv = *(const float4*)&P0[t][tx * 4];
      float kar[4] = {ka.x, ka.y, ka.z, ka.w};
      float wcr[4] = {wc_.x, wc_.y, wc_.z, wc_.w};
      float ucr[4] = {uv.x, uv.y, uv.z, uv.w};
#pragma unroll
      for (int i = 0; i < 4; ++i)
#pragma unroll
        for (int j = 0; j < 4; ++j) {
          accm[i][j] += kar[i] * wcr[j];
          accb[i][j] += kar[i] * ucr[j];
        }
    }
    float gLv = __expf(lam[63]);
    float* mp = Mtg + (long)blk * (DD * DD);
    float* bp = bvg + (long)blk * (DD * DD);
#pragma unroll
    for (int i = 0; i < 4; ++i) {
      int rr = ty * 4 + i;    // d
      float4 mv, b4;
      mv.x = ((rr == tx * 4 + 0) ? gLv : 0.f) - accm[i][0];
      mv.y = ((rr == tx * 4 + 1) ? gLv : 0.f) - accm[i][1];
      mv.z = ((rr == tx * 4 + 2) ? gLv : 0.f) - accm[i][2];
      mv.w = ((rr == tx * 4 + 3) ? gLv : 0.f) - accm[i][3];
      *(float4*)&mp[rr * 64 + tx * 4] = mv;   // [d][s]
      b4.x = accb[i][0]; b4.y = accb[i][1];
      b4.z = accb[i][2]; b4.w = accb[i][3];
      *(float4*)&bp[rr * 64 + tx * 4] = b4;   // [d][e]
    }
  }
}

// ---------------------------------------------------------------------------
// Sequential pass v5: S_{c+1} = M_c S_c + b_c, e-split 16-way (512 blocks).
// M quarter-row in registers; in-wave shfl reduction; Ss broadcast LDS.
// ---------------------------------------------------------------------------
__global__ __launch_bounds__(256) void gdn_seq5(
    const float* __restrict__ Mtg, const float* __restrict__ bvg,
    float* __restrict__ Sall) {
  const int bh = blockIdx.x & 31;         // XCD/L2-sharing swizzle
  const int esec = blockIdx.x >> 5;       // 0..15
  const int tid = threadIdx.x;
  const int lane = tid & 63;
  const int w = tid >> 6;
  const int d = w * 16 + (lane & 15);
  const int q = lane >> 4;                // 0..3 (s-quarter)
  const int eo = esec * 4;
  __shared__ float Ss[4][68];             // [e][s]
  float S0 = 0.f, S1 = 0.f, S2 = 0.f, S3 = 0.f;
  float4 mreg[4], mnext[4];
  float4 breg, bnext;
  {
    const float* mt0 = Mtg + (long)bh * NC * 4096;
#pragma unroll
    for (int p = 0; p < 4; ++p)
      mreg[p] = *(const float4*)&mt0[d * 64 + q * 16 + p * 4];
    breg = *(const float4*)&bvg[(long)bh * NC * 4096 + d * 64 + eo];
  }
  for (int c = 0; c < NC; ++c) {
    const long cb = (long)bh * NC + c;
    if (q == 0) {
      *(float4*)&Sall[cb * 4096 + d * 64 + eo] = make_float4(S0, S1, S2, S3);
      Ss[0][d] = S0; Ss[1][d] = S1; Ss[2][d] = S2; Ss[3][d] = S3;
    }
    __syncthreads();
    if (c + 1 < NC) {
      const float* mtn = Mtg + (cb + 1) * 4096;
#pragma unroll
      for (int p = 0; p < 4; ++p)
        mnext[p] = *(const float4*)&mtn[d * 64 + q * 16 + p * 4];
      bnext = *(const float4*)&bvg[(cb + 1) * 4096 + d * 64 + eo];
    }
    float p0 = 0.f, p1 = 0.f, p2 = 0.f, p3 = 0.f;
#pragma unroll
    for (int j = 0; j < 4; ++j) {
      float4 m4 = mreg[j];
      float4 s0 = *(const float4*)&Ss[0][q * 16 + j * 4];
      float4 s1 = *(const float4*)&Ss[1][q * 16 + j * 4];
      float4 s2 = *(const float4*)&Ss[2][q * 16 + j * 4];
      float4 s3 = *(const float4*)&Ss[3][q * 16 + j * 4];
      p0 += m4.x * s0.x + m4.y * s0.y + m4.z * s0.z + m4.w * s0.w;
      p1 += m4.x * s1.x + m4.y * s1.y + m4.z * s1.z + m4.w * s1.w;
      p2 += m4.x * s2.x + m4.y * s2.y + m4.z * s2.z + m4.w * s2.w;
      p3 += m4.x * s3.x + m4.y * s3.y + m4.z * s3.z + m4.w * s3.w;
    }
    p0 += __shfl_xor(p0, 16); p0 += __shfl_xor(p0, 32);
    p1 += __shfl_xor(p1, 16); p1 += __shfl_xor(p1, 32);
    p2 += __shfl_xor(p2, 16); p2 += __shfl_xor(p2, 32);
    p3 += __shfl_xor(p3, 16); p3 += __shfl_xor(p3, 32);
    S0 = breg.x + p0; S1 = breg.y + p1;
    S2 = breg.z + p2; S3 = breg.w + p3;
    __syncthreads();
    mreg[0] = mnext[0]; mreg[1] = mnext[1];
    mreg[2] = mnext[2]; mreg[3] = mnext[3];
    breg = bnext;
  }
}

// ---------------------------------------------------------------------------
// Fully parallel per-chunk output: u = U0 - W.S ; o = B.u + Qh.S, then
// FUSED rms_norm(o)*scale*silu(g) -> gated bf16.
// ---------------------------------------------------------------------------
__global__ __launch_bounds__(256) void gdn_out(
    const u16* __restrict__ U0g, const u16* __restrict__ Wtg,
    const u16* __restrict__ Btg, const u16* __restrict__ Qhtg,
    const float* __restrict__ Sall, const u16* __restrict__ gg,
    const float* __restrict__ scale, u16* __restrict__ gated) {
  const int blk = blockIdx.x;
  const int bh = blk / NC, c = blk % NC;
  const int b = bh >> 4, h = bh & 15;
  const int tid = threadIdx.x;
  const int tx = tid & 15, ty = tid >> 4;
  __shared__ float S[64][64];
  __shared__ float ub[64][64];
  __shared__ float op[64][64];
  const int e4 = (tid & 15) * 4;
  const int t0s = tid >> 4;
  {
    const int r = tid >> 2, qq = (tid & 3) * 16;
#pragma unroll
    for (int p = 0; p < 4; ++p)
      *(float4*)&S[r][qq + p * 4] =
          *(const float4*)&Sall[(long)blk * 4096 + r * 64 + qq + p * 4];
  }
#pragma unroll
  for (int p = 0; p < 4; ++p) {
    int t = t0s + p * 16;
    ushort4 w4 = *(const ushort4*)&Wtg[(long)blk * 4096 + t * 64 + e4];
    *(float4*)&op[t][e4] = make_float4(b2f(w4.x), b2f(w4.y), b2f(w4.z), b2f(w4.w));
  }
  __syncthreads();
  float acc[4][4];
#pragma unroll
  for (int i = 0; i < 4; ++i) {
    ushort4 u4 = *(const ushort4*)&U0g[(long)blk * 4096 + (ty * 4 + i) * 64 + tx * 4];
    acc[i][0] = b2f(u4.x); acc[i][1] = b2f(u4.y);
    acc[i][2] = b2f(u4.z); acc[i][3] = b2f(u4.w);
  }
  for (int d = 0; d < 64; ++d) {
    float4 a4 = *(const float4*)&op[d][ty * 4];
    float4 b4 = *(const float4*)&S[d][tx * 4];
    float ar[4] = {a4.x, a4.y, a4.z, a4.w};
    float br[4] = {b4.x, b4.y, b4.z, b4.w};
#pragma unroll
    for (int i = 0; i < 4; ++i)
#pragma unroll
      for (int j = 0; j < 4; ++j) acc[i][j] -= ar[i] * br[j];
  }
#pragma unroll
  for (int i = 0; i < 4; ++i)
    *(float4*)&ub[ty * 4 + i][tx * 4] =
        make_float4(acc[i][0], acc[i][1], acc[i][2], acc[i][3]);
  __syncthreads();
#pragma unroll
  for (int p = 0; p < 4; ++p) {
    int t = t0s + p * 16;
    ushort4 w4 = *(const ushort4*)&Btg[(long)blk * 4096 + t * 64 + e4];
    *(float4*)&op[t][e4] = make_float4(b2f(w4.x), b2f(w4.y), b2f(w4.z), b2f(w4.w));
  }
  __syncthreads();
  float acco[4][4] = {};
  for (int s = 0; s < 64; ++s) {
    float4 a4 = *(const float4*)&op[s][ty * 4];
    float4 b4 = *(const float4*)&ub[s][tx * 4];
    float ar[4] = {a4.x, a4.y, a4.z, a4.w};
    float br[4] = {b4.x, b4.y, b4.z, b4.w};
#pragma unroll
    for (int i = 0; i < 4; ++i)
#pragma unroll
      for (int j = 0; j < 4; ++j) acco[i][j] += ar[i] * br[j];
  }
  __syncthreads();
#pragma unroll
  for (int p = 0; p < 4; ++p) {
    int t = t0s + p * 16;
    ushort4 w4 = *(const ushort4*)&Qhtg[(long)blk * 4096 + t * 64 + e4];
    *(float4*)&op[t][e4] = make_float4(b2f(w4.x), b2f(w4.y), b2f(w4.z), b2f(w4.w));
  }
  __syncthreads();
  for (int d = 0; d < 64; ++d) {
    float4 a4 = *(const float4*)&op[d][ty * 4];
    float4 b4 = *(const float4*)&S[d][tx * 4];
    float ar[4] = {a4.x, a4.y, a4.z, a4.w};
    float br[4] = {b4.x, b4.y, b4.z, b4.w};
#pragma unroll
    for (int i = 0; i < 4; ++i)
#pragma unroll
      for (int j = 0; j < 4; ++j) acco[i][j] += ar[i] * br[j];
  }
  // fused epilogue: rms over e (16 lanes), * scale * silu(g), bf16 out
  float4 sc = *(const float4*)&scale[tx * 4];
#pragma unroll
  for (int i = 0; i < 4; ++i) {
    int t = ty * 4 + i;
    float ssq = acco[i][0] * acco[i][0] + acco[i][1] * acco[i][1] +
                acco[i][2] * acco[i][2] + acco[i][3] * acco[i][3];
    ssq += __shfl_xor(ssq, 1);
    ssq += __shfl_xor(ssq, 2);
    ssq += __shfl_xor(ssq, 4);
    ssq += __shfl_xor(ssq, 8);
    float r = rsqrtf(ssq * (1.f / 64.f) + EPSF);
    long gidx = ((long)(b * TT + c * CH + t) * HH + h) * DD + tx * 4;
    ushort4 g4u = *(const ushort4*)&gg[gidx];
    float4 g4 = make_float4(b2f(g4u.x), b2f(g4u.y), b2f(g4u.z), b2f(g4u.w));
    ushort4 res;
    res.x = f2bf(acco[i][0] * r * sc.x * (g4.x / (1.f + __expf(-g4.x))));
    res.y = f2bf(acco[i][1] * r * sc.y * (g4.y / (1.f + __expf(-g4.y))));
    res.z = f2bf(acco[i][2] * r * sc.z * (g4.z / (1.f + __expf(-g4.z))));
    res.w = f2bf(acco[i][3] * r * sc.w * (g4.w / (1.f + __expf(-g4.w))));
    *(ushort4*)&gated[gidx] = res;
  }
}

// ---------------------------------------------------------------------------
extern "C" void kernel_launch(void* const* d_in, const int* in_sizes, int n_in,
                              void* d_out, int out_size, void* d_ws,
                              size_t ws_size, hipStream_t stream) {
  const float* x      = (const float*)d_in[0];
  const float* wq     = (const float*)d_in[1];
  const float* wk     = (const float*)d_in[2];
  const float* wv     = (const float*)d_in[3];
  const float* wg     = (const float*)d_in[4];
  const float* wo     = (const float*)d_in[5];
  const float* wa     = (const float*)d_in[6];
  const float* wb     = (const float*)d_in[7];
  const float* cqw    = (const float*)d_in[8];
  const float* cqb    = (const float*)d_in[9];
  const float* ckw    = (const float*)d_in[10];
  const float* ckb    = (const float*)d_in[11];
  const float* cvw    = (const float*)d_in[12];
  const float* cvb    = (const float*)d_in[13];
  const float* A_log  = (const float*)d_in[14];
  const float* dtb    = (const float*)d_in[15];
  const float* oscale = (const float*)d_in[16];
  float* out = (float*)d_out;

  u16 *pqb, *pkb, *pvb, *qb, *kb, *vb, *gb;
  u16 *xb, *wbb, *wob, *gatedb, *U0, *Wt, *Bt, *Qht;
  float *beta, *ldec, *Mc, *bc, *Sall;
  hipGetSymbolAddress((void**)&pqb,   HIP_SYMBOL(g_pqb));
  hipGetSymbolAddress((void**)&pkb,   HIP_SYMBOL(g_pkb));
  hipGetSymbolAddress((void**)&pvb,   HIP_SYMBOL(g_pvb));
  hipGetSymbolAddress((void**)&qb,    HIP_SYMBOL(g_qb));
  hipGetSymbolAddress((void**)&kb,    HIP_SYMBOL(g_kb));
  hipGetSymbolAddress((void**)&vb,    HIP_SYMBOL(g_vb));
  hipGetSymbolAddress((void**)&gb,    HIP_SYMBOL(g_gb));
  hipGetSymbolAddress((void**)&beta,  HIP_SYMBOL(g_beta));
  hipGetSymbolAddress((void**)&ldec,  HIP_SYMBOL(g_ldec));
  hipGetSymbolAddress((void**)&xb,    HIP_SYMBOL(g_xb));
  hipGetSymbolAddress((void**)&wbb,   HIP_SYMBOL(g_wbb));
  hipGetSymbolAddress((void**)&wob,   HIP_SYMBOL(g_wob));
  hipGetSymbolAddress((void**)&gatedb,HIP_SYMBOL(g_gatedb));
  hipGetSymbolAddress((void**)&U0,    HIP_SYMBOL(g_U0));
  hipGetSymbolAddress((void**)&Wt,    HIP_SYMBOL(g_Wt));
  hipGetSymbolAddress((void**)&Bt,    HIP_SYMBOL(g_Bt));
  hipGetSymbolAddress((void**)&Qht,   HIP_SYMBOL(g_Qht));
  hipGetSymbolAddress((void**)&Mc,    HIP_SYMBOL(g_Mc));
  hipGetSymbolAddress((void**)&bc,    HIP_SYMBOL(g_bc));
  hipGetSymbolAddress((void**)&Sall,  HIP_SYMBOL(g_Sall));

  cast_all<<<9216, 256, 0, stream>>>(x, wq, wk, wv, wg, wo, xb, wbb, wob);

  // fused QKVG projection -> bf16 outputs (BK=64, XCD serpentine)
  bgemm4<u16, 32><<<1024, 256, 0, stream>>>(xb, wbb, pqb, pkb, pvb, gb);

  conv3<<<dim3(BT, 3), 256, 0, stream>>>(pqb, pkb, pvb,
                                         cqw, cqb, ckw, ckb, cvw, cvb,
                                         qb, kb, vb);
  proj_ab3<<<BT / 8, 256, 0, stream>>>(x, wa, wb, dtb, A_log, beta, ldec);

  gdn_prep<<<NCHK, 256, 0, stream>>>(qb, kb, vb, beta, ldec,
                                     U0, Wt, Bt, Qht, Mc, bc);
  gdn_seq5<<<NBH * 16, 256, 0, stream>>>(Mc, bc, Sall);
  // gdn_out fuses rms_norm * scale * silu(g) -> gatedb
  gdn_out<<<NCHK, 256, 0, stream>>>(U0, Wt, Bt, Qht, Sall, gb, oscale, gatedb);

  // final projection: out = gated_bf16 @ wo^T (fp32 out, 256 blocks)
  bgemm4<float, 8><<<256, 256, 0, stream>>>(gatedb, wob, out, out, out, out);
}